// Round 3
// baseline (876.937 us; speedup 1.0000x reference)
//
#include <hip/hip_runtime.h>
#include <math.h>

#define DD 64
#define HH 8
#define KORD 4

// ---------- CSR build ----------
__global__ void k_count(const int* __restrict__ dst, int E, int* __restrict__ deg) {
    int i = blockIdx.x * 256 + threadIdx.x;
    if (i < E) atomicAdd(&deg[dst[i]], 1);
}

__global__ void k_blocksum(const int* __restrict__ deg, int n, int* __restrict__ bsum) {
    __shared__ int s[256];
    int i = blockIdx.x * 256 + threadIdx.x;
    s[threadIdx.x] = (i < n) ? deg[i] : 0;
    __syncthreads();
    for (int off = 128; off > 0; off >>= 1) {
        if (threadIdx.x < off) s[threadIdx.x] += s[threadIdx.x + off];
        __syncthreads();
    }
    if (threadIdx.x == 0) bsum[blockIdx.x] = s[0];
}

__global__ void k_scan_bsum(int* __restrict__ bsum, int nb) {
    __shared__ int s[256];
    int t = threadIdx.x;
    int v = (t < nb) ? bsum[t] : 0;
    s[t] = v;
    __syncthreads();
    for (int off = 1; off < 256; off <<= 1) {
        int tmp = (t >= off) ? s[t - off] : 0;
        __syncthreads();
        s[t] += tmp;
        __syncthreads();
    }
    if (t < nb) bsum[t] = s[t] - v;  // exclusive
}

__global__ void k_scan_final(const int* __restrict__ deg, const int* __restrict__ bsum,
                             int n, int E, int* __restrict__ offsets,
                             int* __restrict__ cursor, float* __restrict__ dinv) {
    __shared__ int s[256];
    int t = threadIdx.x, i = blockIdx.x * 256 + t;
    int v = (i < n) ? deg[i] : 0;
    s[t] = v;
    __syncthreads();
    for (int off = 1; off < 256; off <<= 1) {
        int tmp = (t >= off) ? s[t - off] : 0;
        __syncthreads();
        s[t] += tmp;
        __syncthreads();
    }
    if (i < n) {
        int excl = s[t] - v + bsum[blockIdx.x];
        offsets[i] = excl;
        cursor[i] = excl;
        int dv = v < 1 ? 1 : v;
        dinv[i] = 1.0f / sqrtf((float)dv);
    }
    if (i == 0) offsets[n] = E;
}

// scatter: build dst-sorted edge arrays (src, ew, dinv[src]) + inverse permutation
__global__ void k_scatter(const int* __restrict__ dst, const int* __restrict__ src,
                          const float* __restrict__ ew, const float* __restrict__ dinv,
                          int E, int* __restrict__ cursor, int* __restrict__ invp,
                          int* __restrict__ srcs, float* __restrict__ ews,
                          float* __restrict__ dinvs) {
    int i = blockIdx.x * 256 + threadIdx.x;
    if (i < E) {
        int s = src[i];
        int p = atomicAdd(&cursor[dst[i]], 1);
        invp[i] = p;
        srcs[p] = s;
        ews[p] = ew[i];
        dinvs[p] = dinv[s];
    }
}

// chunk-major WE transpose for scalar loads: WETc[q*256 + d*4 + c] = WE[(4q+c)*64 + d]
__global__ void k_wet(const float* __restrict__ WE, float* __restrict__ WETc) {
    for (int idx = threadIdx.x; idx < 4096; idx += 256) {
        int q = idx >> 8;
        int d = (idx >> 2) & 63;
        int c = idx & 3;
        WETc[idx] = WE[(q * 4 + c) * 64 + d];
    }
}

// ---------- pass 1: Tx1 = lap_mul(h), agg = sum ew*h[src] ----------
__global__ void k_pass1(const int* __restrict__ offsets, const int* __restrict__ srcs,
                        const float* __restrict__ ews, const float* __restrict__ dinvs,
                        const float* __restrict__ dinv, const float* __restrict__ h,
                        int n, float* __restrict__ Tx1, float* __restrict__ agg) {
    int w = threadIdx.x >> 6, lane = threadIdx.x & 63;
    int node = blockIdx.x * 4 + w;
    if (node >= n) return;
    int beg = offsets[node], end = offsets[node + 1];
    float aL = 0.f, aG = 0.f;
    int e2 = beg;
    for (; e2 + 4 <= end; e2 += 4) {
        int s0 = srcs[e2], s1 = srcs[e2 + 1], s2 = srcs[e2 + 2], s3 = srcs[e2 + 3];
        float v0 = h[(size_t)s0 * DD + lane], v1 = h[(size_t)s1 * DD + lane];
        float v2 = h[(size_t)s2 * DD + lane], v3 = h[(size_t)s3 * DD + lane];
        float d0 = dinvs[e2], d1 = dinvs[e2 + 1], d2 = dinvs[e2 + 2], d3 = dinvs[e2 + 3];
        float w0 = ews[e2], w1 = ews[e2 + 1], w2 = ews[e2 + 2], w3 = ews[e2 + 3];
        aL += d0 * v0 + d1 * v1 + d2 * v2 + d3 * v3;
        aG += w0 * v0 + w1 * v1 + w2 * v2 + w3 * v3;
    }
    for (; e2 < end; ++e2) {
        int s = srcs[e2];
        float v = h[(size_t)s * DD + lane];
        aL += dinvs[e2] * v;
        aG += ews[e2] * v;
    }
    Tx1[node * DD + lane] = -dinv[node] * aL;
    agg[node * DD + lane] = aG;
}

// ---------- out = alpha * lap_mul(x) + beta * prev ----------
__global__ void k_lap(const int* __restrict__ offsets, const int* __restrict__ srcs,
                      const float* __restrict__ dinvs, const float* __restrict__ dinv,
                      const float* __restrict__ x, const float* __restrict__ prev,
                      float alpha, float beta, int n, float* __restrict__ out) {
    int w = threadIdx.x >> 6, lane = threadIdx.x & 63;
    int node = blockIdx.x * 4 + w;
    if (node >= n) return;
    int beg = offsets[node], end = offsets[node + 1];
    float a = 0.f;
    int e2 = beg;
    for (; e2 + 4 <= end; e2 += 4) {
        int s0 = srcs[e2], s1 = srcs[e2 + 1], s2 = srcs[e2 + 2], s3 = srcs[e2 + 3];
        float v0 = x[(size_t)s0 * DD + lane], v1 = x[(size_t)s1 * DD + lane];
        float v2 = x[(size_t)s2 * DD + lane], v3 = x[(size_t)s3 * DD + lane];
        float d0 = dinvs[e2], d1 = dinvs[e2 + 1], d2 = dinvs[e2 + 2], d3 = dinvs[e2 + 3];
        a += d0 * v0 + d1 * v1 + d2 * v2 + d3 * v3;
    }
    for (; e2 < end; ++e2) {
        a += dinvs[e2] * x[(size_t)srcs[e2] * DD + lane];
    }
    out[node * DD + lane] = alpha * (-dinv[node] * a) + beta * prev[node * DD + lane];
}

// ---------- QKV projections, 8 nodes per wave ----------
__global__ void k_qkv(const float* __restrict__ h, const float* __restrict__ p,
                      const float* __restrict__ WQ, const float* __restrict__ WK,
                      const float* __restrict__ WV, int n,
                      float* __restrict__ Qh, float* __restrict__ Kh, float* __restrict__ Vh) {
    __shared__ float hp[32][128];
    int base = blockIdx.x * 32;
    int t = threadIdx.x;
    for (int idx = t; idx < 4096; idx += 256) {
        int ni = idx >> 7, j = idx & 127;
        int node = base + ni;
        float v = 0.f;
        if (node < n) v = (j < 64) ? h[node * 64 + j] : p[node * 64 + (j - 64)];
        hp[ni][j] = v;
    }
    __syncthreads();
    int w = t >> 6, lane = t & 63;
    float q[8], k[8], v[8];
#pragma unroll
    for (int r = 0; r < 8; ++r) { q[r] = 0.f; k[r] = 0.f; v[r] = 0.f; }
    for (int i = 0; i < 128; ++i) {
        float wq = WQ[i * 64 + lane], wk = WK[i * 64 + lane], wv = WV[i * 64 + lane];
#pragma unroll
        for (int r = 0; r < 8; ++r) {
            float x = hp[w * 8 + r][i];
            q[r] += x * wq; k[r] += x * wk; v[r] += x * wv;
        }
    }
#pragma unroll
    for (int r = 0; r < 8; ++r) {
        int node = base + w * 8 + r;
        if (node < n) {
            Qh[node * 64 + lane] = q[r];
            Kh[node * 64 + lane] = k[r];
            Vh[node * 64 + lane] = v[r];
        }
    }
}

// ---------- per-edge scores: eh[64] accumulators, streamed e-row, scalar WE loads ----------
__global__ __launch_bounds__(256) void k_score(
        const float* __restrict__ efeat, const float* __restrict__ WETc,
        const int* __restrict__ src, const int* __restrict__ dst,
        const int* __restrict__ invp,
        const float* __restrict__ Qh, const float* __restrict__ Kh,
        int E, float* __restrict__ ssS) {
    int edge = blockIdx.x * 256 + threadIdx.x;
    if (edge >= E) return;
    const float4* e4 = (const float4*)efeat + (size_t)edge * 16;
    const float4* W4 = (const float4*)WETc;
    float eh[64];
#pragma unroll
    for (int d = 0; d < 64; ++d) eh[d] = 0.f;
#pragma unroll 1
    for (int q = 0; q < 16; ++q) {
        float4 er = e4[q];
        const float4* Wq = W4 + q * 64;
#pragma unroll
        for (int d = 0; d < 64; ++d) {
            float4 wv = Wq[d];  // wave-uniform -> s_load
            eh[d] += er.x * wv.x + er.y * wv.y + er.z * wv.z + er.w * wv.w;
        }
    }
    int s_ = src[edge], t_ = dst[edge];
    int wp = invp[edge];
    const float4* Kp = (const float4*)Kh + (size_t)s_ * 16;
    const float4* Qp = (const float4*)Qh + (size_t)t_ * 16;
    const float invs = 0.35355339059327373f;  // 1/sqrt(8)
    float res[8];
#pragma unroll
    for (int h = 0; h < 8; ++h) {
        float4 kv0 = Kp[h * 2], kv1 = Kp[h * 2 + 1];
        float4 qv0 = Qp[h * 2], qv1 = Qp[h * 2 + 1];
        float sc = kv0.x * qv0.x * eh[h * 8 + 0] + kv0.y * qv0.y * eh[h * 8 + 1]
                 + kv0.z * qv0.z * eh[h * 8 + 2] + kv0.w * qv0.w * eh[h * 8 + 3]
                 + kv1.x * qv1.x * eh[h * 8 + 4] + kv1.y * qv1.y * eh[h * 8 + 5]
                 + kv1.z * qv1.z * eh[h * 8 + 6] + kv1.w * qv1.w * eh[h * 8 + 7];
        res[h] = __expf(fminf(fmaxf(sc * invs, -5.0f), 5.0f));
    }
    float4* o4 = (float4*)(ssS + (size_t)wp * HH);
    o4[0] = make_float4(res[0], res[1], res[2], res[3]);
    o4[1] = make_float4(res[4], res[5], res[6], res[7]);
}

// ---------- attention aggregation per node (ss already dst-sorted) ----------
__global__ void k_attn_agg(const int* __restrict__ offsets, const int* __restrict__ srcs,
                           const float* __restrict__ Vh, const float* __restrict__ ssS,
                           int n, float* __restrict__ out) {
    int w = threadIdx.x >> 6, lane = threadIdx.x & 63;
    int node = blockIdx.x * 4 + w;
    if (node >= n) return;
    int beg = offsets[node], end = offsets[node + 1];
    int hh = lane >> 3;
    float aV = 0.f, aZ = 0.f;
    int e2 = beg;
    for (; e2 + 4 <= end; e2 += 4) {
        int s0 = srcs[e2], s1 = srcs[e2 + 1], s2 = srcs[e2 + 2], s3 = srcs[e2 + 3];
        float v0 = Vh[(size_t)s0 * DD + lane], v1 = Vh[(size_t)s1 * DD + lane];
        float v2 = Vh[(size_t)s2 * DD + lane], v3 = Vh[(size_t)s3 * DD + lane];
        float sv0 = ssS[(size_t)e2 * HH + hh], sv1 = ssS[(size_t)(e2 + 1) * HH + hh];
        float sv2 = ssS[(size_t)(e2 + 2) * HH + hh], sv3 = ssS[(size_t)(e2 + 3) * HH + hh];
        aV += sv0 * v0 + sv1 * v1 + sv2 * v2 + sv3 * v3;
        aZ += sv0 + sv1 + sv2 + sv3;
    }
    for (; e2 < end; ++e2) {
        int s = srcs[e2];
        float sv = ssS[(size_t)e2 * HH + hh];
        aV += sv * Vh[(size_t)s * DD + lane];
        aZ += sv;
    }
    out[node * 192 + 128 + lane] = aV / (aZ + 1e-6f);
}

// ---------- output: cheb + gcn ----------
__global__ void k_out(const float* __restrict__ Tx0, const float* __restrict__ Tx1,
                      const float* __restrict__ Tx2, const float* __restrict__ Tx3,
                      const float* __restrict__ aggG, const float* __restrict__ fc,
                      const float* __restrict__ Wc, const float* __restrict__ bc,
                      const float* __restrict__ Wg, const float* __restrict__ bg,
                      int n, float* __restrict__ out) {
    __shared__ float sT[KORD][32][64];
    __shared__ float sA[32][64];
    int base = blockIdx.x * 32;
    int t = threadIdx.x;
    for (int idx = t; idx < 2048; idx += 256) {
        int ni = idx >> 6, j = idx & 63;
        int node = base + ni;
        if (node < n) {
            sT[0][ni][j] = fc[node] * Tx0[node * 64 + j];
            sT[1][ni][j] = fc[n + node] * Tx1[node * 64 + j];
            sT[2][ni][j] = fc[2 * n + node] * Tx2[node * 64 + j];
            sT[3][ni][j] = fc[3 * n + node] * Tx3[node * 64 + j];
            sA[ni][j] = aggG[node * 64 + j];
        } else {
            sT[0][ni][j] = 0.f; sT[1][ni][j] = 0.f;
            sT[2][ni][j] = 0.f; sT[3][ni][j] = 0.f;
            sA[ni][j] = 0.f;
        }
    }
    __syncthreads();
    int w = t >> 6, lane = t & 63;
    float acc[8];
#pragma unroll
    for (int i = 0; i < 8; ++i) acc[i] = 0.f;
#pragma unroll
    for (int k = 0; k < KORD; ++k) {
        for (int j = 0; j < 64; ++j) {
            float wv = Wc[k * 4096 + j * 64 + lane];
#pragma unroll
            for (int i = 0; i < 8; ++i) acc[i] += sT[k][w * 8 + i][j] * wv;
        }
    }
    float acc2[8];
#pragma unroll
    for (int i = 0; i < 8; ++i) acc2[i] = 0.f;
    for (int j = 0; j < 64; ++j) {
        float wv = Wg[j * 64 + lane];
#pragma unroll
        for (int i = 0; i < 8; ++i) acc2[i] += sA[w * 8 + i][j] * wv;
    }
    float bcv = bc[lane], bgv = bg[lane];
#pragma unroll
    for (int i = 0; i < 8; ++i) {
        int node = base + w * 8 + i;
        if (node < n) {
            out[node * 192 + lane] = acc[i] + bcv;
            out[node * 192 + 64 + lane] = acc2[i] + bgv;
        }
    }
}

extern "C" void kernel_launch(void* const* d_in, const int* in_sizes, int n_in,
                              void* d_out, int out_size, void* d_ws, size_t ws_size,
                              hipStream_t stream) {
    const float* h  = (const float*)d_in[0];
    const float* p  = (const float*)d_in[1];
    const float* ef = (const float*)d_in[2];
    const float* ew = (const float*)d_in[3];
    const float* fc = (const float*)d_in[4];
    const int* esrc = (const int*)d_in[5];
    const int* edst = (const int*)d_in[6];
    const float* Wc = (const float*)d_in[7];
    const float* bc = (const float*)d_in[8];
    const float* Wg = (const float*)d_in[9];
    const float* bg = (const float*)d_in[10];
    const float* WQ = (const float*)d_in[11];
    const float* WK = (const float*)d_in[12];
    const float* WV = (const float*)d_in[13];
    const float* WE = (const float*)d_in[14];

    const int n = in_sizes[0] / DD;   // 50000
    const int E = in_sizes[5];        // 800000
    float* out = (float*)d_out;

    char* wsp = (char*)d_ws;
    size_t o = 0;
    auto alloc = [&](size_t bytes) -> void* {
        void* r = (void*)(wsp + o);
        o = (o + bytes + 255) & ~(size_t)255;
        return r;
    };
    int* deg     = (int*)alloc((size_t)n * 4);
    int* offsets = (int*)alloc((size_t)(n + 1) * 4);
    int* cursor  = (int*)alloc((size_t)n * 4);
    int* invp    = (int*)alloc((size_t)E * 4);
    int* srcs    = (int*)alloc((size_t)E * 4);
    float* ews   = (float*)alloc((size_t)E * 4);
    float* dinvs = (float*)alloc((size_t)E * 4);
    int* bsum    = (int*)alloc(1024 * 4);
    float* dinv  = (float*)alloc((size_t)n * 4);
    float* WETc  = (float*)alloc(4096 * 4);
    float* Tx1   = (float*)alloc((size_t)n * DD * 4);
    float* Tx2   = (float*)alloc((size_t)n * DD * 4);
    float* Tx3   = (float*)alloc((size_t)n * DD * 4);
    float* agg   = (float*)alloc((size_t)n * DD * 4);
    float* Qh    = (float*)alloc((size_t)n * DD * 4);
    float* Kh    = (float*)alloc((size_t)n * DD * 4);
    float* Vh    = (float*)alloc((size_t)n * DD * 4);
    float* ssS   = (float*)alloc((size_t)E * HH * 4);
    (void)ws_size; (void)n_in; (void)out_size;

    hipMemsetAsync(deg, 0, (size_t)n * 4, stream);

    int nb = (n + 255) / 256;
    k_count<<<(E + 255) / 256, 256, 0, stream>>>(edst, E, deg);
    k_blocksum<<<nb, 256, 0, stream>>>(deg, n, bsum);
    k_scan_bsum<<<1, 256, 0, stream>>>(bsum, nb);
    k_scan_final<<<nb, 256, 0, stream>>>(deg, bsum, n, E, offsets, cursor, dinv);
    k_scatter<<<(E + 255) / 256, 256, 0, stream>>>(edst, esrc, ew, dinv, E, cursor,
                                                   invp, srcs, ews, dinvs);
    k_wet<<<1, 256, 0, stream>>>(WE, WETc);

    k_pass1<<<(n + 3) / 4, 256, 0, stream>>>(offsets, srcs, ews, dinvs, dinv, h, n, Tx1, agg);
    k_lap<<<(n + 3) / 4, 256, 0, stream>>>(offsets, srcs, dinvs, dinv, Tx1, h, 2.0f, -1.0f, n, Tx2);
    k_lap<<<(n + 3) / 4, 256, 0, stream>>>(offsets, srcs, dinvs, dinv, Tx2, Tx1, 2.0f, -1.0f, n, Tx3);

    k_qkv<<<(n + 31) / 32, 256, 0, stream>>>(h, p, WQ, WK, WV, n, Qh, Kh, Vh);
    k_score<<<(E + 255) / 256, 256, 0, stream>>>(ef, WETc, esrc, edst, invp, Qh, Kh, E, ssS);
    k_attn_agg<<<(n + 3) / 4, 256, 0, stream>>>(offsets, srcs, Vh, ssS, n, out);

    k_out<<<(n + 31) / 32, 256, 0, stream>>>(h, Tx1, Tx2, Tx3, agg, fc, Wc, bc, Wg, bg, n, out);
}

// Round 4
// 875.560 us; speedup vs baseline: 1.0016x; 1.0016x over previous
//
#include <hip/hip_runtime.h>
#include <math.h>

#define DD 64
#define HH 8
#define KORD 4

// ---------- CSR build ----------
__global__ void k_count(const int* __restrict__ dst, int E, int* __restrict__ deg) {
    int i = blockIdx.x * 256 + threadIdx.x;
    if (i < E) atomicAdd(&deg[dst[i]], 1);
}

__global__ void k_blocksum(const int* __restrict__ deg, int n, int* __restrict__ bsum) {
    __shared__ int s[256];
    int i = blockIdx.x * 256 + threadIdx.x;
    s[threadIdx.x] = (i < n) ? deg[i] : 0;
    __syncthreads();
    for (int off = 128; off > 0; off >>= 1) {
        if (threadIdx.x < off) s[threadIdx.x] += s[threadIdx.x + off];
        __syncthreads();
    }
    if (threadIdx.x == 0) bsum[blockIdx.x] = s[0];
}

__global__ void k_scan_bsum(int* __restrict__ bsum, int nb) {
    __shared__ int s[256];
    int t = threadIdx.x;
    int v = (t < nb) ? bsum[t] : 0;
    s[t] = v;
    __syncthreads();
    for (int off = 1; off < 256; off <<= 1) {
        int tmp = (t >= off) ? s[t - off] : 0;
        __syncthreads();
        s[t] += tmp;
        __syncthreads();
    }
    if (t < nb) bsum[t] = s[t] - v;  // exclusive
}

__global__ void k_scan_final(const int* __restrict__ deg, const int* __restrict__ bsum,
                             int n, int E, int* __restrict__ offsets,
                             int* __restrict__ cursor, float* __restrict__ dinv) {
    __shared__ int s[256];
    int t = threadIdx.x, i = blockIdx.x * 256 + t;
    int v = (i < n) ? deg[i] : 0;
    s[t] = v;
    __syncthreads();
    for (int off = 1; off < 256; off <<= 1) {
        int tmp = (t >= off) ? s[t - off] : 0;
        __syncthreads();
        s[t] += tmp;
        __syncthreads();
    }
    if (i < n) {
        int excl = s[t] - v + bsum[blockIdx.x];
        offsets[i] = excl;
        cursor[i] = excl;
        int dv = v < 1 ? 1 : v;
        dinv[i] = 1.0f / sqrtf((float)dv);
    }
    if (i == 0) offsets[n] = E;
}

// scatter: build dst-sorted edge arrays (src, ew, dinv[src]) + inverse permutation
__global__ void k_scatter(const int* __restrict__ dst, const int* __restrict__ src,
                          const float* __restrict__ ew, const float* __restrict__ dinv,
                          int E, int* __restrict__ cursor, int* __restrict__ invp,
                          int* __restrict__ srcs, float* __restrict__ ews,
                          float* __restrict__ dinvs) {
    int i = blockIdx.x * 256 + threadIdx.x;
    if (i < E) {
        int s = src[i];
        int p = atomicAdd(&cursor[dst[i]], 1);
        invp[i] = p;
        srcs[p] = s;
        ews[p] = ew[i];
        dinvs[p] = dinv[s];
    }
}

// WE^T: WET[d*64 + j] = WE[j*64 + d]  (lane d reads its column contiguously)
__global__ void k_wet(const float* __restrict__ WE, float* __restrict__ WET) {
    for (int idx = threadIdx.x; idx < 4096; idx += 256) {
        int d = idx >> 6, j = idx & 63;
        WET[idx] = WE[j * 64 + d];
    }
}

// ---------- pass 1: Tx1 = lap_mul(h), agg = sum ew*h[src] ----------
__global__ void k_pass1(const int* __restrict__ offsets, const int* __restrict__ srcs,
                        const float* __restrict__ ews, const float* __restrict__ dinvs,
                        const float* __restrict__ dinv, const float* __restrict__ h,
                        int n, float* __restrict__ Tx1, float* __restrict__ agg) {
    int w = threadIdx.x >> 6, lane = threadIdx.x & 63;
    int node = blockIdx.x * 4 + w;
    if (node >= n) return;
    int beg = offsets[node], end = offsets[node + 1];
    float aL = 0.f, aG = 0.f;
    int e2 = beg;
    for (; e2 + 4 <= end; e2 += 4) {
        int s0 = srcs[e2], s1 = srcs[e2 + 1], s2 = srcs[e2 + 2], s3 = srcs[e2 + 3];
        float v0 = h[(size_t)s0 * DD + lane], v1 = h[(size_t)s1 * DD + lane];
        float v2 = h[(size_t)s2 * DD + lane], v3 = h[(size_t)s3 * DD + lane];
        float d0 = dinvs[e2], d1 = dinvs[e2 + 1], d2 = dinvs[e2 + 2], d3 = dinvs[e2 + 3];
        float w0 = ews[e2], w1 = ews[e2 + 1], w2 = ews[e2 + 2], w3 = ews[e2 + 3];
        aL += d0 * v0 + d1 * v1 + d2 * v2 + d3 * v3;
        aG += w0 * v0 + w1 * v1 + w2 * v2 + w3 * v3;
    }
    for (; e2 < end; ++e2) {
        int s = srcs[e2];
        float v = h[(size_t)s * DD + lane];
        aL += dinvs[e2] * v;
        aG += ews[e2] * v;
    }
    Tx1[node * DD + lane] = -dinv[node] * aL;
    agg[node * DD + lane] = aG;
}

// ---------- out = alpha * lap_mul(x) + beta * prev ----------
__global__ void k_lap(const int* __restrict__ offsets, const int* __restrict__ srcs,
                      const float* __restrict__ dinvs, const float* __restrict__ dinv,
                      const float* __restrict__ x, const float* __restrict__ prev,
                      float alpha, float beta, int n, float* __restrict__ out) {
    int w = threadIdx.x >> 6, lane = threadIdx.x & 63;
    int node = blockIdx.x * 4 + w;
    if (node >= n) return;
    int beg = offsets[node], end = offsets[node + 1];
    float a = 0.f;
    int e2 = beg;
    for (; e2 + 4 <= end; e2 += 4) {
        int s0 = srcs[e2], s1 = srcs[e2 + 1], s2 = srcs[e2 + 2], s3 = srcs[e2 + 3];
        float v0 = x[(size_t)s0 * DD + lane], v1 = x[(size_t)s1 * DD + lane];
        float v2 = x[(size_t)s2 * DD + lane], v3 = x[(size_t)s3 * DD + lane];
        float d0 = dinvs[e2], d1 = dinvs[e2 + 1], d2 = dinvs[e2 + 2], d3 = dinvs[e2 + 3];
        a += d0 * v0 + d1 * v1 + d2 * v2 + d3 * v3;
    }
    for (; e2 < end; ++e2) {
        a += dinvs[e2] * x[(size_t)srcs[e2] * DD + lane];
    }
    out[node * DD + lane] = alpha * (-dinv[node] * a) + beta * prev[node * DD + lane];
}

// ---------- QKV projections, 8 nodes per wave ----------
__global__ void k_qkv(const float* __restrict__ h, const float* __restrict__ p,
                      const float* __restrict__ WQ, const float* __restrict__ WK,
                      const float* __restrict__ WV, int n,
                      float* __restrict__ Qh, float* __restrict__ Kh, float* __restrict__ Vh) {
    __shared__ float hp[32][128];
    int base = blockIdx.x * 32;
    int t = threadIdx.x;
    for (int idx = t; idx < 4096; idx += 256) {
        int ni = idx >> 7, j = idx & 127;
        int node = base + ni;
        float v = 0.f;
        if (node < n) v = (j < 64) ? h[node * 64 + j] : p[node * 64 + (j - 64)];
        hp[ni][j] = v;
    }
    __syncthreads();
    int w = t >> 6, lane = t & 63;
    float q[8], k[8], v[8];
#pragma unroll
    for (int r = 0; r < 8; ++r) { q[r] = 0.f; k[r] = 0.f; v[r] = 0.f; }
    for (int i = 0; i < 128; ++i) {
        float wq = WQ[i * 64 + lane], wk = WK[i * 64 + lane], wv = WV[i * 64 + lane];
#pragma unroll
        for (int r = 0; r < 8; ++r) {
            float x = hp[w * 8 + r][i];
            q[r] += x * wq; k[r] += x * wk; v[r] += x * wv;
        }
    }
#pragma unroll
    for (int r = 0; r < 8; ++r) {
        int node = base + w * 8 + r;
        if (node < n) {
            Qh[node * 64 + lane] = q[r];
            Kh[node * 64 + lane] = k[r];
            Vh[node * 64 + lane] = v[r];
        }
    }
}

// ---------- per-edge scores: WAVE per edge; lane=d; WE col in VGPRs; e-row scalar ----------
__global__ __launch_bounds__(256, 1) void k_score(
        const float* __restrict__ efeat, const float* __restrict__ WET,
        const int* __restrict__ src, const int* __restrict__ dst,
        const int* __restrict__ invp,
        const float* __restrict__ Qh, const float* __restrict__ Kh,
        int E, int nwaves, float* __restrict__ ssS) {
    int lane = threadIdx.x & 63;
    // wave-uniform wave id (readfirstlane forces SGPR / scalar-load selection)
    int wid = __builtin_amdgcn_readfirstlane(blockIdx.x * 4 + (threadIdx.x >> 6));
    int per = (E + nwaves - 1) / nwaves;
    int beg = wid * per;
    int end = beg + per;
    if (end > E) end = E;
    if (beg >= E) return;

    // lane d holds WE[:, d] (64 floats) for the whole kernel
    float wcol[64];
    const float4* wt4 = (const float4*)(WET + (size_t)lane * 64);
#pragma unroll
    for (int q = 0; q < 16; ++q) {
        float4 wv = wt4[q];
        wcol[q * 4 + 0] = wv.x; wcol[q * 4 + 1] = wv.y;
        wcol[q * 4 + 2] = wv.z; wcol[q * 4 + 3] = wv.w;
    }
    const float invs = 0.35355339059327373f;  // 1/sqrt(8)

    for (int e = beg; e < end; ++e) {
        // e-row: wave-uniform address -> scalar loads into SGPRs
        const float4* er4 = (const float4*)efeat + (size_t)e * 16;
        float eh = 0.f;
#pragma unroll
        for (int q = 0; q < 16; ++q) {
            float4 ev = er4[q];
            eh += ev.x * wcol[q * 4 + 0] + ev.y * wcol[q * 4 + 1]
                + ev.z * wcol[q * 4 + 2] + ev.w * wcol[q * 4 + 3];
        }
        int s_ = src[e], t_ = dst[e], wp = invp[e];  // uniform -> s_load
        float kv = Kh[(size_t)s_ * 64 + lane];  // coalesced 256B
        float qv = Qh[(size_t)t_ * 64 + lane];
        float prod = kv * qv * eh * invs;
        prod += __shfl_xor(prod, 1, 64);
        prod += __shfl_xor(prod, 2, 64);
        prod += __shfl_xor(prod, 4, 64);
        float sc = __expf(fminf(fmaxf(prod, -5.0f), 5.0f));
        if ((lane & 7) == 0) ssS[(size_t)wp * HH + (lane >> 3)] = sc;
    }
}

// ---------- attention aggregation per node (ss already dst-sorted) ----------
__global__ void k_attn_agg(const int* __restrict__ offsets, const int* __restrict__ srcs,
                           const float* __restrict__ Vh, const float* __restrict__ ssS,
                           int n, float* __restrict__ out) {
    int w = threadIdx.x >> 6, lane = threadIdx.x & 63;
    int node = blockIdx.x * 4 + w;
    if (node >= n) return;
    int beg = offsets[node], end = offsets[node + 1];
    int hh = lane >> 3;
    float aV = 0.f, aZ = 0.f;
    int e2 = beg;
    for (; e2 + 4 <= end; e2 += 4) {
        int s0 = srcs[e2], s1 = srcs[e2 + 1], s2 = srcs[e2 + 2], s3 = srcs[e2 + 3];
        float v0 = Vh[(size_t)s0 * DD + lane], v1 = Vh[(size_t)s1 * DD + lane];
        float v2 = Vh[(size_t)s2 * DD + lane], v3 = Vh[(size_t)s3 * DD + lane];
        float sv0 = ssS[(size_t)e2 * HH + hh], sv1 = ssS[(size_t)(e2 + 1) * HH + hh];
        float sv2 = ssS[(size_t)(e2 + 2) * HH + hh], sv3 = ssS[(size_t)(e2 + 3) * HH + hh];
        aV += sv0 * v0 + sv1 * v1 + sv2 * v2 + sv3 * v3;
        aZ += sv0 + sv1 + sv2 + sv3;
    }
    for (; e2 < end; ++e2) {
        int s = srcs[e2];
        float sv = ssS[(size_t)e2 * HH + hh];
        aV += sv * Vh[(size_t)s * DD + lane];
        aZ += sv;
    }
    out[node * 192 + 128 + lane] = aV / (aZ + 1e-6f);
}

// ---------- output: cheb + gcn ----------
__global__ void k_out(const float* __restrict__ Tx0, const float* __restrict__ Tx1,
                      const float* __restrict__ Tx2, const float* __restrict__ Tx3,
                      const float* __restrict__ aggG, const float* __restrict__ fc,
                      const float* __restrict__ Wc, const float* __restrict__ bc,
                      const float* __restrict__ Wg, const float* __restrict__ bg,
                      int n, float* __restrict__ out) {
    __shared__ float sT[KORD][32][64];
    __shared__ float sA[32][64];
    int base = blockIdx.x * 32;
    int t = threadIdx.x;
    for (int idx = t; idx < 2048; idx += 256) {
        int ni = idx >> 6, j = idx & 63;
        int node = base + ni;
        if (node < n) {
            sT[0][ni][j] = fc[node] * Tx0[node * 64 + j];
            sT[1][ni][j] = fc[n + node] * Tx1[node * 64 + j];
            sT[2][ni][j] = fc[2 * n + node] * Tx2[node * 64 + j];
            sT[3][ni][j] = fc[3 * n + node] * Tx3[node * 64 + j];
            sA[ni][j] = aggG[node * 64 + j];
        } else {
            sT[0][ni][j] = 0.f; sT[1][ni][j] = 0.f;
            sT[2][ni][j] = 0.f; sT[3][ni][j] = 0.f;
            sA[ni][j] = 0.f;
        }
    }
    __syncthreads();
    int w = t >> 6, lane = t & 63;
    float acc[8];
#pragma unroll
    for (int i = 0; i < 8; ++i) acc[i] = 0.f;
#pragma unroll
    for (int k = 0; k < KORD; ++k) {
        for (int j = 0; j < 64; ++j) {
            float wv = Wc[k * 4096 + j * 64 + lane];
#pragma unroll
            for (int i = 0; i < 8; ++i) acc[i] += sT[k][w * 8 + i][j] * wv;
        }
    }
    float acc2[8];
#pragma unroll
    for (int i = 0; i < 8; ++i) acc2[i] = 0.f;
    for (int j = 0; j < 64; ++j) {
        float wv = Wg[j * 64 + lane];
#pragma unroll
        for (int i = 0; i < 8; ++i) acc2[i] += sA[w * 8 + i][j] * wv;
    }
    float bcv = bc[lane], bgv = bg[lane];
#pragma unroll
    for (int i = 0; i < 8; ++i) {
        int node = base + w * 8 + i;
        if (node < n) {
            out[node * 192 + lane] = acc[i] + bcv;
            out[node * 192 + 64 + lane] = acc2[i] + bgv;
        }
    }
}

extern "C" void kernel_launch(void* const* d_in, const int* in_sizes, int n_in,
                              void* d_out, int out_size, void* d_ws, size_t ws_size,
                              hipStream_t stream) {
    const float* h  = (const float*)d_in[0];
    const float* p  = (const float*)d_in[1];
    const float* ef = (const float*)d_in[2];
    const float* ew = (const float*)d_in[3];
    const float* fc = (const float*)d_in[4];
    const int* esrc = (const int*)d_in[5];
    const int* edst = (const int*)d_in[6];
    const float* Wc = (const float*)d_in[7];
    const float* bc = (const float*)d_in[8];
    const float* Wg = (const float*)d_in[9];
    const float* bg = (const float*)d_in[10];
    const float* WQ = (const float*)d_in[11];
    const float* WK = (const float*)d_in[12];
    const float* WV = (const float*)d_in[13];
    const float* WE = (const float*)d_in[14];

    const int n = in_sizes[0] / DD;   // 50000
    const int E = in_sizes[5];        // 800000
    float* out = (float*)d_out;

    char* wsp = (char*)d_ws;
    size_t o = 0;
    auto alloc = [&](size_t bytes) -> void* {
        void* r = (void*)(wsp + o);
        o = (o + bytes + 255) & ~(size_t)255;
        return r;
    };
    int* deg     = (int*)alloc((size_t)n * 4);
    int* offsets = (int*)alloc((size_t)(n + 1) * 4);
    int* cursor  = (int*)alloc((size_t)n * 4);
    int* invp    = (int*)alloc((size_t)E * 4);
    int* srcs    = (int*)alloc((size_t)E * 4);
    float* ews   = (float*)alloc((size_t)E * 4);
    float* dinvs = (float*)alloc((size_t)E * 4);
    int* bsum    = (int*)alloc(1024 * 4);
    float* dinv  = (float*)alloc((size_t)n * 4);
    float* WET   = (float*)alloc(4096 * 4);
    float* Tx1   = (float*)alloc((size_t)n * DD * 4);
    float* Tx2   = (float*)alloc((size_t)n * DD * 4);
    float* Tx3   = (float*)alloc((size_t)n * DD * 4);
    float* agg   = (float*)alloc((size_t)n * DD * 4);
    float* Qh    = (float*)alloc((size_t)n * DD * 4);
    float* Kh    = (float*)alloc((size_t)n * DD * 4);
    float* Vh    = (float*)alloc((size_t)n * DD * 4);
    float* ssS   = (float*)alloc((size_t)E * HH * 4);
    (void)ws_size; (void)n_in; (void)out_size;

    hipMemsetAsync(deg, 0, (size_t)n * 4, stream);

    int nb = (n + 255) / 256;
    k_count<<<(E + 255) / 256, 256, 0, stream>>>(edst, E, deg);
    k_blocksum<<<nb, 256, 0, stream>>>(deg, n, bsum);
    k_scan_bsum<<<1, 256, 0, stream>>>(bsum, nb);
    k_scan_final<<<nb, 256, 0, stream>>>(deg, bsum, n, E, offsets, cursor, dinv);
    k_scatter<<<(E + 255) / 256, 256, 0, stream>>>(edst, esrc, ew, dinv, E, cursor,
                                                   invp, srcs, ews, dinvs);
    k_wet<<<1, 256, 0, stream>>>(WE, WET);

    k_pass1<<<(n + 3) / 4, 256, 0, stream>>>(offsets, srcs, ews, dinvs, dinv, h, n, Tx1, agg);
    k_lap<<<(n + 3) / 4, 256, 0, stream>>>(offsets, srcs, dinvs, dinv, Tx1, h, 2.0f, -1.0f, n, Tx2);
    k_lap<<<(n + 3) / 4, 256, 0, stream>>>(offsets, srcs, dinvs, dinv, Tx2, Tx1, 2.0f, -1.0f, n, Tx3);

    k_qkv<<<(n + 31) / 32, 256, 0, stream>>>(h, p, WQ, WK, WV, n, Qh, Kh, Vh);

    const int score_blocks = 4096;
    const int score_waves = score_blocks * 4;
    k_score<<<score_blocks, 256, 0, stream>>>(ef, WET, esrc, edst, invp, Qh, Kh,
                                              E, score_waves, ssS);
    k_attn_agg<<<(n + 3) / 4, 256, 0, stream>>>(offsets, srcs, Vh, ssS, n, out);

    k_out<<<(n + 31) / 32, 256, 0, stream>>>(h, Tx1, Tx2, Tx3, agg, fc, Wc, bc, Wg, bg, n, out);
}

// Round 5
// 631.022 us; speedup vs baseline: 1.3897x; 1.3875x over previous
//
#include <hip/hip_runtime.h>
#include <math.h>

#define DD 64
#define HH 8
#define KORD 4

// ---------- CSR build ----------
__global__ void k_count(const int* __restrict__ dst, int E, int* __restrict__ deg) {
    int i = blockIdx.x * 256 + threadIdx.x;
    if (i < E) atomicAdd(&deg[dst[i]], 1);
}

__global__ void k_blocksum(const int* __restrict__ deg, int n, int* __restrict__ bsum) {
    __shared__ int s[256];
    int i = blockIdx.x * 256 + threadIdx.x;
    s[threadIdx.x] = (i < n) ? deg[i] : 0;
    __syncthreads();
    for (int off = 128; off > 0; off >>= 1) {
        if (threadIdx.x < off) s[threadIdx.x] += s[threadIdx.x + off];
        __syncthreads();
    }
    if (threadIdx.x == 0) bsum[blockIdx.x] = s[0];
}

__global__ void k_scan_bsum(int* __restrict__ bsum, int nb) {
    __shared__ int s[256];
    int t = threadIdx.x;
    int v = (t < nb) ? bsum[t] : 0;
    s[t] = v;
    __syncthreads();
    for (int off = 1; off < 256; off <<= 1) {
        int tmp = (t >= off) ? s[t - off] : 0;
        __syncthreads();
        s[t] += tmp;
        __syncthreads();
    }
    if (t < nb) bsum[t] = s[t] - v;  // exclusive
}

__global__ void k_scan_final(const int* __restrict__ deg, const int* __restrict__ bsum,
                             int n, int E, int* __restrict__ offsets,
                             int* __restrict__ cursor, float* __restrict__ dinv) {
    __shared__ int s[256];
    int t = threadIdx.x, i = blockIdx.x * 256 + t;
    int v = (i < n) ? deg[i] : 0;
    s[t] = v;
    __syncthreads();
    for (int off = 1; off < 256; off <<= 1) {
        int tmp = (t >= off) ? s[t - off] : 0;
        __syncthreads();
        s[t] += tmp;
        __syncthreads();
    }
    if (i < n) {
        int excl = s[t] - v + bsum[blockIdx.x];
        offsets[i] = excl;
        cursor[i] = excl;
        int dv = v < 1 ? 1 : v;
        dinv[i] = 1.0f / sqrtf((float)dv);
    }
    if (i == 0) offsets[n] = E;
}

// scatter: build dst-sorted edge arrays (src, ew, dinv[src]) + inverse permutation
__global__ void k_scatter(const int* __restrict__ dst, const int* __restrict__ src,
                          const float* __restrict__ ew, const float* __restrict__ dinv,
                          int E, int* __restrict__ cursor, int* __restrict__ invp,
                          int* __restrict__ srcs, float* __restrict__ ews,
                          float* __restrict__ dinvs) {
    int i = blockIdx.x * 256 + threadIdx.x;
    if (i < E) {
        int s = src[i];
        int p = atomicAdd(&cursor[dst[i]], 1);
        invp[i] = p;
        srcs[p] = s;
        ews[p] = ew[i];
        dinvs[p] = dinv[s];
    }
}

// ---------- pass 1: Tx1 = lap_mul(h), agg = sum ew*h[src] ----------
__global__ void k_pass1(const int* __restrict__ offsets, const int* __restrict__ srcs,
                        const float* __restrict__ ews, const float* __restrict__ dinvs,
                        const float* __restrict__ dinv, const float* __restrict__ h,
                        int n, float* __restrict__ Tx1, float* __restrict__ agg) {
    int w = threadIdx.x >> 6, lane = threadIdx.x & 63;
    int node = blockIdx.x * 4 + w;
    if (node >= n) return;
    int beg = offsets[node], end = offsets[node + 1];
    float aL = 0.f, aG = 0.f;
    int e2 = beg;
    for (; e2 + 4 <= end; e2 += 4) {
        int s0 = srcs[e2], s1 = srcs[e2 + 1], s2 = srcs[e2 + 2], s3 = srcs[e2 + 3];
        float v0 = h[(size_t)s0 * DD + lane], v1 = h[(size_t)s1 * DD + lane];
        float v2 = h[(size_t)s2 * DD + lane], v3 = h[(size_t)s3 * DD + lane];
        float d0 = dinvs[e2], d1 = dinvs[e2 + 1], d2 = dinvs[e2 + 2], d3 = dinvs[e2 + 3];
        float w0 = ews[e2], w1 = ews[e2 + 1], w2 = ews[e2 + 2], w3 = ews[e2 + 3];
        aL += d0 * v0 + d1 * v1 + d2 * v2 + d3 * v3;
        aG += w0 * v0 + w1 * v1 + w2 * v2 + w3 * v3;
    }
    for (; e2 < end; ++e2) {
        int s = srcs[e2];
        float v = h[(size_t)s * DD + lane];
        aL += dinvs[e2] * v;
        aG += ews[e2] * v;
    }
    Tx1[node * DD + lane] = -dinv[node] * aL;
    agg[node * DD + lane] = aG;
}

// ---------- out = alpha * lap_mul(x) + beta * prev ----------
__global__ void k_lap(const int* __restrict__ offsets, const int* __restrict__ srcs,
                      const float* __restrict__ dinvs, const float* __restrict__ dinv,
                      const float* __restrict__ x, const float* __restrict__ prev,
                      float alpha, float beta, int n, float* __restrict__ out) {
    int w = threadIdx.x >> 6, lane = threadIdx.x & 63;
    int node = blockIdx.x * 4 + w;
    if (node >= n) return;
    int beg = offsets[node], end = offsets[node + 1];
    float a = 0.f;
    int e2 = beg;
    for (; e2 + 4 <= end; e2 += 4) {
        int s0 = srcs[e2], s1 = srcs[e2 + 1], s2 = srcs[e2 + 2], s3 = srcs[e2 + 3];
        float v0 = x[(size_t)s0 * DD + lane], v1 = x[(size_t)s1 * DD + lane];
        float v2 = x[(size_t)s2 * DD + lane], v3 = x[(size_t)s3 * DD + lane];
        float d0 = dinvs[e2], d1 = dinvs[e2 + 1], d2 = dinvs[e2 + 2], d3 = dinvs[e2 + 3];
        a += d0 * v0 + d1 * v1 + d2 * v2 + d3 * v3;
    }
    for (; e2 < end; ++e2) {
        a += dinvs[e2] * x[(size_t)srcs[e2] * DD + lane];
    }
    out[node * DD + lane] = alpha * (-dinv[node] * a) + beta * prev[node * DD + lane];
}

// ---------- QKV projections, 8 nodes per wave ----------
__global__ void k_qkv(const float* __restrict__ h, const float* __restrict__ p,
                      const float* __restrict__ WQ, const float* __restrict__ WK,
                      const float* __restrict__ WV, int n,
                      float* __restrict__ Qh, float* __restrict__ Kh, float* __restrict__ Vh) {
    __shared__ float hp[32][128];
    int base = blockIdx.x * 32;
    int t = threadIdx.x;
    for (int idx = t; idx < 4096; idx += 256) {
        int ni = idx >> 7, j = idx & 127;
        int node = base + ni;
        float v = 0.f;
        if (node < n) v = (j < 64) ? h[node * 64 + j] : p[node * 64 + (j - 64)];
        hp[ni][j] = v;
    }
    __syncthreads();
    int w = t >> 6, lane = t & 63;
    float q[8], k[8], v[8];
#pragma unroll
    for (int r = 0; r < 8; ++r) { q[r] = 0.f; k[r] = 0.f; v[r] = 0.f; }
    for (int i = 0; i < 128; ++i) {
        float wq = WQ[i * 64 + lane], wk = WK[i * 64 + lane], wv = WV[i * 64 + lane];
#pragma unroll
        for (int r = 0; r < 8; ++r) {
            float x = hp[w * 8 + r][i];
            q[r] += x * wq; k[r] += x * wk; v[r] += x * wv;
        }
    }
#pragma unroll
    for (int r = 0; r < 8; ++r) {
        int node = base + w * 8 + r;
        if (node < n) {
            Qh[node * 64 + lane] = q[r];
            Kh[node * 64 + lane] = k[r];
            Vh[node * 64 + lane] = v[r];
        }
    }
}

// ---------- per-edge scores: LDS-tiled GEMM (64 edges x 64 d per block),
// 4x4 micro-tile per thread, fused K*Q*Eh head-reduce epilogue ----------
__global__ __launch_bounds__(256) void k_score(
        const float* __restrict__ efeat, const float* __restrict__ WE,
        const int* __restrict__ src, const int* __restrict__ dst,
        const int* __restrict__ invp, const float* __restrict__ Qh,
        const float* __restrict__ Kh, int E, float* __restrict__ ssS) {
    __shared__ float sE[64 * 64];   // e-rows, 16B-slot XOR-swizzled by (row&7)
    __shared__ float sWE[64 * 64];  // [j][d] row-major (input layout)
    __shared__ int ssrc[64], sdst[64], swp[64];
    int t = threadIdx.x;
    int ebase = blockIdx.x * 64;

    for (int i = t; i < 4096; i += 256) sWE[i] = WE[i];
    if (t < 64) {
        int e = ebase + t;
        bool ok = e < E;
        ssrc[t] = ok ? src[e] : 0;
        sdst[t] = ok ? dst[e] : 0;
        swp[t] = ok ? invp[e] : 0;
    }
    {
        int er = t >> 2;   // edge row 0..63
        int jq = t & 3;
        int ge = ebase + er;
        const float4* grow = (const float4*)(efeat + (size_t)ge * 64);
        float4* srow = (float4*)(sE + er * 64);
        int sw = er & 7;
#pragma unroll
        for (int q = 0; q < 4; ++q) {
            int slot = jq + q * 4;
            float4 v = (ge < E) ? grow[slot] : make_float4(0.f, 0.f, 0.f, 0.f);
            srow[slot ^ sw] = v;
        }
    }
    __syncthreads();

    int k = t & 15;        // edge group: edges k, k+16, k+32, k+48
    int dg = t >> 4;       // d group 0..15, d = dg*4 .. dg*4+3
    int d0 = dg * 4;
    int sw = k & 7;        // (k+16i)&7 == k&7
    const float4* sE4 = (const float4*)sE;
    const float4* sW4 = (const float4*)sWE;

    float4 a0 = {0, 0, 0, 0}, a1 = {0, 0, 0, 0}, a2 = {0, 0, 0, 0}, a3 = {0, 0, 0, 0};

#pragma unroll
    for (int j4 = 0; j4 < 16; ++j4) {
        float4 w0 = sW4[(j4 * 4 + 0) * 16 + dg];
        float4 w1 = sW4[(j4 * 4 + 1) * 16 + dg];
        float4 w2 = sW4[(j4 * 4 + 2) * 16 + dg];
        float4 w3 = sW4[(j4 * 4 + 3) * 16 + dg];
        int slot = j4 ^ sw;
        float4 e0 = sE4[(k + 0) * 16 + slot];
        float4 e1 = sE4[(k + 16) * 16 + slot];
        float4 e2 = sE4[(k + 32) * 16 + slot];
        float4 e3 = sE4[(k + 48) * 16 + slot];
        a0.x += e0.x * w0.x + e0.y * w1.x + e0.z * w2.x + e0.w * w3.x;
        a0.y += e0.x * w0.y + e0.y * w1.y + e0.z * w2.y + e0.w * w3.y;
        a0.z += e0.x * w0.z + e0.y * w1.z + e0.z * w2.z + e0.w * w3.z;
        a0.w += e0.x * w0.w + e0.y * w1.w + e0.z * w2.w + e0.w * w3.w;
        a1.x += e1.x * w0.x + e1.y * w1.x + e1.z * w2.x + e1.w * w3.x;
        a1.y += e1.x * w0.y + e1.y * w1.y + e1.z * w2.y + e1.w * w3.y;
        a1.z += e1.x * w0.z + e1.y * w1.z + e1.z * w2.z + e1.w * w3.z;
        a1.w += e1.x * w0.w + e1.y * w1.w + e1.z * w2.w + e1.w * w3.w;
        a2.x += e2.x * w0.x + e2.y * w1.x + e2.z * w2.x + e2.w * w3.x;
        a2.y += e2.x * w0.y + e2.y * w1.y + e2.z * w2.y + e2.w * w3.y;
        a2.z += e2.x * w0.z + e2.y * w1.z + e2.z * w2.z + e2.w * w3.z;
        a2.w += e2.x * w0.w + e2.y * w1.w + e2.z * w2.w + e2.w * w3.w;
        a3.x += e3.x * w0.x + e3.y * w1.x + e3.z * w2.x + e3.w * w3.x;
        a3.y += e3.x * w0.y + e3.y * w1.y + e3.z * w2.y + e3.w * w3.y;
        a3.z += e3.x * w0.z + e3.y * w1.z + e3.z * w2.z + e3.w * w3.z;
        a3.w += e3.x * w0.w + e3.y * w1.w + e3.z * w2.w + e3.w * w3.w;
    }

    // epilogue: part_i = sum_c K[s_i][d0+c]*Q[t_i][d0+c]*Eh_i[c]
    const float invs = 0.35355339059327373f;  // 1/sqrt(8)
    float p0, p1, p2, p3;
    {
        int e = k;
        const float4 kv = *(const float4*)(Kh + (size_t)ssrc[e] * 64 + d0);
        const float4 qv = *(const float4*)(Qh + (size_t)sdst[e] * 64 + d0);
        p0 = kv.x * qv.x * a0.x + kv.y * qv.y * a0.y + kv.z * qv.z * a0.z + kv.w * qv.w * a0.w;
    }
    {
        int e = k + 16;
        const float4 kv = *(const float4*)(Kh + (size_t)ssrc[e] * 64 + d0);
        const float4 qv = *(const float4*)(Qh + (size_t)sdst[e] * 64 + d0);
        p1 = kv.x * qv.x * a1.x + kv.y * qv.y * a1.y + kv.z * qv.z * a1.z + kv.w * qv.w * a1.w;
    }
    {
        int e = k + 32;
        const float4 kv = *(const float4*)(Kh + (size_t)ssrc[e] * 64 + d0);
        const float4 qv = *(const float4*)(Qh + (size_t)sdst[e] * 64 + d0);
        p2 = kv.x * qv.x * a2.x + kv.y * qv.y * a2.y + kv.z * qv.z * a2.z + kv.w * qv.w * a2.w;
    }
    {
        int e = k + 48;
        const float4 kv = *(const float4*)(Kh + (size_t)ssrc[e] * 64 + d0);
        const float4 qv = *(const float4*)(Qh + (size_t)sdst[e] * 64 + d0);
        p3 = kv.x * qv.x * a3.x + kv.y * qv.y * a3.y + kv.z * qv.z * a3.z + kv.w * qv.w * a3.w;
    }
    // combine the two d-groups of each head (dg and dg^1 live in lanes l and l^16)
    p0 += __shfl_xor(p0, 16, 64);
    p1 += __shfl_xor(p1, 16, 64);
    p2 += __shfl_xor(p2, 16, 64);
    p3 += __shfl_xor(p3, 16, 64);
    if ((dg & 1) == 0) {
        int head = dg >> 1;
        float s0 = __expf(fminf(fmaxf(p0 * invs, -5.0f), 5.0f));
        float s1 = __expf(fminf(fmaxf(p1 * invs, -5.0f), 5.0f));
        float s2 = __expf(fminf(fmaxf(p2 * invs, -5.0f), 5.0f));
        float s3 = __expf(fminf(fmaxf(p3 * invs, -5.0f), 5.0f));
        if (ebase + k < E)      ssS[(size_t)swp[k] * HH + head] = s0;
        if (ebase + k + 16 < E) ssS[(size_t)swp[k + 16] * HH + head] = s1;
        if (ebase + k + 32 < E) ssS[(size_t)swp[k + 32] * HH + head] = s2;
        if (ebase + k + 48 < E) ssS[(size_t)swp[k + 48] * HH + head] = s3;
    }
}

// ---------- attention aggregation per node (ss already dst-sorted) ----------
__global__ void k_attn_agg(const int* __restrict__ offsets, const int* __restrict__ srcs,
                           const float* __restrict__ Vh, const float* __restrict__ ssS,
                           int n, float* __restrict__ out) {
    int w = threadIdx.x >> 6, lane = threadIdx.x & 63;
    int node = blockIdx.x * 4 + w;
    if (node >= n) return;
    int beg = offsets[node], end = offsets[node + 1];
    int hh = lane >> 3;
    float aV = 0.f, aZ = 0.f;
    int e2 = beg;
    for (; e2 + 4 <= end; e2 += 4) {
        int s0 = srcs[e2], s1 = srcs[e2 + 1], s2 = srcs[e2 + 2], s3 = srcs[e2 + 3];
        float v0 = Vh[(size_t)s0 * DD + lane], v1 = Vh[(size_t)s1 * DD + lane];
        float v2 = Vh[(size_t)s2 * DD + lane], v3 = Vh[(size_t)s3 * DD + lane];
        float sv0 = ssS[(size_t)e2 * HH + hh], sv1 = ssS[(size_t)(e2 + 1) * HH + hh];
        float sv2 = ssS[(size_t)(e2 + 2) * HH + hh], sv3 = ssS[(size_t)(e2 + 3) * HH + hh];
        aV += sv0 * v0 + sv1 * v1 + sv2 * v2 + sv3 * v3;
        aZ += sv0 + sv1 + sv2 + sv3;
    }
    for (; e2 < end; ++e2) {
        int s = srcs[e2];
        float sv = ssS[(size_t)e2 * HH + hh];
        aV += sv * Vh[(size_t)s * DD + lane];
        aZ += sv;
    }
    out[node * 192 + 128 + lane] = aV / (aZ + 1e-6f);
}

// ---------- output: cheb + gcn ----------
__global__ void k_out(const float* __restrict__ Tx0, const float* __restrict__ Tx1,
                      const float* __restrict__ Tx2, const float* __restrict__ Tx3,
                      const float* __restrict__ aggG, const float* __restrict__ fc,
                      const float* __restrict__ Wc, const float* __restrict__ bc,
                      const float* __restrict__ Wg, const float* __restrict__ bg,
                      int n, float* __restrict__ out) {
    __shared__ float sT[KORD][32][64];
    __shared__ float sA[32][64];
    int base = blockIdx.x * 32;
    int t = threadIdx.x;
    for (int idx = t; idx < 2048; idx += 256) {
        int ni = idx >> 6, j = idx & 63;
        int node = base + ni;
        if (node < n) {
            sT[0][ni][j] = fc[node] * Tx0[node * 64 + j];
            sT[1][ni][j] = fc[n + node] * Tx1[node * 64 + j];
            sT[2][ni][j] = fc[2 * n + node] * Tx2[node * 64 + j];
            sT[3][ni][j] = fc[3 * n + node] * Tx3[node * 64 + j];
            sA[ni][j] = aggG[node * 64 + j];
        } else {
            sT[0][ni][j] = 0.f; sT[1][ni][j] = 0.f;
            sT[2][ni][j] = 0.f; sT[3][ni][j] = 0.f;
            sA[ni][j] = 0.f;
        }
    }
    __syncthreads();
    int w = t >> 6, lane = t & 63;
    float acc[8];
#pragma unroll
    for (int i = 0; i < 8; ++i) acc[i] = 0.f;
#pragma unroll
    for (int k = 0; k < KORD; ++k) {
        for (int j = 0; j < 64; ++j) {
            float wv = Wc[k * 4096 + j * 64 + lane];
#pragma unroll
            for (int i = 0; i < 8; ++i) acc[i] += sT[k][w * 8 + i][j] * wv;
        }
    }
    float acc2[8];
#pragma unroll
    for (int i = 0; i < 8; ++i) acc2[i] = 0.f;
    for (int j = 0; j < 64; ++j) {
        float wv = Wg[j * 64 + lane];
#pragma unroll
        for (int i = 0; i < 8; ++i) acc2[i] += sA[w * 8 + i][j] * wv;
    }
    float bcv = bc[lane], bgv = bg[lane];
#pragma unroll
    for (int i = 0; i < 8; ++i) {
        int node = base + w * 8 + i;
        if (node < n) {
            out[node * 192 + lane] = acc[i] + bcv;
            out[node * 192 + 64 + lane] = acc2[i] + bgv;
        }
    }
}

extern "C" void kernel_launch(void* const* d_in, const int* in_sizes, int n_in,
                              void* d_out, int out_size, void* d_ws, size_t ws_size,
                              hipStream_t stream) {
    const float* h  = (const float*)d_in[0];
    const float* p  = (const float*)d_in[1];
    const float* ef = (const float*)d_in[2];
    const float* ew = (const float*)d_in[3];
    const float* fc = (const float*)d_in[4];
    const int* esrc = (const int*)d_in[5];
    const int* edst = (const int*)d_in[6];
    const float* Wc = (const float*)d_in[7];
    const float* bc = (const float*)d_in[8];
    const float* Wg = (const float*)d_in[9];
    const float* bg = (const float*)d_in[10];
    const float* WQ = (const float*)d_in[11];
    const float* WK = (const float*)d_in[12];
    const float* WV = (const float*)d_in[13];
    const float* WE = (const float*)d_in[14];

    const int n = in_sizes[0] / DD;   // 50000
    const int E = in_sizes[5];        // 800000
    float* out = (float*)d_out;

    char* wsp = (char*)d_ws;
    size_t o = 0;
    auto alloc = [&](size_t bytes) -> void* {
        void* r = (void*)(wsp + o);
        o = (o + bytes + 255) & ~(size_t)255;
        return r;
    };
    int* deg     = (int*)alloc((size_t)n * 4);
    int* offsets = (int*)alloc((size_t)(n + 1) * 4);
    int* cursor  = (int*)alloc((size_t)n * 4);
    int* invp    = (int*)alloc((size_t)E * 4);
    int* srcs    = (int*)alloc((size_t)E * 4);
    float* ews   = (float*)alloc((size_t)E * 4);
    float* dinvs = (float*)alloc((size_t)E * 4);
    int* bsum    = (int*)alloc(1024 * 4);
    float* dinv  = (float*)alloc((size_t)n * 4);
    float* Tx1   = (float*)alloc((size_t)n * DD * 4);
    float* Tx2   = (float*)alloc((size_t)n * DD * 4);
    float* Tx3   = (float*)alloc((size_t)n * DD * 4);
    float* agg   = (float*)alloc((size_t)n * DD * 4);
    float* Qh    = (float*)alloc((size_t)n * DD * 4);
    float* Kh    = (float*)alloc((size_t)n * DD * 4);
    float* Vh    = (float*)alloc((size_t)n * DD * 4);
    float* ssS   = (float*)alloc((size_t)E * HH * 4);
    (void)ws_size; (void)n_in; (void)out_size;

    hipMemsetAsync(deg, 0, (size_t)n * 4, stream);

    int nb = (n + 255) / 256;
    k_count<<<(E + 255) / 256, 256, 0, stream>>>(edst, E, deg);
    k_blocksum<<<nb, 256, 0, stream>>>(deg, n, bsum);
    k_scan_bsum<<<1, 256, 0, stream>>>(bsum, nb);
    k_scan_final<<<nb, 256, 0, stream>>>(deg, bsum, n, E, offsets, cursor, dinv);
    k_scatter<<<(E + 255) / 256, 256, 0, stream>>>(edst, esrc, ew, dinv, E, cursor,
                                                   invp, srcs, ews, dinvs);

    k_pass1<<<(n + 3) / 4, 256, 0, stream>>>(offsets, srcs, ews, dinvs, dinv, h, n, Tx1, agg);
    k_lap<<<(n + 3) / 4, 256, 0, stream>>>(offsets, srcs, dinvs, dinv, Tx1, h, 2.0f, -1.0f, n, Tx2);
    k_lap<<<(n + 3) / 4, 256, 0, stream>>>(offsets, srcs, dinvs, dinv, Tx2, Tx1, 2.0f, -1.0f, n, Tx3);

    k_qkv<<<(n + 31) / 32, 256, 0, stream>>>(h, p, WQ, WK, WV, n, Qh, Kh, Vh);

    k_score<<<(E + 63) / 64, 256, 0, stream>>>(ef, WE, esrc, edst, invp, Qh, Kh, E, ssS);
    k_attn_agg<<<(n + 3) / 4, 256, 0, stream>>>(offsets, srcs, Vh, ssS, n, out);

    k_out<<<(n + 31) / 32, 256, 0, stream>>>(h, Tx1, Tx2, Tx3, agg, fc, Wc, bc, Wg, bg, n, out);
}

// Round 6
// 605.773 us; speedup vs baseline: 1.4476x; 1.0417x over previous
//
#include <hip/hip_runtime.h>
#include <math.h>

#define DD 64
#define HH 8
#define KORD 4

// ---------- CSR build ----------
__global__ void k_count(const int* __restrict__ dst, int E, int* __restrict__ deg) {
    int i = blockIdx.x * 256 + threadIdx.x;
    if (i < E) atomicAdd(&deg[dst[i]], 1);
}

__global__ void k_blocksum(const int* __restrict__ deg, int n, int* __restrict__ bsum) {
    __shared__ int s[256];
    int i = blockIdx.x * 256 + threadIdx.x;
    s[threadIdx.x] = (i < n) ? deg[i] : 0;
    __syncthreads();
    for (int off = 128; off > 0; off >>= 1) {
        if (threadIdx.x < off) s[threadIdx.x] += s[threadIdx.x + off];
        __syncthreads();
    }
    if (threadIdx.x == 0) bsum[blockIdx.x] = s[0];
}

__global__ void k_scan_bsum(int* __restrict__ bsum, int nb) {
    __shared__ int s[256];
    int t = threadIdx.x;
    int v = (t < nb) ? bsum[t] : 0;
    s[t] = v;
    __syncthreads();
    for (int off = 1; off < 256; off <<= 1) {
        int tmp = (t >= off) ? s[t - off] : 0;
        __syncthreads();
        s[t] += tmp;
        __syncthreads();
    }
    if (t < nb) bsum[t] = s[t] - v;  // exclusive
}

__global__ void k_scan_final(const int* __restrict__ deg, const int* __restrict__ bsum,
                             int n, int E, int* __restrict__ offsets,
                             int* __restrict__ cursor, float* __restrict__ dinv) {
    __shared__ int s[256];
    int t = threadIdx.x, i = blockIdx.x * 256 + t;
    int v = (i < n) ? deg[i] : 0;
    s[t] = v;
    __syncthreads();
    for (int off = 1; off < 256; off <<= 1) {
        int tmp = (t >= off) ? s[t - off] : 0;
        __syncthreads();
        s[t] += tmp;
        __syncthreads();
    }
    if (i < n) {
        int excl = s[t] - v + bsum[blockIdx.x];
        offsets[i] = excl;
        cursor[i] = excl;
        int dv = v < 1 ? 1 : v;
        dinv[i] = 1.0f / sqrtf((float)dv);
    }
    if (i == 0) offsets[n] = E;
}

// scatter: dst-sorted edge arrays (src, dst, ew, dinv[src]) + forward perm
__global__ void k_scatter(const int* __restrict__ dst, const int* __restrict__ src,
                          const float* __restrict__ ew, const float* __restrict__ dinv,
                          int E, int* __restrict__ cursor, int* __restrict__ eperm,
                          int* __restrict__ srcs, int* __restrict__ dsts,
                          float* __restrict__ ews, float* __restrict__ dinvs) {
    int i = blockIdx.x * 256 + threadIdx.x;
    if (i < E) {
        int s = src[i], d = dst[i];
        int p = atomicAdd(&cursor[d], 1);
        eperm[p] = i;
        srcs[p] = s;
        dsts[p] = d;
        ews[p] = ew[i];
        dinvs[p] = dinv[s];
    }
}

// ---------- pass 1: Tx1 = lap_mul(h), agg = sum ew*h[src] ----------
__global__ void k_pass1(const int* __restrict__ offsets, const int* __restrict__ srcs,
                        const float* __restrict__ ews, const float* __restrict__ dinvs,
                        const float* __restrict__ dinv, const float* __restrict__ h,
                        int n, float* __restrict__ Tx1, float* __restrict__ agg) {
    int w = threadIdx.x >> 6, lane = threadIdx.x & 63;
    int node = blockIdx.x * 4 + w;
    if (node >= n) return;
    int beg = offsets[node], end = offsets[node + 1];
    float aL = 0.f, aG = 0.f;
    int e2 = beg;
    for (; e2 + 8 <= end; e2 += 8) {
#pragma unroll
        for (int u = 0; u < 8; ++u) {
            int s = srcs[e2 + u];
            float v = h[(size_t)s * DD + lane];
            aL = fmaf(dinvs[e2 + u], v, aL);
            aG = fmaf(ews[e2 + u], v, aG);
        }
    }
    for (; e2 < end; ++e2) {
        int s = srcs[e2];
        float v = h[(size_t)s * DD + lane];
        aL = fmaf(dinvs[e2], v, aL);
        aG = fmaf(ews[e2], v, aG);
    }
    Tx1[node * DD + lane] = -dinv[node] * aL;
    agg[node * DD + lane] = aG;
}

// ---------- out = alpha * lap_mul(x) + beta * prev ----------
__global__ void k_lap(const int* __restrict__ offsets, const int* __restrict__ srcs,
                      const float* __restrict__ dinvs, const float* __restrict__ dinv,
                      const float* __restrict__ x, const float* __restrict__ prev,
                      float alpha, float beta, int n, float* __restrict__ out) {
    int w = threadIdx.x >> 6, lane = threadIdx.x & 63;
    int node = blockIdx.x * 4 + w;
    if (node >= n) return;
    int beg = offsets[node], end = offsets[node + 1];
    float a = 0.f;
    int e2 = beg;
    for (; e2 + 8 <= end; e2 += 8) {
#pragma unroll
        for (int u = 0; u < 8; ++u) {
            a = fmaf(dinvs[e2 + u], x[(size_t)srcs[e2 + u] * DD + lane], a);
        }
    }
    for (; e2 < end; ++e2) {
        a = fmaf(dinvs[e2], x[(size_t)srcs[e2] * DD + lane], a);
    }
    out[node * DD + lane] = alpha * (-dinv[node] * a) + beta * prev[node * DD + lane];
}

// ---------- QKV projections, 8 nodes per wave ----------
__global__ void k_qkv(const float* __restrict__ h, const float* __restrict__ p,
                      const float* __restrict__ WQ, const float* __restrict__ WK,
                      const float* __restrict__ WV, int n,
                      float* __restrict__ Qh, float* __restrict__ Kh, float* __restrict__ Vh) {
    __shared__ float hp[32][128];
    int base = blockIdx.x * 32;
    int t = threadIdx.x;
    for (int idx = t; idx < 4096; idx += 256) {
        int ni = idx >> 7, j = idx & 127;
        int node = base + ni;
        float v = 0.f;
        if (node < n) v = (j < 64) ? h[node * 64 + j] : p[node * 64 + (j - 64)];
        hp[ni][j] = v;
    }
    __syncthreads();
    int w = t >> 6, lane = t & 63;
    float q[8], k[8], v[8];
#pragma unroll
    for (int r = 0; r < 8; ++r) { q[r] = 0.f; k[r] = 0.f; v[r] = 0.f; }
    for (int i = 0; i < 128; ++i) {
        float wq = WQ[i * 64 + lane], wk = WK[i * 64 + lane], wv = WV[i * 64 + lane];
#pragma unroll
        for (int r = 0; r < 8; ++r) {
            float x = hp[w * 8 + r][i];
            q[r] = fmaf(x, wq, q[r]); k[r] = fmaf(x, wk, k[r]); v[r] = fmaf(x, wv, v[r]);
        }
    }
#pragma unroll
    for (int r = 0; r < 8; ++r) {
        int node = base + w * 8 + r;
        if (node < n) {
            Qh[node * 64 + lane] = q[r];
            Kh[node * 64 + lane] = k[r];
            Vh[node * 64 + lane] = v[r];
        }
    }
}

// ---------- per-edge scores: persistent LDS-GEMM over dst-sorted edges ----------
#define ACC4(a, e)                                                     \
    a.x = fmaf(e.x, w0.x, a.x); a.x = fmaf(e.y, w1.x, a.x);            \
    a.x = fmaf(e.z, w2.x, a.x); a.x = fmaf(e.w, w3.x, a.x);            \
    a.y = fmaf(e.x, w0.y, a.y); a.y = fmaf(e.y, w1.y, a.y);            \
    a.y = fmaf(e.z, w2.y, a.y); a.y = fmaf(e.w, w3.y, a.y);            \
    a.z = fmaf(e.x, w0.z, a.z); a.z = fmaf(e.y, w1.z, a.z);            \
    a.z = fmaf(e.z, w2.z, a.z); a.z = fmaf(e.w, w3.z, a.z);            \
    a.w = fmaf(e.x, w0.w, a.w); a.w = fmaf(e.y, w1.w, a.w);            \
    a.w = fmaf(e.z, w2.w, a.w); a.w = fmaf(e.w, w3.w, a.w);

__global__ __launch_bounds__(256) void k_score(
        const float* __restrict__ efeat, const float* __restrict__ WE,
        const int* __restrict__ srcs, const int* __restrict__ dsts,
        const int* __restrict__ eperm, const float* __restrict__ Qh,
        const float* __restrict__ Kh, int E, int ntiles, float* __restrict__ ssS) {
    __shared__ float sE[64 * 64];   // e-rows (sorted order), 16B-slot XOR-swizzled
    __shared__ float sWE[64 * 64];  // [j][d] row-major, staged once
    __shared__ int ssrc[64], sdst[64];
    int t = threadIdx.x;
    for (int i = t; i < 4096; i += 256) sWE[i] = WE[i];

    int k = t & 15;        // edge group: edges k, k+16, k+32, k+48
    int dg = t >> 4;       // d group 0..15
    int d0 = dg * 4;
    int sw = k & 7;
    const float4* sE4 = (const float4*)sE;
    const float4* sW4 = (const float4*)sWE;
    const float invs = 0.35355339059327373f;  // 1/sqrt(8)

    int er = t >> 2, jq = t & 3, sw2 = er & 7;

    for (int tile = blockIdx.x; tile < ntiles; tile += gridDim.x) {
        int ebase = tile * 64;
        __syncthreads();  // WAR on sE (and first-iter sWE RAW is covered below)
        if (t < 64) {
            int e = ebase + t;
            bool ok = e < E;
            ssrc[t] = ok ? srcs[e] : 0;
            sdst[t] = ok ? dsts[e] : 0;
        }
        {
            int se = ebase + er;
            bool ok = se < E;
            int ge = ok ? eperm[se] : 0;
            const float4* grow = (const float4*)(efeat + (size_t)ge * 64);
            float4* srow = (float4*)(sE + er * 64);
#pragma unroll
            for (int q = 0; q < 4; ++q) {
                int slot = jq + q * 4;
                float4 v = ok ? grow[slot] : make_float4(0.f, 0.f, 0.f, 0.f);
                srow[slot ^ sw2] = v;
            }
        }
        __syncthreads();

        float4 a0 = {0, 0, 0, 0}, a1 = {0, 0, 0, 0}, a2 = {0, 0, 0, 0}, a3 = {0, 0, 0, 0};
#pragma unroll
        for (int j4 = 0; j4 < 16; ++j4) {
            float4 w0 = sW4[(j4 * 4 + 0) * 16 + dg];
            float4 w1 = sW4[(j4 * 4 + 1) * 16 + dg];
            float4 w2 = sW4[(j4 * 4 + 2) * 16 + dg];
            float4 w3 = sW4[(j4 * 4 + 3) * 16 + dg];
            int slot = j4 ^ sw;
            float4 e0 = sE4[(k + 0) * 16 + slot];
            float4 e1 = sE4[(k + 16) * 16 + slot];
            float4 e2 = sE4[(k + 32) * 16 + slot];
            float4 e3 = sE4[(k + 48) * 16 + slot];
            ACC4(a0, e0)
            ACC4(a1, e1)
            ACC4(a2, e2)
            ACC4(a3, e3)
        }

        float p0, p1, p2, p3;
        {
            const float4 kv = *(const float4*)(Kh + (size_t)ssrc[k] * 64 + d0);
            const float4 qv = *(const float4*)(Qh + (size_t)sdst[k] * 64 + d0);
            p0 = kv.x * qv.x * a0.x + kv.y * qv.y * a0.y + kv.z * qv.z * a0.z + kv.w * qv.w * a0.w;
        }
        {
            const float4 kv = *(const float4*)(Kh + (size_t)ssrc[k + 16] * 64 + d0);
            const float4 qv = *(const float4*)(Qh + (size_t)sdst[k + 16] * 64 + d0);
            p1 = kv.x * qv.x * a1.x + kv.y * qv.y * a1.y + kv.z * qv.z * a1.z + kv.w * qv.w * a1.w;
        }
        {
            const float4 kv = *(const float4*)(Kh + (size_t)ssrc[k + 32] * 64 + d0);
            const float4 qv = *(const float4*)(Qh + (size_t)sdst[k + 32] * 64 + d0);
            p2 = kv.x * qv.x * a2.x + kv.y * qv.y * a2.y + kv.z * qv.z * a2.z + kv.w * qv.w * a2.w;
        }
        {
            const float4 kv = *(const float4*)(Kh + (size_t)ssrc[k + 48] * 64 + d0);
            const float4 qv = *(const float4*)(Qh + (size_t)sdst[k + 48] * 64 + d0);
            p3 = kv.x * qv.x * a3.x + kv.y * qv.y * a3.y + kv.z * qv.z * a3.z + kv.w * qv.w * a3.w;
        }
        // combine the two d-groups of each head (dg and dg^1 in lanes l, l^16)
        p0 += __shfl_xor(p0, 16, 64);
        p1 += __shfl_xor(p1, 16, 64);
        p2 += __shfl_xor(p2, 16, 64);
        p3 += __shfl_xor(p3, 16, 64);
        if ((dg & 1) == 0) {
            int head = dg >> 1;
            float s0 = __expf(fminf(fmaxf(p0 * invs, -5.0f), 5.0f));
            float s1 = __expf(fminf(fmaxf(p1 * invs, -5.0f), 5.0f));
            float s2 = __expf(fminf(fmaxf(p2 * invs, -5.0f), 5.0f));
            float s3 = __expf(fminf(fmaxf(p3 * invs, -5.0f), 5.0f));
            if (ebase + k < E)      ssS[(size_t)(ebase + k) * HH + head] = s0;
            if (ebase + k + 16 < E) ssS[(size_t)(ebase + k + 16) * HH + head] = s1;
            if (ebase + k + 32 < E) ssS[(size_t)(ebase + k + 32) * HH + head] = s2;
            if (ebase + k + 48 < E) ssS[(size_t)(ebase + k + 48) * HH + head] = s3;
        }
    }
}

// ---------- attention aggregation per node (ss dst-sorted) ----------
__global__ void k_attn_agg(const int* __restrict__ offsets, const int* __restrict__ srcs,
                           const float* __restrict__ Vh, const float* __restrict__ ssS,
                           int n, float* __restrict__ out) {
    int w = threadIdx.x >> 6, lane = threadIdx.x & 63;
    int node = blockIdx.x * 4 + w;
    if (node >= n) return;
    int beg = offsets[node], end = offsets[node + 1];
    int hh = lane >> 3;
    float aV = 0.f, aZ = 0.f;
    int e2 = beg;
    for (; e2 + 8 <= end; e2 += 8) {
#pragma unroll
        for (int u = 0; u < 8; ++u) {
            int s = srcs[e2 + u];
            float sv = ssS[(size_t)(e2 + u) * HH + hh];
            aV = fmaf(sv, Vh[(size_t)s * DD + lane], aV);
            aZ += sv;
        }
    }
    for (; e2 < end; ++e2) {
        int s = srcs[e2];
        float sv = ssS[(size_t)e2 * HH + hh];
        aV = fmaf(sv, Vh[(size_t)s * DD + lane], aV);
        aZ += sv;
    }
    out[node * 192 + 128 + lane] = aV / (aZ + 1e-6f);
}

// ---------- output: cheb + gcn ----------
__global__ void k_out(const float* __restrict__ Tx0, const float* __restrict__ Tx1,
                      const float* __restrict__ Tx2, const float* __restrict__ Tx3,
                      const float* __restrict__ aggG, const float* __restrict__ fc,
                      const float* __restrict__ Wc, const float* __restrict__ bc,
                      const float* __restrict__ Wg, const float* __restrict__ bg,
                      int n, float* __restrict__ out) {
    __shared__ float sT[KORD][32][64];
    __shared__ float sA[32][64];
    int base = blockIdx.x * 32;
    int t = threadIdx.x;
    for (int idx = t; idx < 2048; idx += 256) {
        int ni = idx >> 6, j = idx & 63;
        int node = base + ni;
        if (node < n) {
            sT[0][ni][j] = fc[node] * Tx0[node * 64 + j];
            sT[1][ni][j] = fc[n + node] * Tx1[node * 64 + j];
            sT[2][ni][j] = fc[2 * n + node] * Tx2[node * 64 + j];
            sT[3][ni][j] = fc[3 * n + node] * Tx3[node * 64 + j];
            sA[ni][j] = aggG[node * 64 + j];
        } else {
            sT[0][ni][j] = 0.f; sT[1][ni][j] = 0.f;
            sT[2][ni][j] = 0.f; sT[3][ni][j] = 0.f;
            sA[ni][j] = 0.f;
        }
    }
    __syncthreads();
    int w = t >> 6, lane = t & 63;
    float acc[8];
#pragma unroll
    for (int i = 0; i < 8; ++i) acc[i] = 0.f;
#pragma unroll
    for (int k = 0; k < KORD; ++k) {
        for (int j = 0; j < 64; ++j) {
            float wv = Wc[k * 4096 + j * 64 + lane];
#pragma unroll
            for (int i = 0; i < 8; ++i) acc[i] = fmaf(sT[k][w * 8 + i][j], wv, acc[i]);
        }
    }
    float acc2[8];
#pragma unroll
    for (int i = 0; i < 8; ++i) acc2[i] = 0.f;
    for (int j = 0; j < 64; ++j) {
        float wv = Wg[j * 64 + lane];
#pragma unroll
        for (int i = 0; i < 8; ++i) acc2[i] = fmaf(sA[w * 8 + i][j], wv, acc2[i]);
    }
    float bcv = bc[lane], bgv = bg[lane];
#pragma unroll
    for (int i = 0; i < 8; ++i) {
        int node = base + w * 8 + i;
        if (node < n) {
            out[node * 192 + lane] = acc[i] + bcv;
            out[node * 192 + 64 + lane] = acc2[i] + bgv;
        }
    }
}

extern "C" void kernel_launch(void* const* d_in, const int* in_sizes, int n_in,
                              void* d_out, int out_size, void* d_ws, size_t ws_size,
                              hipStream_t stream) {
    const float* h  = (const float*)d_in[0];
    const float* p  = (const float*)d_in[1];
    const float* ef = (const float*)d_in[2];
    const float* ew = (const float*)d_in[3];
    const float* fc = (const float*)d_in[4];
    const int* esrc = (const int*)d_in[5];
    const int* edst = (const int*)d_in[6];
    const float* Wc = (const float*)d_in[7];
    const float* bc = (const float*)d_in[8];
    const float* Wg = (const float*)d_in[9];
    const float* bg = (const float*)d_in[10];
    const float* WQ = (const float*)d_in[11];
    const float* WK = (const float*)d_in[12];
    const float* WV = (const float*)d_in[13];
    const float* WE = (const float*)d_in[14];

    const int n = in_sizes[0] / DD;   // 50000
    const int E = in_sizes[5];        // 800000
    float* out = (float*)d_out;

    char* wsp = (char*)d_ws;
    size_t o = 0;
    auto alloc = [&](size_t bytes) -> void* {
        void* r = (void*)(wsp + o);
        o = (o + bytes + 255) & ~(size_t)255;
        return r;
    };
    int* deg     = (int*)alloc((size_t)n * 4);
    int* offsets = (int*)alloc((size_t)(n + 1) * 4);
    int* cursor  = (int*)alloc((size_t)n * 4);
    int* eperm   = (int*)alloc((size_t)E * 4);
    int* srcs    = (int*)alloc((size_t)E * 4);
    int* dsts    = (int*)alloc((size_t)E * 4);
    float* ews   = (float*)alloc((size_t)E * 4);
    float* dinvs = (float*)alloc((size_t)E * 4);
    int* bsum    = (int*)alloc(1024 * 4);
    float* dinv  = (float*)alloc((size_t)n * 4);
    float* Tx1   = (float*)alloc((size_t)n * DD * 4);
    float* Tx2   = (float*)alloc((size_t)n * DD * 4);
    float* Tx3   = (float*)alloc((size_t)n * DD * 4);
    float* agg   = (float*)alloc((size_t)n * DD * 4);
    float* Qh    = (float*)alloc((size_t)n * DD * 4);
    float* Kh    = (float*)alloc((size_t)n * DD * 4);
    float* Vh    = (float*)alloc((size_t)n * DD * 4);
    float* ssS   = (float*)alloc((size_t)E * HH * 4);
    (void)ws_size; (void)n_in; (void)out_size;

    hipMemsetAsync(deg, 0, (size_t)n * 4, stream);

    int nb = (n + 255) / 256;
    k_count<<<(E + 255) / 256, 256, 0, stream>>>(edst, E, deg);
    k_blocksum<<<nb, 256, 0, stream>>>(deg, n, bsum);
    k_scan_bsum<<<1, 256, 0, stream>>>(bsum, nb);
    k_scan_final<<<nb, 256, 0, stream>>>(deg, bsum, n, E, offsets, cursor, dinv);
    k_scatter<<<(E + 255) / 256, 256, 0, stream>>>(edst, esrc, ew, dinv, E, cursor,
                                                   eperm, srcs, dsts, ews, dinvs);

    k_pass1<<<(n + 3) / 4, 256, 0, stream>>>(offsets, srcs, ews, dinvs, dinv, h, n, Tx1, agg);
    k_lap<<<(n + 3) / 4, 256, 0, stream>>>(offsets, srcs, dinvs, dinv, Tx1, h, 2.0f, -1.0f, n, Tx2);
    k_lap<<<(n + 3) / 4, 256, 0, stream>>>(offsets, srcs, dinvs, dinv, Tx2, Tx1, 2.0f, -1.0f, n, Tx3);

    k_qkv<<<(n + 31) / 32, 256, 0, stream>>>(h, p, WQ, WK, WV, n, Qh, Kh, Vh);

    int ntiles = (E + 63) / 64;
    k_score<<<1024, 256, 0, stream>>>(ef, WE, srcs, dsts, eperm, Qh, Kh, E, ntiles, ssS);
    k_attn_agg<<<(n + 3) / 4, 256, 0, stream>>>(offsets, srcs, Vh, ssS, n, out);

    k_out<<<(n + 31) / 32, 256, 0, stream>>>(h, Tx1, Tx2, Tx3, agg, fc, Wc, bc, Wg, bg, n, out);
}

// Round 7
// 581.242 us; speedup vs baseline: 1.5087x; 1.0422x over previous
//
#include <hip/hip_runtime.h>
#include <math.h>

#define DD 64
#define HH 8
#define KORD 4

typedef __attribute__((ext_vector_type(8))) short bf16x8;
typedef __attribute__((ext_vector_type(4))) float f32x4;

__device__ __forceinline__ short f2bf(float f) {
    unsigned u = __builtin_bit_cast(unsigned, f);
    u = (u + 0x7fffu + ((u >> 16) & 1u)) >> 16;
    return (short)u;
}

// ---------- CSR build ----------
__global__ void k_count(const int* __restrict__ dst, int E, int* __restrict__ deg) {
    int i = blockIdx.x * 256 + threadIdx.x;
    if (i < E) atomicAdd(&deg[dst[i]], 1);
}

__global__ void k_blocksum(const int* __restrict__ deg, int n, int* __restrict__ bsum) {
    __shared__ int s[256];
    int i = blockIdx.x * 256 + threadIdx.x;
    s[threadIdx.x] = (i < n) ? deg[i] : 0;
    __syncthreads();
    for (int off = 128; off > 0; off >>= 1) {
        if (threadIdx.x < off) s[threadIdx.x] += s[threadIdx.x + off];
        __syncthreads();
    }
    if (threadIdx.x == 0) bsum[blockIdx.x] = s[0];
}

__global__ void k_scan_bsum(int* __restrict__ bsum, int nb) {
    __shared__ int s[256];
    int t = threadIdx.x;
    int v = (t < nb) ? bsum[t] : 0;
    s[t] = v;
    __syncthreads();
    for (int off = 1; off < 256; off <<= 1) {
        int tmp = (t >= off) ? s[t - off] : 0;
        __syncthreads();
        s[t] += tmp;
        __syncthreads();
    }
    if (t < nb) bsum[t] = s[t] - v;  // exclusive
}

__global__ void k_scan_final(const int* __restrict__ deg, const int* __restrict__ bsum,
                             int n, int E, int* __restrict__ offsets,
                             int* __restrict__ cursor, float* __restrict__ dinv) {
    __shared__ int s[256];
    int t = threadIdx.x, i = blockIdx.x * 256 + t;
    int v = (i < n) ? deg[i] : 0;
    s[t] = v;
    __syncthreads();
    for (int off = 1; off < 256; off <<= 1) {
        int tmp = (t >= off) ? s[t - off] : 0;
        __syncthreads();
        s[t] += tmp;
        __syncthreads();
    }
    if (i < n) {
        int excl = s[t] - v + bsum[blockIdx.x];
        offsets[i] = excl;
        cursor[i] = excl;
        int dv = v < 1 ? 1 : v;
        dinv[i] = 1.0f / sqrtf((float)dv);
    }
    if (i == 0) offsets[n] = E;
}

// scatter: dst-sorted edge arrays (src, dst, ew, dinv[src]) + forward perm
__global__ void k_scatter(const int* __restrict__ dst, const int* __restrict__ src,
                          const float* __restrict__ ew, const float* __restrict__ dinv,
                          int E, int* __restrict__ cursor, int* __restrict__ eperm,
                          int* __restrict__ srcs, int* __restrict__ dsts,
                          float* __restrict__ ews, float* __restrict__ dinvs) {
    int i = blockIdx.x * 256 + threadIdx.x;
    if (i < E) {
        int s = src[i], d = dst[i];
        int p = atomicAdd(&cursor[d], 1);
        eperm[p] = i;
        srcs[p] = s;
        dsts[p] = d;
        ews[p] = ew[i];
        dinvs[p] = dinv[s];
    }
}

// WE^T in bf16 with head-aligned column permutation:
// WETb[col][j] = bf16(WE[j][d(col)]), d(col) = ((q&7)<<3) + (q>>3) + (tc<<1)
__global__ void k_wetb(const float* __restrict__ WE, short* __restrict__ WETb) {
    int idx = blockIdx.x * 256 + threadIdx.x;
    if (idx < 4096) {
        int col = idx >> 6, j = idx & 63;
        int q = col & 15, tc = col >> 4;
        int d = ((q & 7) << 3) + (q >> 3) + (tc << 1);
        WETb[col * 64 + j] = f2bf(WE[j * 64 + d]);
    }
}

// ---------- pass 1: Tx1 = lap_mul(h), agg = sum ew*h[src] ----------
__global__ void k_pass1(const int* __restrict__ offsets, const int* __restrict__ srcs,
                        const float* __restrict__ ews, const float* __restrict__ dinvs,
                        const float* __restrict__ dinv, const float* __restrict__ h,
                        int n, float* __restrict__ Tx1, float* __restrict__ agg) {
    int w = threadIdx.x >> 6, lane = threadIdx.x & 63;
    int node = blockIdx.x * 4 + w;
    if (node >= n) return;
    int beg = offsets[node], end = offsets[node + 1];
    float aL = 0.f, aG = 0.f;
    int e2 = beg;
    for (; e2 + 8 <= end; e2 += 8) {
#pragma unroll
        for (int u = 0; u < 8; ++u) {
            int s = srcs[e2 + u];
            float v = h[(size_t)s * DD + lane];
            aL = fmaf(dinvs[e2 + u], v, aL);
            aG = fmaf(ews[e2 + u], v, aG);
        }
    }
    for (; e2 < end; ++e2) {
        int s = srcs[e2];
        float v = h[(size_t)s * DD + lane];
        aL = fmaf(dinvs[e2], v, aL);
        aG = fmaf(ews[e2], v, aG);
    }
    Tx1[node * DD + lane] = -dinv[node] * aL;
    agg[node * DD + lane] = aG;
}

// ---------- out = alpha * lap_mul(x) + beta * prev ----------
__global__ void k_lap(const int* __restrict__ offsets, const int* __restrict__ srcs,
                      const float* __restrict__ dinvs, const float* __restrict__ dinv,
                      const float* __restrict__ x, const float* __restrict__ prev,
                      float alpha, float beta, int n, float* __restrict__ out) {
    int w = threadIdx.x >> 6, lane = threadIdx.x & 63;
    int node = blockIdx.x * 4 + w;
    if (node >= n) return;
    int beg = offsets[node], end = offsets[node + 1];
    float a = 0.f;
    int e2 = beg;
    for (; e2 + 8 <= end; e2 += 8) {
#pragma unroll
        for (int u = 0; u < 8; ++u) {
            a = fmaf(dinvs[e2 + u], x[(size_t)srcs[e2 + u] * DD + lane], a);
        }
    }
    for (; e2 < end; ++e2) {
        a = fmaf(dinvs[e2], x[(size_t)srcs[e2] * DD + lane], a);
    }
    out[node * DD + lane] = alpha * (-dinv[node] * a) + beta * prev[node * DD + lane];
}

// ---------- QKV projections, 8 nodes per wave; K/Q stored column-permuted ----------
__global__ void k_qkv(const float* __restrict__ h, const float* __restrict__ p,
                      const float* __restrict__ WQ, const float* __restrict__ WK,
                      const float* __restrict__ WV, int n,
                      float* __restrict__ Qhp, float* __restrict__ Khp, float* __restrict__ Vh) {
    __shared__ float hp[32][128];
    int base = blockIdx.x * 32;
    int t = threadIdx.x;
    for (int idx = t; idx < 4096; idx += 256) {
        int ni = idx >> 7, j = idx & 127;
        int node = base + ni;
        float v = 0.f;
        if (node < n) v = (j < 64) ? h[node * 64 + j] : p[node * 64 + (j - 64)];
        hp[ni][j] = v;
    }
    __syncthreads();
    int w = t >> 6, lane = t & 63;
    // permuted column for K/Q: col' = tc*16 + q, tc=(d&6)>>1, q=(d>>3)|((d&1)<<3)
    int colp = (((lane & 6) >> 1) << 4) + ((lane >> 3) | ((lane & 1) << 3));
    float q[8], k[8], v[8];
#pragma unroll
    for (int r = 0; r < 8; ++r) { q[r] = 0.f; k[r] = 0.f; v[r] = 0.f; }
    for (int i = 0; i < 128; ++i) {
        float wq = WQ[i * 64 + lane], wk = WK[i * 64 + lane], wv = WV[i * 64 + lane];
#pragma unroll
        for (int r = 0; r < 8; ++r) {
            float x = hp[w * 8 + r][i];
            q[r] = fmaf(x, wq, q[r]); k[r] = fmaf(x, wk, k[r]); v[r] = fmaf(x, wv, v[r]);
        }
    }
#pragma unroll
    for (int r = 0; r < 8; ++r) {
        int node = base + w * 8 + r;
        if (node < n) {
            Qhp[node * 64 + colp] = q[r];
            Khp[node * 64 + colp] = k[r];
            Vh[node * 64 + lane] = v[r];
        }
    }
}

// ---------- per-edge scores: MFMA. One wave per 16 sorted edges.
// A = e-rows (f32->bf16 in-register), B = WETb fragments held in registers.
// C layout (verified): col = lane&15, row = (lane>>4)*4 + reg.
__global__ __launch_bounds__(256) void k_score(
        const float* __restrict__ efeat, const short* __restrict__ WETb,
        const int* __restrict__ srcs, const int* __restrict__ dsts,
        const int* __restrict__ eperm, const float* __restrict__ Qhp,
        const float* __restrict__ Khp, int E, float* __restrict__ ssS) {
    int lane = threadIdx.x & 63;
    int q = lane & 15, g = lane >> 4;

    // B-fragments: bfrag[kc][tc] = WE'[k = g*8 + kc*32 + i][col = tc*16 + q]
    bf16x8 bfrag[2][4];
#pragma unroll
    for (int kc = 0; kc < 2; ++kc)
#pragma unroll
        for (int tc = 0; tc < 4; ++tc)
            bfrag[kc][tc] = *(const bf16x8*)(WETb + (tc * 16 + q) * 64 + kc * 32 + g * 8);

    const float invs = 0.35355339059327373f;  // 1/sqrt(8)
    int nwaves = (gridDim.x * blockDim.x) >> 6;
    int wid = (blockIdx.x * blockDim.x + threadIdx.x) >> 6;
    int ntiles = (E + 15) >> 4;

    for (int wt = wid; wt < ntiles; wt += nwaves) {
        int ebase = wt * 16;
        int er = ebase + q;
        int erc = er < E ? er : E - 1;
        int row = eperm[erc];
        const float* ep = efeat + (size_t)row * 64;

        f32x4 acc0 = {0, 0, 0, 0}, acc1 = {0, 0, 0, 0};
        f32x4 acc2 = {0, 0, 0, 0}, acc3 = {0, 0, 0, 0};
#pragma unroll
        for (int kc = 0; kc < 2; ++kc) {
            const float4 f0 = *(const float4*)(ep + kc * 32 + g * 8);
            const float4 f1 = *(const float4*)(ep + kc * 32 + g * 8 + 4);
            bf16x8 a;
            a[0] = f2bf(f0.x); a[1] = f2bf(f0.y); a[2] = f2bf(f0.z); a[3] = f2bf(f0.w);
            a[4] = f2bf(f1.x); a[5] = f2bf(f1.y); a[6] = f2bf(f1.z); a[7] = f2bf(f1.w);
            acc0 = __builtin_amdgcn_mfma_f32_16x16x32_bf16(a, bfrag[kc][0], acc0, 0, 0, 0);
            acc1 = __builtin_amdgcn_mfma_f32_16x16x32_bf16(a, bfrag[kc][1], acc1, 0, 0, 0);
            acc2 = __builtin_amdgcn_mfma_f32_16x16x32_bf16(a, bfrag[kc][2], acc2, 0, 0, 0);
            acc3 = __builtin_amdgcn_mfma_f32_16x16x32_bf16(a, bfrag[kc][3], acc3, 0, 0, 0);
        }

#pragma unroll
        for (int r = 0; r < 4; ++r) {
            int R = g * 4 + r;
            int e = ebase + R;
            int ec = e < E ? e : E - 1;
            int s_ = srcs[ec], t_ = dsts[ec];
            const float* Kp = Khp + (size_t)s_ * 64 + q;
            const float* Qp = Qhp + (size_t)t_ * 64 + q;
            float pv = Kp[0] * Qp[0] * acc0[r]
                     + Kp[16] * Qp[16] * acc1[r]
                     + Kp[32] * Qp[32] * acc2[r]
                     + Kp[48] * Qp[48] * acc3[r];
            pv *= invs;
            pv += __shfl_xor(pv, 8, 64);
            float sc = __expf(fminf(fmaxf(pv, -5.0f), 5.0f));
            if ((lane & 8) == 0 && e < E) ssS[(size_t)e * HH + (q & 7)] = sc;
        }
    }
}

// ---------- attention aggregation per node (ss dst-sorted) ----------
__global__ void k_attn_agg(const int* __restrict__ offsets, const int* __restrict__ srcs,
                           const float* __restrict__ Vh, const float* __restrict__ ssS,
                           int n, float* __restrict__ out) {
    int w = threadIdx.x >> 6, lane = threadIdx.x & 63;
    int node = blockIdx.x * 4 + w;
    if (node >= n) return;
    int beg = offsets[node], end = offsets[node + 1];
    int hh = lane >> 3;
    float aV = 0.f, aZ = 0.f;
    int e2 = beg;
    for (; e2 + 8 <= end; e2 += 8) {
#pragma unroll
        for (int u = 0; u < 8; ++u) {
            int s = srcs[e2 + u];
            float sv = ssS[(size_t)(e2 + u) * HH + hh];
            aV = fmaf(sv, Vh[(size_t)s * DD + lane], aV);
            aZ += sv;
        }
    }
    for (; e2 < end; ++e2) {
        int s = srcs[e2];
        float sv = ssS[(size_t)e2 * HH + hh];
        aV = fmaf(sv, Vh[(size_t)s * DD + lane], aV);
        aZ += sv;
    }
    out[node * 192 + 128 + lane] = aV / (aZ + 1e-6f);
}

// ---------- output: cheb + gcn ----------
__global__ void k_out(const float* __restrict__ Tx0, const float* __restrict__ Tx1,
                      const float* __restrict__ Tx2, const float* __restrict__ Tx3,
                      const float* __restrict__ aggG, const float* __restrict__ fc,
                      const float* __restrict__ Wc, const float* __restrict__ bc,
                      const float* __restrict__ Wg, const float* __restrict__ bg,
                      int n, float* __restrict__ out) {
    __shared__ float sT[KORD][32][64];
    __shared__ float sA[32][64];
    int base = blockIdx.x * 32;
    int t = threadIdx.x;
    for (int idx = t; idx < 2048; idx += 256) {
        int ni = idx >> 6, j = idx & 63;
        int node = base + ni;
        if (node < n) {
            sT[0][ni][j] = fc[node] * Tx0[node * 64 + j];
            sT[1][ni][j] = fc[n + node] * Tx1[node * 64 + j];
            sT[2][ni][j] = fc[2 * n + node] * Tx2[node * 64 + j];
            sT[3][ni][j] = fc[3 * n + node] * Tx3[node * 64 + j];
            sA[ni][j] = aggG[node * 64 + j];
        } else {
            sT[0][ni][j] = 0.f; sT[1][ni][j] = 0.f;
            sT[2][ni][j] = 0.f; sT[3][ni][j] = 0.f;
            sA[ni][j] = 0.f;
        }
    }
    __syncthreads();
    int w = t >> 6, lane = t & 63;
    float acc[8];
#pragma unroll
    for (int i = 0; i < 8; ++i) acc[i] = 0.f;
#pragma unroll
    for (int k = 0; k < KORD; ++k) {
        for (int j = 0; j < 64; ++j) {
            float wv = Wc[k * 4096 + j * 64 + lane];
#pragma unroll
            for (int i = 0; i < 8; ++i) acc[i] = fmaf(sT[k][w * 8 + i][j], wv, acc[i]);
        }
    }
    float acc2[8];
#pragma unroll
    for (int i = 0; i < 8; ++i) acc2[i] = 0.f;
    for (int j = 0; j < 64; ++j) {
        float wv = Wg[j * 64 + lane];
#pragma unroll
        for (int i = 0; i < 8; ++i) acc2[i] = fmaf(sA[w * 8 + i][j], wv, acc2[i]);
    }
    float bcv = bc[lane], bgv = bg[lane];
#pragma unroll
    for (int i = 0; i < 8; ++i) {
        int node = base + w * 8 + i;
        if (node < n) {
            out[node * 192 + lane] = acc[i] + bcv;
            out[node * 192 + 64 + lane] = acc2[i] + bgv;
        }
    }
}

extern "C" void kernel_launch(void* const* d_in, const int* in_sizes, int n_in,
                              void* d_out, int out_size, void* d_ws, size_t ws_size,
                              hipStream_t stream) {
    const float* h  = (const float*)d_in[0];
    const float* p  = (const float*)d_in[1];
    const float* ef = (const float*)d_in[2];
    const float* ew = (const float*)d_in[3];
    const float* fc = (const float*)d_in[4];
    const int* esrc = (const int*)d_in[5];
    const int* edst = (const int*)d_in[6];
    const float* Wc = (const float*)d_in[7];
    const float* bc = (const float*)d_in[8];
    const float* Wg = (const float*)d_in[9];
    const float* bg = (const float*)d_in[10];
    const float* WQ = (const float*)d_in[11];
    const float* WK = (const float*)d_in[12];
    const float* WV = (const float*)d_in[13];
    const float* WE = (const float*)d_in[14];

    const int n = in_sizes[0] / DD;   // 50000
    const int E = in_sizes[5];        // 800000
    float* out = (float*)d_out;

    char* wsp = (char*)d_ws;
    size_t o = 0;
    auto alloc = [&](size_t bytes) -> void* {
        void* r = (void*)(wsp + o);
        o = (o + bytes + 255) & ~(size_t)255;
        return r;
    };
    int* deg     = (int*)alloc((size_t)n * 4);
    int* offsets = (int*)alloc((size_t)(n + 1) * 4);
    int* cursor  = (int*)alloc((size_t)n * 4);
    int* eperm   = (int*)alloc((size_t)E * 4);
    int* srcs    = (int*)alloc((size_t)E * 4);
    int* dsts    = (int*)alloc((size_t)E * 4);
    float* ews   = (float*)alloc((size_t)E * 4);
    float* dinvs = (float*)alloc((size_t)E * 4);
    int* bsum    = (int*)alloc(1024 * 4);
    float* dinv  = (float*)alloc((size_t)n * 4);
    short* WETb  = (short*)alloc(4096 * 2);
    float* Tx1   = (float*)alloc((size_t)n * DD * 4);
    float* Tx2   = (float*)alloc((size_t)n * DD * 4);
    float* Tx3   = (float*)alloc((size_t)n * DD * 4);
    float* agg   = (float*)alloc((size_t)n * DD * 4);
    float* Qhp   = (float*)alloc((size_t)n * DD * 4);
    float* Khp   = (float*)alloc((size_t)n * DD * 4);
    float* Vh    = (float*)alloc((size_t)n * DD * 4);
    float* ssS   = (float*)alloc((size_t)E * HH * 4);
    (void)ws_size; (void)n_in; (void)out_size;

    hipMemsetAsync(deg, 0, (size_t)n * 4, stream);

    int nb = (n + 255) / 256;
    k_count<<<(E + 255) / 256, 256, 0, stream>>>(edst, E, deg);
    k_blocksum<<<nb, 256, 0, stream>>>(deg, n, bsum);
    k_scan_bsum<<<1, 256, 0, stream>>>(bsum, nb);
    k_scan_final<<<nb, 256, 0, stream>>>(deg, bsum, n, E, offsets, cursor, dinv);
    k_scatter<<<(E + 255) / 256, 256, 0, stream>>>(edst, esrc, ew, dinv, E, cursor,
                                                   eperm, srcs, dsts, ews, dinvs);
    k_wetb<<<16, 256, 0, stream>>>(WE, WETb);

    k_pass1<<<(n + 3) / 4, 256, 0, stream>>>(offsets, srcs, ews, dinvs, dinv, h, n, Tx1, agg);
    k_lap<<<(n + 3) / 4, 256, 0, stream>>>(offsets, srcs, dinvs, dinv, Tx1, h, 2.0f, -1.0f, n, Tx2);
    k_lap<<<(n + 3) / 4, 256, 0, stream>>>(offsets, srcs, dinvs, dinv, Tx2, Tx1, 2.0f, -1.0f, n, Tx3);

    k_qkv<<<(n + 31) / 32, 256, 0, stream>>>(h, p, WQ, WK, WV, n, Qhp, Khp, Vh);

    k_score<<<2048, 256, 0, stream>>>(ef, WETb, srcs, dsts, eperm, Qhp, Khp, E, ssS);
    k_attn_agg<<<(n + 3) / 4, 256, 0, stream>>>(offsets, srcs, Vh, ssS, n, out);

    k_out<<<(n + 31) / 32, 256, 0, stream>>>(h, Tx1, Tx2, Tx3, agg, fc, Wc, bc, Wg, bg, n, out);
}

// Round 8
// 548.456 us; speedup vs baseline: 1.5989x; 1.0598x over previous
//
#include <hip/hip_runtime.h>
#include <math.h>

#define DD 64
#define HH 8
#define KORD 4

typedef __attribute__((ext_vector_type(8))) short bf16x8;
typedef __attribute__((ext_vector_type(4))) float f32x4;

__device__ __forceinline__ short f2bf(float f) {
    unsigned u = __builtin_bit_cast(unsigned, f);
    u = (u + 0x7fffu + ((u >> 16) & 1u)) >> 16;
    return (short)u;
}
__device__ __forceinline__ float bf2f(unsigned short u) {
    unsigned x = ((unsigned)u) << 16;
    return __builtin_bit_cast(float, x);
}

// ---------- CSR build ----------
__global__ void k_count(const int* __restrict__ dst, int E, int* __restrict__ deg) {
    int i = blockIdx.x * 256 + threadIdx.x;
    if (i < E) atomicAdd(&deg[dst[i]], 1);
}

__global__ void k_blocksum(const int* __restrict__ deg, int n, int* __restrict__ bsum) {
    __shared__ int s[256];
    int i = blockIdx.x * 256 + threadIdx.x;
    s[threadIdx.x] = (i < n) ? deg[i] : 0;
    __syncthreads();
    for (int off = 128; off > 0; off >>= 1) {
        if (threadIdx.x < off) s[threadIdx.x] += s[threadIdx.x + off];
        __syncthreads();
    }
    if (threadIdx.x == 0) bsum[blockIdx.x] = s[0];
}

__global__ void k_scan_bsum(int* __restrict__ bsum, int nb) {
    __shared__ int s[256];
    int t = threadIdx.x;
    int v = (t < nb) ? bsum[t] : 0;
    s[t] = v;
    __syncthreads();
    for (int off = 1; off < 256; off <<= 1) {
        int tmp = (t >= off) ? s[t - off] : 0;
        __syncthreads();
        s[t] += tmp;
        __syncthreads();
    }
    if (t < nb) bsum[t] = s[t] - v;  // exclusive
}

__global__ void k_scan_final(const int* __restrict__ deg, const int* __restrict__ bsum,
                             int n, int E, int* __restrict__ offsets,
                             int* __restrict__ cursor, float* __restrict__ dinv) {
    __shared__ int s[256];
    int t = threadIdx.x, i = blockIdx.x * 256 + t;
    int v = (i < n) ? deg[i] : 0;
    s[t] = v;
    __syncthreads();
    for (int off = 1; off < 256; off <<= 1) {
        int tmp = (t >= off) ? s[t - off] : 0;
        __syncthreads();
        s[t] += tmp;
        __syncthreads();
    }
    if (i < n) {
        int excl = s[t] - v + bsum[blockIdx.x];
        offsets[i] = excl;
        cursor[i] = excl;
        int dv = v < 1 ? 1 : v;
        dinv[i] = 1.0f / sqrtf((float)dv);
    }
    if (i == 0) offsets[n] = E;
}

// scatter: dst-sorted edge arrays (src, ew, dinv[src]) + inverse permutation
__global__ void k_scatter(const int* __restrict__ dst, const int* __restrict__ src,
                          const float* __restrict__ ew, const float* __restrict__ dinv,
                          int E, int* __restrict__ cursor, int* __restrict__ invp,
                          int* __restrict__ srcs, float* __restrict__ ews,
                          float* __restrict__ dinvs) {
    int i = blockIdx.x * 256 + threadIdx.x;
    if (i < E) {
        int s = src[i];
        int p = atomicAdd(&cursor[dst[i]], 1);
        invp[i] = p;
        srcs[p] = s;
        ews[p] = ew[i];
        dinvs[p] = dinv[s];
    }
}

// h -> bf16 copy
__global__ void k_hb(const float* __restrict__ h, unsigned short* __restrict__ hb, int m) {
    int i = blockIdx.x * 256 + threadIdx.x;
    if (i < m) hb[i] = (unsigned short)f2bf(h[i]);
}

// WE^T in bf16 with head-aligned column permutation:
// WETb[col][j] = bf16(WE[j][d(col)]), d(col) = ((q&7)<<3) + (q>>3) + (tc<<1)
__global__ void k_wetb(const float* __restrict__ WE, short* __restrict__ WETb) {
    int idx = blockIdx.x * 256 + threadIdx.x;
    if (idx < 4096) {
        int col = idx >> 6, j = idx & 63;
        int q = col & 15, tc = col >> 4;
        int d = ((q & 7) << 3) + (q >> 3) + (tc << 1);
        WETb[col * 64 + j] = f2bf(WE[j * 64 + d]);
    }
}

// ---------- pass 1: Tx1 = lap_mul(h), agg = sum ew*h[src]  (bf16 gathers) ----------
__global__ void k_pass1(const int* __restrict__ offsets, const int* __restrict__ srcs,
                        const float* __restrict__ ews, const float* __restrict__ dinvs,
                        const float* __restrict__ dinv, const unsigned short* __restrict__ hb,
                        int n, unsigned short* __restrict__ Tx1b,
                        unsigned short* __restrict__ aggb) {
    int w = threadIdx.x >> 6, lane = threadIdx.x & 63;
    int node = blockIdx.x * 4 + w;
    if (node >= n) return;
    int beg = offsets[node], end = offsets[node + 1];
    float aL = 0.f, aG = 0.f;
    int e2 = beg;
    for (; e2 + 8 <= end; e2 += 8) {
#pragma unroll
        for (int u = 0; u < 8; ++u) {
            int s = srcs[e2 + u];
            float v = bf2f(hb[(size_t)s * DD + lane]);
            aL = fmaf(dinvs[e2 + u], v, aL);
            aG = fmaf(ews[e2 + u], v, aG);
        }
    }
    for (; e2 < end; ++e2) {
        int s = srcs[e2];
        float v = bf2f(hb[(size_t)s * DD + lane]);
        aL = fmaf(dinvs[e2], v, aL);
        aG = fmaf(ews[e2], v, aG);
    }
    Tx1b[node * DD + lane] = (unsigned short)f2bf(-dinv[node] * aL);
    aggb[node * DD + lane] = (unsigned short)f2bf(aG);
}

// ---------- out = alpha * lap_mul(x) + beta * prev  (bf16 tables) ----------
__global__ void k_lap(const int* __restrict__ offsets, const int* __restrict__ srcs,
                      const float* __restrict__ dinvs, const float* __restrict__ dinv,
                      const unsigned short* __restrict__ x, const unsigned short* __restrict__ prev,
                      float alpha, float beta, int n, unsigned short* __restrict__ out) {
    int w = threadIdx.x >> 6, lane = threadIdx.x & 63;
    int node = blockIdx.x * 4 + w;
    if (node >= n) return;
    int beg = offsets[node], end = offsets[node + 1];
    float a = 0.f;
    int e2 = beg;
    for (; e2 + 8 <= end; e2 += 8) {
#pragma unroll
        for (int u = 0; u < 8; ++u) {
            a = fmaf(dinvs[e2 + u], bf2f(x[(size_t)srcs[e2 + u] * DD + lane]), a);
        }
    }
    for (; e2 < end; ++e2) {
        a = fmaf(dinvs[e2], bf2f(x[(size_t)srcs[e2] * DD + lane]), a);
    }
    float v = alpha * (-dinv[node] * a) + beta * bf2f(prev[node * DD + lane]);
    out[node * DD + lane] = (unsigned short)f2bf(v);
}

// ---------- QKV projections, 8 nodes per wave; K/Q stored column-permuted; V bf16 ----------
__global__ void k_qkv(const float* __restrict__ h, const float* __restrict__ p,
                      const float* __restrict__ WQ, const float* __restrict__ WK,
                      const float* __restrict__ WV, int n,
                      float* __restrict__ Qhp, float* __restrict__ Khp,
                      unsigned short* __restrict__ Vhb) {
    __shared__ float hp[32][128];
    int base = blockIdx.x * 32;
    int t = threadIdx.x;
    for (int idx = t; idx < 4096; idx += 256) {
        int ni = idx >> 7, j = idx & 127;
        int node = base + ni;
        float v = 0.f;
        if (node < n) v = (j < 64) ? h[node * 64 + j] : p[node * 64 + (j - 64)];
        hp[ni][j] = v;
    }
    __syncthreads();
    int w = t >> 6, lane = t & 63;
    // permuted column for K/Q: col' = tc*16 + q, tc=(d&6)>>1, q=(d>>3)|((d&1)<<3)
    int colp = (((lane & 6) >> 1) << 4) + ((lane >> 3) | ((lane & 1) << 3));
    float q[8], k[8], v[8];
#pragma unroll
    for (int r = 0; r < 8; ++r) { q[r] = 0.f; k[r] = 0.f; v[r] = 0.f; }
    for (int i = 0; i < 128; ++i) {
        float wq = WQ[i * 64 + lane], wk = WK[i * 64 + lane], wv = WV[i * 64 + lane];
#pragma unroll
        for (int r = 0; r < 8; ++r) {
            float x = hp[w * 8 + r][i];
            q[r] = fmaf(x, wq, q[r]); k[r] = fmaf(x, wk, k[r]); v[r] = fmaf(x, wv, v[r]);
        }
    }
#pragma unroll
    for (int r = 0; r < 8; ++r) {
        int node = base + w * 8 + r;
        if (node < n) {
            Qhp[node * 64 + colp] = q[r];
            Khp[node * 64 + colp] = k[r];
            Vhb[node * 64 + lane] = (unsigned short)f2bf(v[r]);
        }
    }
}

// ---------- per-edge scores: MFMA over ORIGINAL-order edges (coalesced e-stream).
// A = e-rows (f32->bf16 in-register), B = WETb fragments in registers.
// C layout (verified): col = lane&15, row = (lane>>4)*4 + reg. ss scattered via invp.
__global__ __launch_bounds__(256) void k_score(
        const float* __restrict__ efeat, const short* __restrict__ WETb,
        const int* __restrict__ src, const int* __restrict__ dst,
        const int* __restrict__ invp, const float* __restrict__ Qhp,
        const float* __restrict__ Khp, int E, float* __restrict__ ssS) {
    int lane = threadIdx.x & 63;
    int q = lane & 15, g = lane >> 4;

    // B-fragments: bfrag[kc][tc] = WE'[k = g*8 + kc*32 + i][col = tc*16 + q]
    bf16x8 bfrag[2][4];
#pragma unroll
    for (int kc = 0; kc < 2; ++kc)
#pragma unroll
        for (int tc = 0; tc < 4; ++tc)
            bfrag[kc][tc] = *(const bf16x8*)(WETb + (tc * 16 + q) * 64 + kc * 32 + g * 8);

    const float invs = 0.35355339059327373f;  // 1/sqrt(8)
    int nwaves = (gridDim.x * blockDim.x) >> 6;
    int wid = (blockIdx.x * blockDim.x + threadIdx.x) >> 6;
    int ntiles = (E + 15) >> 4;

    for (int wt = wid; wt < ntiles; wt += nwaves) {
        int ebase = wt * 16;
        int er = ebase + q;
        int erc = er < E ? er : E - 1;
        const float* ep = efeat + (size_t)erc * 64;

        f32x4 acc0 = {0, 0, 0, 0}, acc1 = {0, 0, 0, 0};
        f32x4 acc2 = {0, 0, 0, 0}, acc3 = {0, 0, 0, 0};
#pragma unroll
        for (int kc = 0; kc < 2; ++kc) {
            const float4 f0 = *(const float4*)(ep + kc * 32 + g * 8);
            const float4 f1 = *(const float4*)(ep + kc * 32 + g * 8 + 4);
            bf16x8 a;
            a[0] = f2bf(f0.x); a[1] = f2bf(f0.y); a[2] = f2bf(f0.z); a[3] = f2bf(f0.w);
            a[4] = f2bf(f1.x); a[5] = f2bf(f1.y); a[6] = f2bf(f1.z); a[7] = f2bf(f1.w);
            acc0 = __builtin_amdgcn_mfma_f32_16x16x32_bf16(a, bfrag[kc][0], acc0, 0, 0, 0);
            acc1 = __builtin_amdgcn_mfma_f32_16x16x32_bf16(a, bfrag[kc][1], acc1, 0, 0, 0);
            acc2 = __builtin_amdgcn_mfma_f32_16x16x32_bf16(a, bfrag[kc][2], acc2, 0, 0, 0);
            acc3 = __builtin_amdgcn_mfma_f32_16x16x32_bf16(a, bfrag[kc][3], acc3, 0, 0, 0);
        }

#pragma unroll
        for (int r = 0; r < 4; ++r) {
            int R = g * 4 + r;
            int e = ebase + R;
            int ec = e < E ? e : E - 1;
            int s_ = src[ec], t_ = dst[ec];
            const float* Kp = Khp + (size_t)s_ * 64 + q;
            const float* Qp = Qhp + (size_t)t_ * 64 + q;
            float pv = Kp[0] * Qp[0] * acc0[r]
                     + Kp[16] * Qp[16] * acc1[r]
                     + Kp[32] * Qp[32] * acc2[r]
                     + Kp[48] * Qp[48] * acc3[r];
            pv *= invs;
            pv += __shfl_xor(pv, 8, 64);
            float sc = __expf(fminf(fmaxf(pv, -5.0f), 5.0f));
            if ((lane & 8) == 0 && e < E) {
                int wp = invp[ec];
                ssS[(size_t)wp * HH + (q & 7)] = sc;
            }
        }
    }
}

// ---------- attention aggregation per node (ss dst-sorted, V bf16) ----------
__global__ void k_attn_agg(const int* __restrict__ offsets, const int* __restrict__ srcs,
                           const unsigned short* __restrict__ Vhb, const float* __restrict__ ssS,
                           int n, float* __restrict__ out) {
    int w = threadIdx.x >> 6, lane = threadIdx.x & 63;
    int node = blockIdx.x * 4 + w;
    if (node >= n) return;
    int beg = offsets[node], end = offsets[node + 1];
    int hh = lane >> 3;
    float aV = 0.f, aZ = 0.f;
    int e2 = beg;
    for (; e2 + 8 <= end; e2 += 8) {
#pragma unroll
        for (int u = 0; u < 8; ++u) {
            int s = srcs[e2 + u];
            float sv = ssS[(size_t)(e2 + u) * HH + hh];
            aV = fmaf(sv, bf2f(Vhb[(size_t)s * DD + lane]), aV);
            aZ += sv;
        }
    }
    for (; e2 < end; ++e2) {
        int s = srcs[e2];
        float sv = ssS[(size_t)e2 * HH + hh];
        aV = fmaf(sv, bf2f(Vhb[(size_t)s * DD + lane]), aV);
        aZ += sv;
    }
    out[node * 192 + 128 + lane] = aV / (aZ + 1e-6f);
}

// ---------- output: cheb + gcn (Tx tables bf16, Tx0 = h f32) ----------
__global__ void k_out(const float* __restrict__ h, const unsigned short* __restrict__ Tx1b,
                      const unsigned short* __restrict__ Tx2b, const unsigned short* __restrict__ Tx3b,
                      const unsigned short* __restrict__ aggb, const float* __restrict__ fc,
                      const float* __restrict__ Wc, const float* __restrict__ bc,
                      const float* __restrict__ Wg, const float* __restrict__ bg,
                      int n, float* __restrict__ out) {
    __shared__ float sT[KORD][32][64];
    __shared__ float sA[32][64];
    int base = blockIdx.x * 32;
    int t = threadIdx.x;
    for (int idx = t; idx < 2048; idx += 256) {
        int ni = idx >> 6, j = idx & 63;
        int node = base + ni;
        if (node < n) {
            sT[0][ni][j] = fc[node] * h[node * 64 + j];
            sT[1][ni][j] = fc[n + node] * bf2f(Tx1b[node * 64 + j]);
            sT[2][ni][j] = fc[2 * n + node] * bf2f(Tx2b[node * 64 + j]);
            sT[3][ni][j] = fc[3 * n + node] * bf2f(Tx3b[node * 64 + j]);
            sA[ni][j] = bf2f(aggb[node * 64 + j]);
        } else {
            sT[0][ni][j] = 0.f; sT[1][ni][j] = 0.f;
            sT[2][ni][j] = 0.f; sT[3][ni][j] = 0.f;
            sA[ni][j] = 0.f;
        }
    }
    __syncthreads();
    int w = t >> 6, lane = t & 63;
    float acc[8];
#pragma unroll
    for (int i = 0; i < 8; ++i) acc[i] = 0.f;
#pragma unroll
    for (int k = 0; k < KORD; ++k) {
        for (int j = 0; j < 64; ++j) {
            float wv = Wc[k * 4096 + j * 64 + lane];
#pragma unroll
            for (int i = 0; i < 8; ++i) acc[i] = fmaf(sT[k][w * 8 + i][j], wv, acc[i]);
        }
    }
    float acc2[8];
#pragma unroll
    for (int i = 0; i < 8; ++i) acc2[i] = 0.f;
    for (int j = 0; j < 64; ++j) {
        float wv = Wg[j * 64 + lane];
#pragma unroll
        for (int i = 0; i < 8; ++i) acc2[i] = fmaf(sA[w * 8 + i][j], wv, acc2[i]);
    }
    float bcv = bc[lane], bgv = bg[lane];
#pragma unroll
    for (int i = 0; i < 8; ++i) {
        int node = base + w * 8 + i;
        if (node < n) {
            out[node * 192 + lane] = acc[i] + bcv;
            out[node * 192 + 64 + lane] = acc2[i] + bgv;
        }
    }
}

extern "C" void kernel_launch(void* const* d_in, const int* in_sizes, int n_in,
                              void* d_out, int out_size, void* d_ws, size_t ws_size,
                              hipStream_t stream) {
    const float* h  = (const float*)d_in[0];
    const float* p  = (const float*)d_in[1];
    const float* ef = (const float*)d_in[2];
    const float* ew = (const float*)d_in[3];
    const float* fc = (const float*)d_in[4];
    const int* esrc = (const int*)d_in[5];
    const int* edst = (const int*)d_in[6];
    const float* Wc = (const float*)d_in[7];
    const float* bc = (const float*)d_in[8];
    const float* Wg = (const float*)d_in[9];
    const float* bg = (const float*)d_in[10];
    const float* WQ = (const float*)d_in[11];
    const float* WK = (const float*)d_in[12];
    const float* WV = (const float*)d_in[13];
    const float* WE = (const float*)d_in[14];

    const int n = in_sizes[0] / DD;   // 50000
    const int E = in_sizes[5];        // 800000
    float* out = (float*)d_out;

    char* wsp = (char*)d_ws;
    size_t o = 0;
    auto alloc = [&](size_t bytes) -> void* {
        void* r = (void*)(wsp + o);
        o = (o + bytes + 255) & ~(size_t)255;
        return r;
    };
    int* deg     = (int*)alloc((size_t)n * 4);
    int* offsets = (int*)alloc((size_t)(n + 1) * 4);
    int* cursor  = (int*)alloc((size_t)n * 4);
    int* invp    = (int*)alloc((size_t)E * 4);
    int* srcs    = (int*)alloc((size_t)E * 4);
    float* ews   = (float*)alloc((size_t)E * 4);
    float* dinvs = (float*)alloc((size_t)E * 4);
    int* bsum    = (int*)alloc(1024 * 4);
    float* dinv  = (float*)alloc((size_t)n * 4);
    short* WETb  = (short*)alloc(4096 * 2);
    unsigned short* hb   = (unsigned short*)alloc((size_t)n * DD * 2);
    unsigned short* Tx1b = (unsigned short*)alloc((size_t)n * DD * 2);
    unsigned short* Tx2b = (unsigned short*)alloc((size_t)n * DD * 2);
    unsigned short* Tx3b = (unsigned short*)alloc((size_t)n * DD * 2);
    unsigned short* aggb = (unsigned short*)alloc((size_t)n * DD * 2);
    unsigned short* Vhb  = (unsigned short*)alloc((size_t)n * DD * 2);
    float* Qhp   = (float*)alloc((size_t)n * DD * 4);
    float* Khp   = (float*)alloc((size_t)n * DD * 4);
    float* ssS   = (float*)alloc((size_t)E * HH * 4);
    (void)ws_size; (void)n_in; (void)out_size;

    hipMemsetAsync(deg, 0, (size_t)n * 4, stream);

    int nb = (n + 255) / 256;
    k_count<<<(E + 255) / 256, 256, 0, stream>>>(edst, E, deg);
    k_blocksum<<<nb, 256, 0, stream>>>(deg, n, bsum);
    k_scan_bsum<<<1, 256, 0, stream>>>(bsum, nb);
    k_scan_final<<<nb, 256, 0, stream>>>(deg, bsum, n, E, offsets, cursor, dinv);
    k_scatter<<<(E + 255) / 256, 256, 0, stream>>>(edst, esrc, ew, dinv, E, cursor,
                                                   invp, srcs, ews, dinvs);
    k_hb<<<(n * DD + 255) / 256, 256, 0, stream>>>(h, hb, n * DD);
    k_wetb<<<16, 256, 0, stream>>>(WE, WETb);

    k_pass1<<<(n + 3) / 4, 256, 0, stream>>>(offsets, srcs, ews, dinvs, dinv, hb, n, Tx1b, aggb);
    k_lap<<<(n + 3) / 4, 256, 0, stream>>>(offsets, srcs, dinvs, dinv, Tx1b, hb, 2.0f, -1.0f, n, Tx2b);
    k_lap<<<(n + 3) / 4, 256, 0, stream>>>(offsets, srcs, dinvs, dinv, Tx2b, Tx1b, 2.0f, -1.0f, n, Tx3b);

    k_qkv<<<(n + 31) / 32, 256, 0, stream>>>(h, p, WQ, WK, WV, n, Qhp, Khp, Vhb);

    k_score<<<2048, 256, 0, stream>>>(ef, WETb, esrc, edst, invp, Qhp, Khp, E, ssS);
    k_attn_agg<<<(n + 3) / 4, 256, 0, stream>>>(offsets, srcs, Vhb, ssS, n, out);

    k_out<<<(n + 31) / 32, 256, 0, stream>>>(h, Tx1b, Tx2b, Tx3b, aggb, fc, Wc, bc, Wg, bg, n, out);
}

// Round 9
// 510.061 us; speedup vs baseline: 1.7193x; 1.0753x over previous
//
#include <hip/hip_runtime.h>
#include <math.h>

#define DD 64
#define HH 8
#define KORD 4

typedef __attribute__((ext_vector_type(8))) short bf16x8;
typedef __attribute__((ext_vector_type(4))) float f32x4;
typedef __attribute__((ext_vector_type(4))) unsigned short u16x4;

__device__ __forceinline__ short f2bf(float f) {
    unsigned u = __builtin_bit_cast(unsigned, f);
    u = (u + 0x7fffu + ((u >> 16) & 1u)) >> 16;
    return (short)u;
}
__device__ __forceinline__ float bf2f(unsigned short u) {
    unsigned x = ((unsigned)u) << 16;
    return __builtin_bit_cast(float, x);
}

// ---------- CSR build ----------
__global__ void k_count(const int* __restrict__ dst, int E, int* __restrict__ deg) {
    int i = blockIdx.x * 256 + threadIdx.x;
    if (i < E) atomicAdd(&deg[dst[i]], 1);
}

__global__ void k_blocksum(const int* __restrict__ deg, int n, int* __restrict__ bsum) {
    __shared__ int s[256];
    int i = blockIdx.x * 256 + threadIdx.x;
    s[threadIdx.x] = (i < n) ? deg[i] : 0;
    __syncthreads();
    for (int off = 128; off > 0; off >>= 1) {
        if (threadIdx.x < off) s[threadIdx.x] += s[threadIdx.x + off];
        __syncthreads();
    }
    if (threadIdx.x == 0) bsum[blockIdx.x] = s[0];
}

__global__ void k_scan_bsum(int* __restrict__ bsum, int nb) {
    __shared__ int s[256];
    int t = threadIdx.x;
    int v = (t < nb) ? bsum[t] : 0;
    s[t] = v;
    __syncthreads();
    for (int off = 1; off < 256; off <<= 1) {
        int tmp = (t >= off) ? s[t - off] : 0;
        __syncthreads();
        s[t] += tmp;
        __syncthreads();
    }
    if (t < nb) bsum[t] = s[t] - v;  // exclusive
}

__global__ void k_scan_final(const int* __restrict__ deg, const int* __restrict__ bsum,
                             int n, int E, int* __restrict__ offsets,
                             int* __restrict__ cursor, float* __restrict__ dinv) {
    __shared__ int s[256];
    int t = threadIdx.x, i = blockIdx.x * 256 + t;
    int v = (i < n) ? deg[i] : 0;
    s[t] = v;
    __syncthreads();
    for (int off = 1; off < 256; off <<= 1) {
        int tmp = (t >= off) ? s[t - off] : 0;
        __syncthreads();
        s[t] += tmp;
        __syncthreads();
    }
    if (i < n) {
        int excl = s[t] - v + bsum[blockIdx.x];
        offsets[i] = excl;
        cursor[i] = excl;
        int dv = v < 1 ? 1 : v;
        dinv[i] = 1.0f / sqrtf((float)dv);
    }
    if (i == 0) offsets[n] = E;
}

// scatter: dst-sorted edge arrays + forward perm
__global__ void k_scatter(const int* __restrict__ dst, const int* __restrict__ src,
                          const float* __restrict__ ew, const float* __restrict__ dinv,
                          int E, int* __restrict__ cursor, int* __restrict__ eperm,
                          int* __restrict__ srcs, int* __restrict__ dsts,
                          float* __restrict__ ews, float* __restrict__ dinvs) {
    int i = blockIdx.x * 256 + threadIdx.x;
    if (i < E) {
        int s = src[i], d = dst[i];
        int p = atomicAdd(&cursor[d], 1);
        eperm[p] = i;
        srcs[p] = s;
        dsts[p] = d;
        ews[p] = ew[i];
        dinvs[p] = dinv[s];
    }
}

// h -> bf16 copy
__global__ void k_hb(const float* __restrict__ h, unsigned short* __restrict__ hb, int m) {
    int i = blockIdx.x * 256 + threadIdx.x;
    if (i < m) hb[i] = (unsigned short)f2bf(h[i]);
}

// WE^T in bf16 with head-aligned column permutation
__global__ void k_wetb(const float* __restrict__ WE, short* __restrict__ WETb) {
    int idx = blockIdx.x * 256 + threadIdx.x;
    if (idx < 4096) {
        int col = idx >> 6, j = idx & 63;
        int q = col & 15, tc = col >> 4;
        int d = ((q & 7) << 3) + (q >> 3) + (tc << 1);
        WETb[col * 64 + j] = f2bf(WE[j * 64 + d]);
    }
}

// ---------- pass 1: 4 edges/wave, 16 lanes/edge, 8B loads ----------
__global__ void k_pass1(const int* __restrict__ offsets, const int* __restrict__ srcs,
                        const float* __restrict__ ews, const float* __restrict__ dinvs,
                        const float* __restrict__ dinv, const unsigned short* __restrict__ hb,
                        int n, unsigned short* __restrict__ Tx1b,
                        unsigned short* __restrict__ aggb) {
    int w = threadIdx.x >> 6, lane = threadIdx.x & 63;
    int node = blockIdx.x * 4 + w;
    if (node >= n) return;
    int q = lane & 15, g = lane >> 4;
    int beg = offsets[node], end = offsets[node + 1];
    float aL[4] = {0.f, 0.f, 0.f, 0.f}, aG[4] = {0.f, 0.f, 0.f, 0.f};
    int e2 = beg;
    for (; e2 + 8 <= end; e2 += 8) {
        int ea = e2 + g, eb = e2 + 4 + g;
        int sa = srcs[ea], sb = srcs[eb];
        u16x4 va = *(const u16x4*)(hb + (size_t)sa * DD + q * 4);
        u16x4 vb = *(const u16x4*)(hb + (size_t)sb * DD + q * 4);
        float da = dinvs[ea], db = dinvs[eb];
        float wa = ews[ea], wb = ews[eb];
#pragma unroll
        for (int c = 0; c < 4; ++c) {
            float fa = bf2f(va[c]), fb = bf2f(vb[c]);
            aL[c] = fmaf(da, fa, aL[c]); aL[c] = fmaf(db, fb, aL[c]);
            aG[c] = fmaf(wa, fa, aG[c]); aG[c] = fmaf(wb, fb, aG[c]);
        }
    }
    for (; e2 < end; e2 += 4) {
        int e = e2 + g;
        if (e < end) {
            int s = srcs[e];
            u16x4 v = *(const u16x4*)(hb + (size_t)s * DD + q * 4);
            float d = dinvs[e], wv = ews[e];
#pragma unroll
            for (int c = 0; c < 4; ++c) {
                float f = bf2f(v[c]);
                aL[c] = fmaf(d, f, aL[c]);
                aG[c] = fmaf(wv, f, aG[c]);
            }
        }
    }
#pragma unroll
    for (int c = 0; c < 4; ++c) {
        aL[c] += __shfl_xor(aL[c], 16, 64); aL[c] += __shfl_xor(aL[c], 32, 64);
        aG[c] += __shfl_xor(aG[c], 16, 64); aG[c] += __shfl_xor(aG[c], 32, 64);
    }
    if (g == 0) {
        float dn = dinv[node];
        u16x4 o1, o2;
#pragma unroll
        for (int c = 0; c < 4; ++c) {
            o1[c] = (unsigned short)f2bf(-dn * aL[c]);
            o2[c] = (unsigned short)f2bf(aG[c]);
        }
        *(u16x4*)(Tx1b + (size_t)node * DD + q * 4) = o1;
        *(u16x4*)(aggb + (size_t)node * DD + q * 4) = o2;
    }
}

// ---------- out = alpha * lap_mul(x) + beta * prev ----------
__global__ void k_lap(const int* __restrict__ offsets, const int* __restrict__ srcs,
                      const float* __restrict__ dinvs, const float* __restrict__ dinv,
                      const unsigned short* __restrict__ x, const unsigned short* __restrict__ prev,
                      float alpha, float beta, int n, unsigned short* __restrict__ out) {
    int w = threadIdx.x >> 6, lane = threadIdx.x & 63;
    int node = blockIdx.x * 4 + w;
    if (node >= n) return;
    int q = lane & 15, g = lane >> 4;
    int beg = offsets[node], end = offsets[node + 1];
    float a[4] = {0.f, 0.f, 0.f, 0.f};
    int e2 = beg;
    for (; e2 + 8 <= end; e2 += 8) {
        int ea = e2 + g, eb = e2 + 4 + g;
        int sa = srcs[ea], sb = srcs[eb];
        u16x4 va = *(const u16x4*)(x + (size_t)sa * DD + q * 4);
        u16x4 vb = *(const u16x4*)(x + (size_t)sb * DD + q * 4);
        float da = dinvs[ea], db = dinvs[eb];
#pragma unroll
        for (int c = 0; c < 4; ++c) {
            a[c] = fmaf(da, bf2f(va[c]), a[c]);
            a[c] = fmaf(db, bf2f(vb[c]), a[c]);
        }
    }
    for (; e2 < end; e2 += 4) {
        int e = e2 + g;
        if (e < end) {
            int s = srcs[e];
            u16x4 v = *(const u16x4*)(x + (size_t)s * DD + q * 4);
            float d = dinvs[e];
#pragma unroll
            for (int c = 0; c < 4; ++c) a[c] = fmaf(d, bf2f(v[c]), a[c]);
        }
    }
#pragma unroll
    for (int c = 0; c < 4; ++c) {
        a[c] += __shfl_xor(a[c], 16, 64); a[c] += __shfl_xor(a[c], 32, 64);
    }
    if (g == 0) {
        float dn = dinv[node];
        u16x4 pv = *(const u16x4*)(prev + (size_t)node * DD + q * 4);
        u16x4 o;
#pragma unroll
        for (int c = 0; c < 4; ++c) {
            float v = alpha * (-dn * a[c]) + beta * bf2f(pv[c]);
            o[c] = (unsigned short)f2bf(v);
        }
        *(u16x4*)(out + (size_t)node * DD + q * 4) = o;
    }
}

// ---------- QKV projections, 8 nodes per wave; K/Q stored column-permuted; V bf16 ----------
__global__ void k_qkv(const float* __restrict__ h, const float* __restrict__ p,
                      const float* __restrict__ WQ, const float* __restrict__ WK,
                      const float* __restrict__ WV, int n,
                      float* __restrict__ Qhp, float* __restrict__ Khp,
                      unsigned short* __restrict__ Vhb) {
    __shared__ float hp[32][128];
    int base = blockIdx.x * 32;
    int t = threadIdx.x;
    for (int idx = t; idx < 4096; idx += 256) {
        int ni = idx >> 7, j = idx & 127;
        int node = base + ni;
        float v = 0.f;
        if (node < n) v = (j < 64) ? h[node * 64 + j] : p[node * 64 + (j - 64)];
        hp[ni][j] = v;
    }
    __syncthreads();
    int w = t >> 6, lane = t & 63;
    int colp = (((lane & 6) >> 1) << 4) + ((lane >> 3) | ((lane & 1) << 3));
    float q[8], k[8], v[8];
#pragma unroll
    for (int r = 0; r < 8; ++r) { q[r] = 0.f; k[r] = 0.f; v[r] = 0.f; }
    for (int i = 0; i < 128; ++i) {
        float wq = WQ[i * 64 + lane], wk = WK[i * 64 + lane], wv = WV[i * 64 + lane];
#pragma unroll
        for (int r = 0; r < 8; ++r) {
            float x = hp[w * 8 + r][i];
            q[r] = fmaf(x, wq, q[r]); k[r] = fmaf(x, wk, k[r]); v[r] = fmaf(x, wv, v[r]);
        }
    }
#pragma unroll
    for (int r = 0; r < 8; ++r) {
        int node = base + w * 8 + r;
        if (node < n) {
            Qhp[node * 64 + colp] = q[r];
            Khp[node * 64 + colp] = k[r];
            Vhb[node * 64 + lane] = (unsigned short)f2bf(v[r]);
        }
    }
}

// ---------- per-edge scores: MFMA over dst-sorted edges, depth-2 pipeline ----------
__global__ __launch_bounds__(256) void k_score(
        const float* __restrict__ efeat, const short* __restrict__ WETb,
        const int* __restrict__ srcs, const int* __restrict__ dsts,
        const int* __restrict__ eperm, const float* __restrict__ Qhp,
        const float* __restrict__ Khp, int E, float* __restrict__ ssS) {
    int lane = threadIdx.x & 63;
    int q = lane & 15, g = lane >> 4;

    bf16x8 bfrag[2][4];
#pragma unroll
    for (int kc = 0; kc < 2; ++kc)
#pragma unroll
        for (int tc = 0; tc < 4; ++tc)
            bfrag[kc][tc] = *(const bf16x8*)(WETb + (tc * 16 + q) * 64 + kc * 32 + g * 8);

    const float invs = 0.35355339059327373f;  // 1/sqrt(8)
    int nwaves = (gridDim.x * blockDim.x) >> 6;
    int wid = (blockIdx.x * blockDim.x + threadIdx.x) >> 6;
    int ntiles = (E + 15) >> 4;
    int wt = wid;
    if (wt >= ntiles) return;

    // prologue: e-rows for tile wt, eperm indices for tile wt+nwaves
    int er = wt * 16 + q;
    int rowC = eperm[er < E ? er : E - 1];
    const float* epC = efeat + (size_t)rowC * 64;
    float4 c0 = *(const float4*)(epC + g * 8);
    float4 c1 = *(const float4*)(epC + g * 8 + 4);
    float4 c2 = *(const float4*)(epC + 32 + g * 8);
    float4 c3 = *(const float4*)(epC + 32 + g * 8 + 4);
    int wtN = wt + nwaves;
    int rowN = 0;
    if (wtN < ntiles) {
        int ern = wtN * 16 + q;
        rowN = eperm[ern < E ? ern : E - 1];
    }

    while (true) {
        int ebase = wt * 16;
        bool hasN = wtN < ntiles;
        // issue next-tile e-row loads (latency hidden under MFMA+epilogue)
        float4 n0, n1, n2, n3;
        if (hasN) {
            const float* epN = efeat + (size_t)rowN * 64;
            n0 = *(const float4*)(epN + g * 8);
            n1 = *(const float4*)(epN + g * 8 + 4);
            n2 = *(const float4*)(epN + 32 + g * 8);
            n3 = *(const float4*)(epN + 32 + g * 8 + 4);
        }
        // issue eperm for tile after next
        int wtN2 = wtN + nwaves;
        int rowN2 = 0;
        if (wtN2 < ntiles) {
            int ern = wtN2 * 16 + q;
            rowN2 = eperm[ern < E ? ern : E - 1];
        }
        // issue src/dst for current epilogue
        int sA[4], tA[4];
#pragma unroll
        for (int r = 0; r < 4; ++r) {
            int e = ebase + g * 4 + r;
            int ec = e < E ? e : E - 1;
            sA[r] = srcs[ec];
            tA[r] = dsts[ec];
        }

        // MFMA on current tile
        f32x4 acc0 = {0, 0, 0, 0}, acc1 = {0, 0, 0, 0};
        f32x4 acc2 = {0, 0, 0, 0}, acc3 = {0, 0, 0, 0};
        {
            bf16x8 a;
            a[0] = f2bf(c0.x); a[1] = f2bf(c0.y); a[2] = f2bf(c0.z); a[3] = f2bf(c0.w);
            a[4] = f2bf(c1.x); a[5] = f2bf(c1.y); a[6] = f2bf(c1.z); a[7] = f2bf(c1.w);
            acc0 = __builtin_amdgcn_mfma_f32_16x16x32_bf16(a, bfrag[0][0], acc0, 0, 0, 0);
            acc1 = __builtin_amdgcn_mfma_f32_16x16x32_bf16(a, bfrag[0][1], acc1, 0, 0, 0);
            acc2 = __builtin_amdgcn_mfma_f32_16x16x32_bf16(a, bfrag[0][2], acc2, 0, 0, 0);
            acc3 = __builtin_amdgcn_mfma_f32_16x16x32_bf16(a, bfrag[0][3], acc3, 0, 0, 0);
            a[0] = f2bf(c2.x); a[1] = f2bf(c2.y); a[2] = f2bf(c2.z); a[3] = f2bf(c2.w);
            a[4] = f2bf(c3.x); a[5] = f2bf(c3.y); a[6] = f2bf(c3.z); a[7] = f2bf(c3.w);
            acc0 = __builtin_amdgcn_mfma_f32_16x16x32_bf16(a, bfrag[1][0], acc0, 0, 0, 0);
            acc1 = __builtin_amdgcn_mfma_f32_16x16x32_bf16(a, bfrag[1][1], acc1, 0, 0, 0);
            acc2 = __builtin_amdgcn_mfma_f32_16x16x32_bf16(a, bfrag[1][2], acc2, 0, 0, 0);
            acc3 = __builtin_amdgcn_mfma_f32_16x16x32_bf16(a, bfrag[1][3], acc3, 0, 0, 0);
        }

        // epilogue
#pragma unroll
        for (int r = 0; r < 4; ++r) {
            int e = ebase + g * 4 + r;
            const float* Kp = Khp + (size_t)sA[r] * 64 + q;
            const float* Qp = Qhp + (size_t)tA[r] * 64 + q;
            float pv = Kp[0] * Qp[0] * acc0[r]
                     + Kp[16] * Qp[16] * acc1[r]
                     + Kp[32] * Qp[32] * acc2[r]
                     + Kp[48] * Qp[48] * acc3[r];
            pv *= invs;
            pv += __shfl_xor(pv, 8, 64);
            float sc = __expf(fminf(fmaxf(pv, -5.0f), 5.0f));
            if ((lane & 8) == 0 && e < E) ssS[(size_t)e * HH + (q & 7)] = sc;
        }

        if (!hasN) break;
        c0 = n0; c1 = n1; c2 = n2; c3 = n3;
        wt = wtN; wtN = wtN2; rowN = rowN2;
    }
}

// ---------- attention aggregation: 4 edges/wave, 16 lanes/edge ----------
__global__ void k_attn_agg(const int* __restrict__ offsets, const int* __restrict__ srcs,
                           const unsigned short* __restrict__ Vhb, const float* __restrict__ ssS,
                           int n, float* __restrict__ out) {
    int w = threadIdx.x >> 6, lane = threadIdx.x & 63;
    int node = blockIdx.x * 4 + w;
    if (node >= n) return;
    int q = lane & 15, g = lane >> 4;
    int hh = q >> 1;  // head of features 4q..4q+3
    int beg = offsets[node], end = offsets[node + 1];
    float aV[4] = {0.f, 0.f, 0.f, 0.f};
    float aZ = 0.f;
    int e2 = beg;
    for (; e2 + 8 <= end; e2 += 8) {
        int ea = e2 + g, eb = e2 + 4 + g;
        int sa = srcs[ea], sb = srcs[eb];
        u16x4 va = *(const u16x4*)(Vhb + (size_t)sa * DD + q * 4);
        u16x4 vb = *(const u16x4*)(Vhb + (size_t)sb * DD + q * 4);
        float sva = ssS[(size_t)ea * HH + hh];
        float svb = ssS[(size_t)eb * HH + hh];
#pragma unroll
        for (int c = 0; c < 4; ++c) {
            aV[c] = fmaf(sva, bf2f(va[c]), aV[c]);
            aV[c] = fmaf(svb, bf2f(vb[c]), aV[c]);
        }
        aZ += sva + svb;
    }
    for (; e2 < end; e2 += 4) {
        int e = e2 + g;
        if (e < end) {
            int s = srcs[e];
            u16x4 v = *(const u16x4*)(Vhb + (size_t)s * DD + q * 4);
            float sv = ssS[(size_t)e * HH + hh];
#pragma unroll
            for (int c = 0; c < 4; ++c) aV[c] = fmaf(sv, bf2f(v[c]), aV[c]);
            aZ += sv;
        }
    }
#pragma unroll
    for (int c = 0; c < 4; ++c) {
        aV[c] += __shfl_xor(aV[c], 16, 64);
        aV[c] += __shfl_xor(aV[c], 32, 64);
    }
    aZ += __shfl_xor(aZ, 16, 64);
    aZ += __shfl_xor(aZ, 32, 64);
    if (g == 0) {
        float inv = 1.0f / (aZ + 1e-6f);
        float4 o;
        o.x = aV[0] * inv; o.y = aV[1] * inv; o.z = aV[2] * inv; o.w = aV[3] * inv;
        *(float4*)(out + (size_t)node * 192 + 128 + q * 4) = o;
    }
}

// ---------- output: cheb + gcn (Tx tables bf16, Tx0 = h f32) ----------
__global__ void k_out(const float* __restrict__ h, const unsigned short* __restrict__ Tx1b,
                      const unsigned short* __restrict__ Tx2b, const unsigned short* __restrict__ Tx3b,
                      const unsigned short* __restrict__ aggb, const float* __restrict__ fc,
                      const float* __restrict__ Wc, const float* __restrict__ bc,
                      const float* __restrict__ Wg, const float* __restrict__ bg,
                      int n, float* __restrict__ out) {
    __shared__ float sT[KORD][32][64];
    __shared__ float sA[32][64];
    int base = blockIdx.x * 32;
    int t = threadIdx.x;
    for (int idx = t; idx < 2048; idx += 256) {
        int ni = idx >> 6, j = idx & 63;
        int node = base + ni;
        if (node < n) {
            sT[0][ni][j] = fc[node] * h[node * 64 + j];
            sT[1][ni][j] = fc[n + node] * bf2f(Tx1b[node * 64 + j]);
            sT[2][ni][j] = fc[2 * n + node] * bf2f(Tx2b[node * 64 + j]);
            sT[3][ni][j] = fc[3 * n + node] * bf2f(Tx3b[node * 64 + j]);
            sA[ni][j] = bf2f(aggb[node * 64 + j]);
        } else {
            sT[0][ni][j] = 0.f; sT[1][ni][j] = 0.f;
            sT[2][ni][j] = 0.f; sT[3][ni][j] = 0.f;
            sA[ni][j] = 0.f;
        }
    }
    __syncthreads();
    int w = t >> 6, lane = t & 63;
    float acc[8];
#pragma unroll
    for (int i = 0; i < 8; ++i) acc[i] = 0.f;
#pragma unroll
    for (int k = 0; k < KORD; ++k) {
        for (int j = 0; j < 64; ++j) {
            float wv = Wc[k * 4096 + j * 64 + lane];
#pragma unroll
            for (int i = 0; i < 8; ++i) acc[i] = fmaf(sT[k][w * 8 + i][j], wv, acc[i]);
        }
    }
    float acc2[8];
#pragma unroll
    for (int i = 0; i < 8; ++i) acc2[i] = 0.f;
    for (int j = 0; j < 64; ++j) {
        float wv = Wg[j * 64 + lane];
#pragma unroll
        for (int i = 0; i < 8; ++i) acc2[i] = fmaf(sA[w * 8 + i][j], wv, acc2[i]);
    }
    float bcv = bc[lane], bgv = bg[lane];
#pragma unroll
    for (int i = 0; i < 8; ++i) {
        int node = base + w * 8 + i;
        if (node < n) {
            out[node * 192 + lane] = acc[i] + bcv;
            out[node * 192 + 64 + lane] = acc2[i] + bgv;
        }
    }
}

extern "C" void kernel_launch(void* const* d_in, const int* in_sizes, int n_in,
                              void* d_out, int out_size, void* d_ws, size_t ws_size,
                              hipStream_t stream) {
    const float* h  = (const float*)d_in[0];
    const float* p  = (const float*)d_in[1];
    const float* ef = (const float*)d_in[2];
    const float* ew = (const float*)d_in[3];
    const float* fc = (const float*)d_in[4];
    const int* esrc = (const int*)d_in[5];
    const int* edst = (const int*)d_in[6];
    const float* Wc = (const float*)d_in[7];
    const float* bc = (const float*)d_in[8];
    const float* Wg = (const float*)d_in[9];
    const float* bg = (const float*)d_in[10];
    const float* WQ = (const float*)d_in[11];
    const float* WK = (const float*)d_in[12];
    const float* WV = (const float*)d_in[13];
    const float* WE = (const float*)d_in[14];

    const int n = in_sizes[0] / DD;   // 50000
    const int E = in_sizes[5];        // 800000
    float* out = (float*)d_out;

    char* wsp = (char*)d_ws;
    size_t o = 0;
    auto alloc = [&](size_t bytes) -> void* {
        void* r = (void*)(wsp + o);
        o = (o + bytes + 255) & ~(size_t)255;
        return r;
    };
    int* deg     = (int*)alloc((size_t)n * 4);
    int* offsets = (int*)alloc((size_t)(n + 1) * 4);
    int* cursor  = (int*)alloc((size_t)n * 4);
    int* eperm   = (int*)alloc((size_t)E * 4);
    int* srcs    = (int*)alloc((size_t)E * 4);
    int* dsts    = (int*)alloc((size_t)E * 4);
    float* ews   = (float*)alloc((size_t)E * 4);
    float* dinvs = (float*)alloc((size_t)E * 4);
    int* bsum    = (int*)alloc(1024 * 4);
    float* dinv  = (float*)alloc((size_t)n * 4);
    short* WETb  = (short*)alloc(4096 * 2);
    unsigned short* hb   = (unsigned short*)alloc((size_t)n * DD * 2);
    unsigned short* Tx1b = (unsigned short*)alloc((size_t)n * DD * 2);
    unsigned short* Tx2b = (unsigned short*)alloc((size_t)n * DD * 2);
    unsigned short* Tx3b = (unsigned short*)alloc((size_t)n * DD * 2);
    unsigned short* aggb = (unsigned short*)alloc((size_t)n * DD * 2);
    unsigned short* Vhb  = (unsigned short*)alloc((size_t)n * DD * 2);
    float* Qhp   = (float*)alloc((size_t)n * DD * 4);
    float* Khp   = (float*)alloc((size_t)n * DD * 4);
    float* ssS   = (float*)alloc((size_t)E * HH * 4);
    (void)ws_size; (void)n_in; (void)out_size;

    hipMemsetAsync(deg, 0, (size_t)n * 4, stream);

    int nb = (n + 255) / 256;
    k_count<<<(E + 255) / 256, 256, 0, stream>>>(edst, E, deg);
    k_blocksum<<<nb, 256, 0, stream>>>(deg, n, bsum);
    k_scan_bsum<<<1, 256, 0, stream>>>(bsum, nb);
    k_scan_final<<<nb, 256, 0, stream>>>(deg, bsum, n, E, offsets, cursor, dinv);
    k_scatter<<<(E + 255) / 256, 256, 0, stream>>>(edst, esrc, ew, dinv, E, cursor,
                                                   eperm, srcs, dsts, ews, dinvs);
    k_hb<<<(n * DD + 255) / 256, 256, 0, stream>>>(h, hb, n * DD);
    k_wetb<<<16, 256, 0, stream>>>(WE, WETb);

    k_pass1<<<(n + 3) / 4, 256, 0, stream>>>(offsets, srcs, ews, dinvs, dinv, hb, n, Tx1b, aggb);
    k_lap<<<(n + 3) / 4, 256, 0, stream>>>(offsets, srcs, dinvs, dinv, Tx1b, hb, 2.0f, -1.0f, n, Tx2b);
    k_lap<<<(n + 3) / 4, 256, 0, stream>>>(offsets, srcs, dinvs, dinv, Tx2b, Tx1b, 2.0f, -1.0f, n, Tx3b);

    k_qkv<<<(n + 31) / 32, 256, 0, stream>>>(h, p, WQ, WK, WV, n, Qhp, Khp, Vhb);

    k_score<<<2048, 256, 0, stream>>>(ef, WETb, srcs, dsts, eperm, Qhp, Khp, E, ssS);
    k_attn_agg<<<(n + 3) / 4, 256, 0, stream>>>(offsets, srcs, Vhb, ssS, n, out);

    k_out<<<(n + 31) / 32, 256, 0, stream>>>(h, Tx1b, Tx2b, Tx3b, aggb, fc, Wc, bc, Wg, bg, n, out);
}

// Round 10
// 454.825 us; speedup vs baseline: 1.9281x; 1.1214x over previous
//
#include <hip/hip_runtime.h>
#include <math.h>

#define DD 64
#define HH 8
#define KORD 4

typedef __attribute__((ext_vector_type(8))) short bf16x8;
typedef __attribute__((ext_vector_type(4))) float f32x4;
typedef __attribute__((ext_vector_type(8))) unsigned short u16x8;

__device__ __forceinline__ short f2bf(float f) {
    unsigned u = __builtin_bit_cast(unsigned, f);
    u = (u + 0x7fffu + ((u >> 16) & 1u)) >> 16;
    return (short)u;
}
__device__ __forceinline__ float bf2f(unsigned short u) {
    unsigned x = ((unsigned)u) << 16;
    return __builtin_bit_cast(float, x);
}
__device__ __forceinline__ float i2f(int v) { return __builtin_bit_cast(float, v); }

// ---------- CSR build ----------
__global__ void k_count(const int* __restrict__ dst, int E, int* __restrict__ deg) {
    int i = blockIdx.x * 256 + threadIdx.x;
    if (i < E) atomicAdd(&deg[dst[i]], 1);
}

__global__ void k_blocksum(const int* __restrict__ deg, int n, int* __restrict__ bsum) {
    __shared__ int s[256];
    int i = blockIdx.x * 256 + threadIdx.x;
    s[threadIdx.x] = (i < n) ? deg[i] : 0;
    __syncthreads();
    for (int off = 128; off > 0; off >>= 1) {
        if (threadIdx.x < off) s[threadIdx.x] += s[threadIdx.x + off];
        __syncthreads();
    }
    if (threadIdx.x == 0) bsum[blockIdx.x] = s[0];
}

__global__ void k_scan_bsum(int* __restrict__ bsum, int nb) {
    __shared__ int s[256];
    int t = threadIdx.x;
    int v = (t < nb) ? bsum[t] : 0;
    s[t] = v;
    __syncthreads();
    for (int off = 1; off < 256; off <<= 1) {
        int tmp = (t >= off) ? s[t - off] : 0;
        __syncthreads();
        s[t] += tmp;
        __syncthreads();
    }
    if (t < nb) bsum[t] = s[t] - v;  // exclusive
}

__global__ void k_scan_final(const int* __restrict__ deg, const int* __restrict__ bsum,
                             int n, int E, int* __restrict__ offsets,
                             int* __restrict__ cursor, float* __restrict__ dinv) {
    __shared__ int s[256];
    int t = threadIdx.x, i = blockIdx.x * 256 + t;
    int v = (i < n) ? deg[i] : 0;
    s[t] = v;
    __syncthreads();
    for (int off = 1; off < 256; off <<= 1) {
        int tmp = (t >= off) ? s[t - off] : 0;
        __syncthreads();
        s[t] += tmp;
        __syncthreads();
    }
    if (i < n) {
        int excl = s[t] - v + bsum[blockIdx.x];
        offsets[i] = excl;
        cursor[i] = excl;
        int dv = v < 1 ? 1 : v;
        dinv[i] = 1.0f / sqrtf((float)dv);
    }
    if (i == 0) offsets[n] = E;
}

// scatter: ONE 16B payload store per edge: {src, ew, dinv[src], orig_eid}
__global__ void k_scatter(const int* __restrict__ dst, const int* __restrict__ src,
                          const float* __restrict__ ew, const float* __restrict__ dinv,
                          int E, int* __restrict__ cursor, int4* __restrict__ payload) {
    int i = blockIdx.x * 256 + threadIdx.x;
    if (i < E) {
        int s = src[i], d = dst[i];
        int p = atomicAdd(&cursor[d], 1);
        int4 pl;
        pl.x = s;
        pl.y = __builtin_bit_cast(int, ew[i]);
        pl.z = __builtin_bit_cast(int, dinv[s]);
        pl.w = i;
        payload[p] = pl;
    }
}

// node-parallel dst fill (sequential writes, no atomics)
__global__ void k_dstfill(const int* __restrict__ offsets, int n, int* __restrict__ dsts) {
    int node = blockIdx.x * 256 + threadIdx.x;
    if (node < n) {
        int beg = offsets[node], end = offsets[node + 1];
        for (int e = beg; e < end; ++e) dsts[e] = node;
    }
}

// WE^T in bf16 with head-aligned column permutation
__global__ void k_wetb(const float* __restrict__ WE, short* __restrict__ WETb) {
    int idx = blockIdx.x * 256 + threadIdx.x;
    if (idx < 4096) {
        int col = idx >> 6, j = idx & 63;
        int q = col & 15, tc = col >> 4;
        int d = ((q & 7) << 3) + (q >> 3) + (tc << 1);
        WETb[col * 64 + j] = f2bf(WE[j * 64 + d]);
    }
}

// ---------- pass 1: 8 edges/wave in flight x2, 8 lanes/edge, 16B loads ----------
__global__ void k_pass1(const int* __restrict__ offsets, const int4* __restrict__ payload,
                        const float* __restrict__ dinv, const unsigned short* __restrict__ hb,
                        int n, unsigned short* __restrict__ Tx1b,
                        unsigned short* __restrict__ aggb) {
    int w = threadIdx.x >> 6, lane = threadIdx.x & 63;
    int node = blockIdx.x * 4 + w;
    if (node >= n) return;
    int q = lane & 7, g = lane >> 3;
    int beg = offsets[node], end = offsets[node + 1];
    float aL[8], aG[8];
#pragma unroll
    for (int c = 0; c < 8; ++c) { aL[c] = 0.f; aG[c] = 0.f; }
    int e2 = beg;
    for (; e2 + 16 <= end; e2 += 16) {
        int4 pa = payload[e2 + g], pb = payload[e2 + 8 + g];
        u16x8 va = *(const u16x8*)(hb + (size_t)pa.x * DD + q * 8);
        u16x8 vb = *(const u16x8*)(hb + (size_t)pb.x * DD + q * 8);
        float da = i2f(pa.z), db = i2f(pb.z);
        float wa = i2f(pa.y), wb = i2f(pb.y);
#pragma unroll
        for (int c = 0; c < 8; ++c) {
            float fa = bf2f(va[c]), fb = bf2f(vb[c]);
            aL[c] = fmaf(da, fa, aL[c]); aL[c] = fmaf(db, fb, aL[c]);
            aG[c] = fmaf(wa, fa, aG[c]); aG[c] = fmaf(wb, fb, aG[c]);
        }
    }
    for (; e2 < end; e2 += 8) {
        int e = e2 + g;
        if (e < end) {
            int4 pl = payload[e];
            u16x8 v = *(const u16x8*)(hb + (size_t)pl.x * DD + q * 8);
            float d = i2f(pl.z), wv = i2f(pl.y);
#pragma unroll
            for (int c = 0; c < 8; ++c) {
                float f = bf2f(v[c]);
                aL[c] = fmaf(d, f, aL[c]);
                aG[c] = fmaf(wv, f, aG[c]);
            }
        }
    }
#pragma unroll
    for (int c = 0; c < 8; ++c) {
        aL[c] += __shfl_xor(aL[c], 8, 64);  aL[c] += __shfl_xor(aL[c], 16, 64);
        aL[c] += __shfl_xor(aL[c], 32, 64);
        aG[c] += __shfl_xor(aG[c], 8, 64);  aG[c] += __shfl_xor(aG[c], 16, 64);
        aG[c] += __shfl_xor(aG[c], 32, 64);
    }
    if (g == 0) {
        float dn = dinv[node];
        u16x8 o1, o2;
#pragma unroll
        for (int c = 0; c < 8; ++c) {
            o1[c] = (unsigned short)f2bf(-dn * aL[c]);
            o2[c] = (unsigned short)f2bf(aG[c]);
        }
        *(u16x8*)(Tx1b + (size_t)node * DD + q * 8) = o1;
        *(u16x8*)(aggb + (size_t)node * DD + q * 8) = o2;
    }
}

// ---------- out = alpha * lap_mul(x) + beta * prev ----------
__global__ void k_lap(const int* __restrict__ offsets, const int4* __restrict__ payload,
                      const float* __restrict__ dinv, const unsigned short* __restrict__ x,
                      const unsigned short* __restrict__ prev,
                      float alpha, float beta, int n, unsigned short* __restrict__ out) {
    int w = threadIdx.x >> 6, lane = threadIdx.x & 63;
    int node = blockIdx.x * 4 + w;
    if (node >= n) return;
    int q = lane & 7, g = lane >> 3;
    int beg = offsets[node], end = offsets[node + 1];
    float a[8];
#pragma unroll
    for (int c = 0; c < 8; ++c) a[c] = 0.f;
    int e2 = beg;
    for (; e2 + 16 <= end; e2 += 16) {
        int4 pa = payload[e2 + g], pb = payload[e2 + 8 + g];
        u16x8 va = *(const u16x8*)(x + (size_t)pa.x * DD + q * 8);
        u16x8 vb = *(const u16x8*)(x + (size_t)pb.x * DD + q * 8);
        float da = i2f(pa.z), db = i2f(pb.z);
#pragma unroll
        for (int c = 0; c < 8; ++c) {
            a[c] = fmaf(da, bf2f(va[c]), a[c]);
            a[c] = fmaf(db, bf2f(vb[c]), a[c]);
        }
    }
    for (; e2 < end; e2 += 8) {
        int e = e2 + g;
        if (e < end) {
            int4 pl = payload[e];
            u16x8 v = *(const u16x8*)(x + (size_t)pl.x * DD + q * 8);
            float d = i2f(pl.z);
#pragma unroll
            for (int c = 0; c < 8; ++c) a[c] = fmaf(d, bf2f(v[c]), a[c]);
        }
    }
#pragma unroll
    for (int c = 0; c < 8; ++c) {
        a[c] += __shfl_xor(a[c], 8, 64);  a[c] += __shfl_xor(a[c], 16, 64);
        a[c] += __shfl_xor(a[c], 32, 64);
    }
    if (g == 0) {
        float dn = dinv[node];
        u16x8 pv = *(const u16x8*)(prev + (size_t)node * DD + q * 8);
        u16x8 o;
#pragma unroll
        for (int c = 0; c < 8; ++c) {
            float v = alpha * (-dn * a[c]) + beta * bf2f(pv[c]);
            o[c] = (unsigned short)f2bf(v);
        }
        *(u16x8*)(out + (size_t)node * DD + q * 8) = o;
    }
}

// ---------- fused: Tx3 = 2*lap(Tx2) - Tx1  AND  attention aggregation ----------
__global__ void k_lap3_attn(const int* __restrict__ offsets, const int4* __restrict__ payload,
                            const float* __restrict__ dinv,
                            const unsigned short* __restrict__ Tx2b,
                            const unsigned short* __restrict__ Tx1b,
                            const unsigned short* __restrict__ Vhb,
                            const float* __restrict__ ssS,
                            int n, unsigned short* __restrict__ Tx3b,
                            float* __restrict__ out) {
    int w = threadIdx.x >> 6, lane = threadIdx.x & 63;
    int node = blockIdx.x * 4 + w;
    if (node >= n) return;
    int q = lane & 7, g = lane >> 3;  // head == q
    int beg = offsets[node], end = offsets[node + 1];
    float a[8], aV[8];
#pragma unroll
    for (int c = 0; c < 8; ++c) { a[c] = 0.f; aV[c] = 0.f; }
    float aZ = 0.f;
    int e2 = beg;
    for (; e2 + 16 <= end; e2 += 16) {
        int ea = e2 + g, eb = e2 + 8 + g;
        int4 pa = payload[ea], pb = payload[eb];
        u16x8 xa = *(const u16x8*)(Tx2b + (size_t)pa.x * DD + q * 8);
        u16x8 xb = *(const u16x8*)(Tx2b + (size_t)pb.x * DD + q * 8);
        u16x8 va = *(const u16x8*)(Vhb + (size_t)pa.x * DD + q * 8);
        u16x8 vb = *(const u16x8*)(Vhb + (size_t)pb.x * DD + q * 8);
        float sva = ssS[(size_t)ea * HH + q];
        float svb = ssS[(size_t)eb * HH + q];
        float da = i2f(pa.z), db = i2f(pb.z);
#pragma unroll
        for (int c = 0; c < 8; ++c) {
            a[c] = fmaf(da, bf2f(xa[c]), a[c]);
            a[c] = fmaf(db, bf2f(xb[c]), a[c]);
            aV[c] = fmaf(sva, bf2f(va[c]), aV[c]);
            aV[c] = fmaf(svb, bf2f(vb[c]), aV[c]);
        }
        aZ += sva + svb;
    }
    for (; e2 < end; e2 += 8) {
        int e = e2 + g;
        if (e < end) {
            int4 pl = payload[e];
            u16x8 x = *(const u16x8*)(Tx2b + (size_t)pl.x * DD + q * 8);
            u16x8 v = *(const u16x8*)(Vhb + (size_t)pl.x * DD + q * 8);
            float sv = ssS[(size_t)e * HH + q];
            float d = i2f(pl.z);
#pragma unroll
            for (int c = 0; c < 8; ++c) {
                a[c] = fmaf(d, bf2f(x[c]), a[c]);
                aV[c] = fmaf(sv, bf2f(v[c]), aV[c]);
            }
            aZ += sv;
        }
    }
#pragma unroll
    for (int c = 0; c < 8; ++c) {
        a[c] += __shfl_xor(a[c], 8, 64);   a[c] += __shfl_xor(a[c], 16, 64);
        a[c] += __shfl_xor(a[c], 32, 64);
        aV[c] += __shfl_xor(aV[c], 8, 64); aV[c] += __shfl_xor(aV[c], 16, 64);
        aV[c] += __shfl_xor(aV[c], 32, 64);
    }
    aZ += __shfl_xor(aZ, 8, 64); aZ += __shfl_xor(aZ, 16, 64); aZ += __shfl_xor(aZ, 32, 64);
    if (g == 0) {
        float dn = dinv[node];
        u16x8 pv = *(const u16x8*)(Tx1b + (size_t)node * DD + q * 8);
        u16x8 o;
        float inv = 1.0f / (aZ + 1e-6f);
        float4 o1, o2;
#pragma unroll
        for (int c = 0; c < 8; ++c) {
            float v = 2.0f * (-dn * a[c]) - bf2f(pv[c]);
            o[c] = (unsigned short)f2bf(v);
        }
        o1.x = aV[0] * inv; o1.y = aV[1] * inv; o1.z = aV[2] * inv; o1.w = aV[3] * inv;
        o2.x = aV[4] * inv; o2.y = aV[5] * inv; o2.z = aV[6] * inv; o2.w = aV[7] * inv;
        *(u16x8*)(Tx3b + (size_t)node * DD + q * 8) = o;
        *(float4*)(out + (size_t)node * 192 + 128 + q * 8) = o1;
        *(float4*)(out + (size_t)node * 192 + 128 + q * 8 + 4) = o2;
    }
}

// ---------- QKV projections, 8 nodes per wave; K/Q column-permuted; V + h bf16 ----------
__global__ void k_qkv(const float* __restrict__ h, const float* __restrict__ p,
                      const float* __restrict__ WQ, const float* __restrict__ WK,
                      const float* __restrict__ WV, int n,
                      float* __restrict__ Qhp, float* __restrict__ Khp,
                      unsigned short* __restrict__ Vhb, unsigned short* __restrict__ hb) {
    __shared__ float hp[32][128];
    int base = blockIdx.x * 32;
    int t = threadIdx.x;
    for (int idx = t; idx < 4096; idx += 256) {
        int ni = idx >> 7, j = idx & 127;
        int node = base + ni;
        float v = 0.f;
        if (node < n) {
            v = (j < 64) ? h[node * 64 + j] : p[node * 64 + (j - 64)];
            if (j < 64) hb[(size_t)node * 64 + j] = (unsigned short)f2bf(v);
        }
        hp[ni][j] = v;
    }
    __syncthreads();
    int w = t >> 6, lane = t & 63;
    int colp = (((lane & 6) >> 1) << 4) + ((lane >> 3) | ((lane & 1) << 3));
    float q[8], k[8], v[8];
#pragma unroll
    for (int r = 0; r < 8; ++r) { q[r] = 0.f; k[r] = 0.f; v[r] = 0.f; }
    for (int i = 0; i < 128; ++i) {
        float wq = WQ[i * 64 + lane], wk = WK[i * 64 + lane], wv = WV[i * 64 + lane];
#pragma unroll
        for (int r = 0; r < 8; ++r) {
            float x = hp[w * 8 + r][i];
            q[r] = fmaf(x, wq, q[r]); k[r] = fmaf(x, wk, k[r]); v[r] = fmaf(x, wv, v[r]);
        }
    }
#pragma unroll
    for (int r = 0; r < 8; ++r) {
        int node = base + w * 8 + r;
        if (node < n) {
            Qhp[node * 64 + colp] = q[r];
            Khp[node * 64 + colp] = k[r];
            Vhb[node * 64 + lane] = (unsigned short)f2bf(v[r]);
        }
    }
}

// ---------- per-edge scores: MFMA over dst-sorted edges, depth-2 pipeline ----------
__global__ __launch_bounds__(256) void k_score(
        const float* __restrict__ efeat, const short* __restrict__ WETb,
        const int4* __restrict__ payload, const int* __restrict__ dsts,
        const float* __restrict__ Qhp, const float* __restrict__ Khp,
        int E, float* __restrict__ ssS) {
    int lane = threadIdx.x & 63;
    int q = lane & 15, g = lane >> 4;

    bf16x8 bfrag[2][4];
#pragma unroll
    for (int kc = 0; kc < 2; ++kc)
#pragma unroll
        for (int tc = 0; tc < 4; ++tc)
            bfrag[kc][tc] = *(const bf16x8*)(WETb + (tc * 16 + q) * 64 + kc * 32 + g * 8);

    const float invs = 0.35355339059327373f;  // 1/sqrt(8)
    int nwaves = (gridDim.x * blockDim.x) >> 6;
    int wid = (blockIdx.x * blockDim.x + threadIdx.x) >> 6;
    int ntiles = (E + 15) >> 4;
    int wt = wid;
    if (wt >= ntiles) return;

    int er = wt * 16 + q;
    int rowC = payload[er < E ? er : E - 1].w;
    const float* epC = efeat + (size_t)rowC * 64;
    float4 c0 = *(const float4*)(epC + g * 8);
    float4 c1 = *(const float4*)(epC + g * 8 + 4);
    float4 c2 = *(const float4*)(epC + 32 + g * 8);
    float4 c3 = *(const float4*)(epC + 32 + g * 8 + 4);
    int wtN = wt + nwaves;
    int rowN = 0;
    if (wtN < ntiles) {
        int ern = wtN * 16 + q;
        rowN = payload[ern < E ? ern : E - 1].w;
    }

    while (true) {
        int ebase = wt * 16;
        bool hasN = wtN < ntiles;
        float4 n0, n1, n2, n3;
        if (hasN) {
            const float* epN = efeat + (size_t)rowN * 64;
            n0 = *(const float4*)(epN + g * 8);
            n1 = *(const float4*)(epN + g * 8 + 4);
            n2 = *(const float4*)(epN + 32 + g * 8);
            n3 = *(const float4*)(epN + 32 + g * 8 + 4);
        }
        int wtN2 = wtN + nwaves;
        int rowN2 = 0;
        if (wtN2 < ntiles) {
            int ern = wtN2 * 16 + q;
            rowN2 = payload[ern < E ? ern : E - 1].w;
        }
        int sA[4], tA[4];
#pragma unroll
        for (int r = 0; r < 4; ++r) {
            int e = ebase + g * 4 + r;
            int ec = e < E ? e : E - 1;
            sA[r] = payload[ec].x;
            tA[r] = dsts[ec];
        }

        f32x4 acc0 = {0, 0, 0, 0}, acc1 = {0, 0, 0, 0};
        f32x4 acc2 = {0, 0, 0, 0}, acc3 = {0, 0, 0, 0};
        {
            bf16x8 a;
            a[0] = f2bf(c0.x); a[1] = f2bf(c0.y); a[2] = f2bf(c0.z); a[3] = f2bf(c0.w);
            a[4] = f2bf(c1.x); a[5] = f2bf(c1.y); a[6] = f2bf(c1.z); a[7] = f2bf(c1.w);
            acc0 = __builtin_amdgcn_mfma_f32_16x16x32_bf16(a, bfrag[0][0], acc0, 0, 0, 0);
            acc1 = __builtin_amdgcn_mfma_f32_16x16x32_bf16(a, bfrag[0][1], acc1, 0, 0, 0);
            acc2 = __builtin_amdgcn_mfma_f32_16x16x32_bf16(a, bfrag[0][2], acc2, 0, 0, 0);
            acc3 = __builtin_amdgcn_mfma_f32_16x16x32_bf16(a, bfrag[0][3], acc3, 0, 0, 0);
            a[0] = f2bf(c2.x); a[1] = f2bf(c2.y); a[2] = f2bf(c2.z); a[3] = f2bf(c2.w);
            a[4] = f2bf(c3.x); a[5] = f2bf(c3.y); a[6] = f2bf(c3.z); a[7] = f2bf(c3.w);
            acc0 = __builtin_amdgcn_mfma_f32_16x16x32_bf16(a, bfrag[1][0], acc0, 0, 0, 0);
            acc1 = __builtin_amdgcn_mfma_f32_16x16x32_bf16(a, bfrag[1][1], acc1, 0, 0, 0);
            acc2 = __builtin_amdgcn_mfma_f32_16x16x32_bf16(a, bfrag[1][2], acc2, 0, 0, 0);
            acc3 = __builtin_amdgcn_mfma_f32_16x16x32_bf16(a, bfrag[1][3], acc3, 0, 0, 0);
        }

#pragma unroll
        for (int r = 0; r < 4; ++r) {
            int e = ebase + g * 4 + r;
            const float* Kp = Khp + (size_t)sA[r] * 64 + q;
            const float* Qp = Qhp + (size_t)tA[r] * 64 + q;
            float pv = Kp[0] * Qp[0] * acc0[r]
                     + Kp[16] * Qp[16] * acc1[r]
                     + Kp[32] * Qp[32] * acc2[r]
                     + Kp[48] * Qp[48] * acc3[r];
            pv *= invs;
            pv += __shfl_xor(pv, 8, 64);
            float sc = __expf(fminf(fmaxf(pv, -5.0f), 5.0f));
            if ((lane & 8) == 0 && e < E) ssS[(size_t)e * HH + (q & 7)] = sc;
        }

        if (!hasN) break;
        c0 = n0; c1 = n1; c2 = n2; c3 = n3;
        wt = wtN; wtN = wtN2; rowN = rowN2;
    }
}

// ---------- output: cheb + gcn (Tx tables bf16, Tx0 = h f32) ----------
__global__ void k_out(const float* __restrict__ h, const unsigned short* __restrict__ Tx1b,
                      const unsigned short* __restrict__ Tx2b, const unsigned short* __restrict__ Tx3b,
                      const unsigned short* __restrict__ aggb, const float* __restrict__ fc,
                      const float* __restrict__ Wc, const float* __restrict__ bc,
                      const float* __restrict__ Wg, const float* __restrict__ bg,
                      int n, float* __restrict__ out) {
    __shared__ float sT[KORD][32][64];
    __shared__ float sA[32][64];
    int base = blockIdx.x * 32;
    int t = threadIdx.x;
    for (int idx = t; idx < 2048; idx += 256) {
        int ni = idx >> 6, j = idx & 63;
        int node = base + ni;
        if (node < n) {
            sT[0][ni][j] = fc[node] * h[node * 64 + j];
            sT[1][ni][j] = fc[n + node] * bf2f(Tx1b[node * 64 + j]);
            sT[2][ni][j] = fc[2 * n + node] * bf2f(Tx2b[node * 64 + j]);
            sT[3][ni][j] = fc[3 * n + node] * bf2f(Tx3b[node * 64 + j]);
            sA[ni][j] = bf2f(aggb[node * 64 + j]);
        } else {
            sT[0][ni][j] = 0.f; sT[1][ni][j] = 0.f;
            sT[2][ni][j] = 0.f; sT[3][ni][j] = 0.f;
            sA[ni][j] = 0.f;
        }
    }
    __syncthreads();
    int w = t >> 6, lane = t & 63;
    float acc[8];
#pragma unroll
    for (int i = 0; i < 8; ++i) acc[i] = 0.f;
#pragma unroll
    for (int k = 0; k < KORD; ++k) {
        for (int j = 0; j < 64; ++j) {
            float wv = Wc[k * 4096 + j * 64 + lane];
#pragma unroll
            for (int i = 0; i < 8; ++i) acc[i] = fmaf(sT[k][w * 8 + i][j], wv, acc[i]);
        }
    }
    float acc2[8];
#pragma unroll
    for (int i = 0; i < 8; ++i) acc2[i] = 0.f;
    for (int j = 0; j < 64; ++j) {
        float wv = Wg[j * 64 + lane];
#pragma unroll
        for (int i = 0; i < 8; ++i) acc2[i] = fmaf(sA[w * 8 + i][j], wv, acc2[i]);
    }
    float bcv = bc[lane], bgv = bg[lane];
#pragma unroll
    for (int i = 0; i < 8; ++i) {
        int node = base + w * 8 + i;
        if (node < n) {
            out[node * 192 + lane] = acc[i] + bcv;
            out[node * 192 + 64 + lane] = acc2[i] + bgv;
        }
    }
}

extern "C" void kernel_launch(void* const* d_in, const int* in_sizes, int n_in,
                              void* d_out, int out_size, void* d_ws, size_t ws_size,
                              hipStream_t stream) {
    const float* h  = (const float*)d_in[0];
    const float* p  = (const float*)d_in[1];
    const float* ef = (const float*)d_in[2];
    const float* ew = (const float*)d_in[3];
    const float* fc = (const float*)d_in[4];
    const int* esrc = (const int*)d_in[5];
    const int* edst = (const int*)d_in[6];
    const float* Wc = (const float*)d_in[7];
    const float* bc = (const float*)d_in[8];
    const float* Wg = (const float*)d_in[9];
    const float* bg = (const float*)d_in[10];
    const float* WQ = (const float*)d_in[11];
    const float* WK = (const float*)d_in[12];
    const float* WV = (const float*)d_in[13];
    const float* WE = (const float*)d_in[14];

    const int n = in_sizes[0] / DD;   // 50000
    const int E = in_sizes[5];        // 800000
    float* out = (float*)d_out;

    char* wsp = (char*)d_ws;
    size_t o = 0;
    auto alloc = [&](size_t bytes) -> void* {
        void* r = (void*)(wsp + o);
        o = (o + bytes + 255) & ~(size_t)255;
        return r;
    };
    int* deg     = (int*)alloc((size_t)n * 4);
    int* offsets = (int*)alloc((size_t)(n + 1) * 4);
    int* cursor  = (int*)alloc((size_t)n * 4);
    int4* payload = (int4*)alloc((size_t)E * 16);
    int* dsts    = (int*)alloc((size_t)E * 4);
    int* bsum    = (int*)alloc(1024 * 4);
    float* dinv  = (float*)alloc((size_t)n * 4);
    short* WETb  = (short*)alloc(4096 * 2);
    unsigned short* hb   = (unsigned short*)alloc((size_t)n * DD * 2);
    unsigned short* Tx1b = (unsigned short*)alloc((size_t)n * DD * 2);
    unsigned short* Tx2b = (unsigned short*)alloc((size_t)n * DD * 2);
    unsigned short* Tx3b = (unsigned short*)alloc((size_t)n * DD * 2);
    unsigned short* aggb = (unsigned short*)alloc((size_t)n * DD * 2);
    unsigned short* Vhb  = (unsigned short*)alloc((size_t)n * DD * 2);
    float* Qhp   = (float*)alloc((size_t)n * DD * 4);
    float* Khp   = (float*)alloc((size_t)n * DD * 4);
    float* ssS   = (float*)alloc((size_t)E * HH * 4);
    (void)ws_size; (void)n_in; (void)out_size;

    hipMemsetAsync(deg, 0, (size_t)n * 4, stream);

    int nb = (n + 255) / 256;
    k_count<<<(E + 255) / 256, 256, 0, stream>>>(edst, E, deg);
    k_blocksum<<<nb, 256, 0, stream>>>(deg, n, bsum);
    k_scan_bsum<<<1, 256, 0, stream>>>(bsum, nb);
    k_scan_final<<<nb, 256, 0, stream>>>(deg, bsum, n, E, offsets, cursor, dinv);
    k_scatter<<<(E + 255) / 256, 256, 0, stream>>>(edst, esrc, ew, dinv, E, cursor, payload);
    k_dstfill<<<nb, 256, 0, stream>>>(offsets, n, dsts);
    k_wetb<<<16, 256, 0, stream>>>(WE, WETb);

    k_qkv<<<(n + 31) / 32, 256, 0, stream>>>(h, p, WQ, WK, WV, n, Qhp, Khp, Vhb, hb);

    k_score<<<2048, 256, 0, stream>>>(ef, WETb, payload, dsts, Qhp, Khp, E, ssS);

    k_pass1<<<(n + 3) / 4, 256, 0, stream>>>(offsets, payload, dinv, hb, n, Tx1b, aggb);
    k_lap<<<(n + 3) / 4, 256, 0, stream>>>(offsets, payload, dinv, Tx1b, hb, 2.0f, -1.0f, n, Tx2b);
    k_lap3_attn<<<(n + 3) / 4, 256, 0, stream>>>(offsets, payload, dinv, Tx2b, Tx1b, Vhb,
                                                 ssS, n, Tx3b, out);

    k_out<<<(n + 31) / 32, 256, 0, stream>>>(h, Tx1b, Tx2b, Tx3b, aggb, fc, Wc, bc, Wg, bg, n, out);
}

// Round 11
// 343.065 us; speedup vs baseline: 2.5562x; 1.3258x over previous
//
#include <hip/hip_runtime.h>
#include <math.h>

#define DD 64
#define HH 8
#define KORD 4

typedef __attribute__((ext_vector_type(8))) short bf16x8;
typedef __attribute__((ext_vector_type(4))) float f32x4;
typedef __attribute__((ext_vector_type(8))) unsigned short u16x8;

__device__ __forceinline__ short f2bf(float f) {
    unsigned u = __builtin_bit_cast(unsigned, f);
    u = (u + 0x7fffu + ((u >> 16) & 1u)) >> 16;
    return (short)u;
}
__device__ __forceinline__ float bf2f(unsigned short u) {
    unsigned x = ((unsigned)u) << 16;
    return __builtin_bit_cast(float, x);
}
__device__ __forceinline__ float i2f(int v) { return __builtin_bit_cast(float, v); }

// ---------- CSR build ----------
__global__ void k_count(const int* __restrict__ dst, int E, int* __restrict__ deg) {
    int i = blockIdx.x * 256 + threadIdx.x;
    if (i < E) atomicAdd(&deg[dst[i]], 1);
}

__global__ void k_blocksum(const int* __restrict__ deg, int n, int* __restrict__ bsum) {
    __shared__ int s[256];
    int i = blockIdx.x * 256 + threadIdx.x;
    s[threadIdx.x] = (i < n) ? deg[i] : 0;
    __syncthreads();
    for (int off = 128; off > 0; off >>= 1) {
        if (threadIdx.x < off) s[threadIdx.x] += s[threadIdx.x + off];
        __syncthreads();
    }
    if (threadIdx.x == 0) bsum[blockIdx.x] = s[0];
}

__global__ void k_scan_bsum(int* __restrict__ bsum, int nb) {
    __shared__ int s[256];
    int t = threadIdx.x;
    int v = (t < nb) ? bsum[t] : 0;
    s[t] = v;
    __syncthreads();
    for (int off = 1; off < 256; off <<= 1) {
        int tmp = (t >= off) ? s[t - off] : 0;
        __syncthreads();
        s[t] += tmp;
        __syncthreads();
    }
    if (t < nb) bsum[t] = s[t] - v;  // exclusive
}

__global__ void k_scan_final(const int* __restrict__ deg, const int* __restrict__ bsum,
                             int n, int E, int* __restrict__ offsets,
                             int* __restrict__ cursor, float* __restrict__ dinv) {
    __shared__ int s[256];
    int t = threadIdx.x, i = blockIdx.x * 256 + t;
    int v = (i < n) ? deg[i] : 0;
    s[t] = v;
    __syncthreads();
    for (int off = 1; off < 256; off <<= 1) {
        int tmp = (t >= off) ? s[t - off] : 0;
        __syncthreads();
        s[t] += tmp;
        __syncthreads();
    }
    if (i < n) {
        int excl = s[t] - v + bsum[blockIdx.x];
        offsets[i] = excl;
        cursor[i] = excl;
        int dv = v < 1 ? 1 : v;
        dinv[i] = 1.0f / sqrtf((float)dv);
    }
    if (i == 0) offsets[n] = E;
}

// scatter: ONE 16B payload store per edge: {src, ew, dinv[src], orig_eid}
__global__ void k_scatter(const int* __restrict__ dst, const int* __restrict__ src,
                          const float* __restrict__ ew, const float* __restrict__ dinv,
                          int E, int* __restrict__ cursor, int4* __restrict__ payload) {
    int i = blockIdx.x * 256 + threadIdx.x;
    if (i < E) {
        int s = src[i], d = dst[i];
        int p = atomicAdd(&cursor[d], 1);
        int4 pl;
        pl.x = s;
        pl.y = __builtin_bit_cast(int, ew[i]);
        pl.z = __builtin_bit_cast(int, dinv[s]);
        pl.w = i;
        payload[p] = pl;
    }
}

__global__ void k_dstfill(const int* __restrict__ offsets, int n, int* __restrict__ dsts) {
    int node = blockIdx.x * 256 + threadIdx.x;
    if (node < n) {
        int beg = offsets[node], end = offsets[node + 1];
        for (int e = beg; e < end; ++e) dsts[e] = node;
    }
}

// hpb[node][0..63]=bf16(h), [64..127]=bf16(p)
__global__ void k_hpb(const float* __restrict__ h, const float* __restrict__ p,
                      int n, unsigned short* __restrict__ hpb) {
    int i = blockIdx.x * 256 + threadIdx.x;
    if (i < n * 64) {
        int node = i >> 6, j = i & 63;
        hpb[(size_t)node * 128 + j] = (unsigned short)f2bf(h[i]);
        hpb[(size_t)node * 128 + 64 + j] = (unsigned short)f2bf(p[i]);
    }
}

// All weight transposes to bf16 (one kernel).
// WQTp/WKTp: [col'][k] with head-permuted col'  (d(col) = ((q&7)<<3)+(q>>3)+(tc<<1))
// WVT: [col][k] unpermuted; WcT: [k4][col][kk]; WgT: [col][kk]; WETb: [col'][j]
__global__ void k_prep(const float* __restrict__ WQ, const float* __restrict__ WK,
                       const float* __restrict__ WV, const float* __restrict__ Wc,
                       const float* __restrict__ Wg, const float* __restrict__ WE,
                       unsigned short* __restrict__ WQTp, unsigned short* __restrict__ WKTp,
                       unsigned short* __restrict__ WVT, unsigned short* __restrict__ WcT,
                       unsigned short* __restrict__ WgT, short* __restrict__ WETb) {
    int i = blockIdx.x * 256 + threadIdx.x;
    if (i < 8192) {
        int col = i >> 7, k = i & 127;
        int q = col & 15, tc = col >> 4;
        int d = ((q & 7) << 3) + (q >> 3) + (tc << 1);
        WQTp[i] = (unsigned short)f2bf(WQ[k * 64 + d]);
        WKTp[i] = (unsigned short)f2bf(WK[k * 64 + d]);
        WVT[i]  = (unsigned short)f2bf(WV[k * 64 + col]);
    } else if (i < 8192 + 16384) {
        int j = i - 8192;
        int k4 = j >> 12, r = j & 4095;
        int col = r >> 6, kk = r & 63;
        WcT[j] = (unsigned short)f2bf(Wc[k4 * 4096 + kk * 64 + col]);
    } else if (i < 8192 + 16384 + 4096) {
        int j = i - 8192 - 16384;
        int col = j >> 6, kk = j & 63;
        WgT[j] = (unsigned short)f2bf(Wg[kk * 64 + col]);
    } else if (i < 8192 + 16384 + 4096 + 4096) {
        int j = i - 8192 - 16384 - 4096;
        int col = j >> 6, jj = j & 63;
        int q = col & 15, tc = col >> 4;
        int d = ((q & 7) << 3) + (q >> 3) + (tc << 1);
        WETb[j] = f2bf(WE[jj * 64 + d]);
    }
}

// ---------- pass 1: Tx1 = lap_mul(h), agg = sum ew*h[src]  (hpb stride 128) ----------
__global__ void k_pass1(const int* __restrict__ offsets, const int4* __restrict__ payload,
                        const float* __restrict__ dinv, const unsigned short* __restrict__ hpb,
                        int n, unsigned short* __restrict__ Tx1b,
                        unsigned short* __restrict__ aggb) {
    int w = threadIdx.x >> 6, lane = threadIdx.x & 63;
    int node = blockIdx.x * 4 + w;
    if (node >= n) return;
    int q = lane & 7, g = lane >> 3;
    int beg = offsets[node], end = offsets[node + 1];
    float aL[8], aG[8];
#pragma unroll
    for (int c = 0; c < 8; ++c) { aL[c] = 0.f; aG[c] = 0.f; }
    int e2 = beg;
    for (; e2 + 16 <= end; e2 += 16) {
        int4 pa = payload[e2 + g], pb = payload[e2 + 8 + g];
        u16x8 va = *(const u16x8*)(hpb + (size_t)pa.x * 128 + q * 8);
        u16x8 vb = *(const u16x8*)(hpb + (size_t)pb.x * 128 + q * 8);
        float da = i2f(pa.z), db = i2f(pb.z);
        float wa = i2f(pa.y), wb = i2f(pb.y);
#pragma unroll
        for (int c = 0; c < 8; ++c) {
            float fa = bf2f(va[c]), fb = bf2f(vb[c]);
            aL[c] = fmaf(da, fa, aL[c]); aL[c] = fmaf(db, fb, aL[c]);
            aG[c] = fmaf(wa, fa, aG[c]); aG[c] = fmaf(wb, fb, aG[c]);
        }
    }
    for (; e2 < end; e2 += 8) {
        int e = e2 + g;
        if (e < end) {
            int4 pl = payload[e];
            u16x8 v = *(const u16x8*)(hpb + (size_t)pl.x * 128 + q * 8);
            float d = i2f(pl.z), wv = i2f(pl.y);
#pragma unroll
            for (int c = 0; c < 8; ++c) {
                float f = bf2f(v[c]);
                aL[c] = fmaf(d, f, aL[c]);
                aG[c] = fmaf(wv, f, aG[c]);
            }
        }
    }
#pragma unroll
    for (int c = 0; c < 8; ++c) {
        aL[c] += __shfl_xor(aL[c], 8, 64);  aL[c] += __shfl_xor(aL[c], 16, 64);
        aL[c] += __shfl_xor(aL[c], 32, 64);
        aG[c] += __shfl_xor(aG[c], 8, 64);  aG[c] += __shfl_xor(aG[c], 16, 64);
        aG[c] += __shfl_xor(aG[c], 32, 64);
    }
    if (g == 0) {
        float dn = dinv[node];
        u16x8 o1, o2;
#pragma unroll
        for (int c = 0; c < 8; ++c) {
            o1[c] = (unsigned short)f2bf(-dn * aL[c]);
            o2[c] = (unsigned short)f2bf(aG[c]);
        }
        *(u16x8*)(Tx1b + (size_t)node * DD + q * 8) = o1;
        *(u16x8*)(aggb + (size_t)node * DD + q * 8) = o2;
    }
}

// ---------- out = alpha * lap_mul(x) + beta * prev  (strides xs/ps) ----------
__global__ void k_lap(const int* __restrict__ offsets, const int4* __restrict__ payload,
                      const float* __restrict__ dinv, const unsigned short* __restrict__ x,
                      int xs, const unsigned short* __restrict__ prev, int ps,
                      float alpha, float beta, int n, unsigned short* __restrict__ out) {
    int w = threadIdx.x >> 6, lane = threadIdx.x & 63;
    int node = blockIdx.x * 4 + w;
    if (node >= n) return;
    int q = lane & 7, g = lane >> 3;
    int beg = offsets[node], end = offsets[node + 1];
    float a[8];
#pragma unroll
    for (int c = 0; c < 8; ++c) a[c] = 0.f;
    int e2 = beg;
    for (; e2 + 16 <= end; e2 += 16) {
        int4 pa = payload[e2 + g], pb = payload[e2 + 8 + g];
        u16x8 va = *(const u16x8*)(x + (size_t)pa.x * xs + q * 8);
        u16x8 vb = *(const u16x8*)(x + (size_t)pb.x * xs + q * 8);
        float da = i2f(pa.z), db = i2f(pb.z);
#pragma unroll
        for (int c = 0; c < 8; ++c) {
            a[c] = fmaf(da, bf2f(va[c]), a[c]);
            a[c] = fmaf(db, bf2f(vb[c]), a[c]);
        }
    }
    for (; e2 < end; e2 += 8) {
        int e = e2 + g;
        if (e < end) {
            int4 pl = payload[e];
            u16x8 v = *(const u16x8*)(x + (size_t)pl.x * xs + q * 8);
            float d = i2f(pl.z);
#pragma unroll
            for (int c = 0; c < 8; ++c) a[c] = fmaf(d, bf2f(v[c]), a[c]);
        }
    }
#pragma unroll
    for (int c = 0; c < 8; ++c) {
        a[c] += __shfl_xor(a[c], 8, 64);  a[c] += __shfl_xor(a[c], 16, 64);
        a[c] += __shfl_xor(a[c], 32, 64);
    }
    if (g == 0) {
        float dn = dinv[node];
        u16x8 pv = *(const u16x8*)(prev + (size_t)node * ps + q * 8);
        u16x8 o;
#pragma unroll
        for (int c = 0; c < 8; ++c) {
            float v = alpha * (-dn * a[c]) + beta * bf2f(pv[c]);
            o[c] = (unsigned short)f2bf(v);
        }
        *(u16x8*)(out + (size_t)node * DD + q * 8) = o;
    }
}

// ---------- fused: Tx3 = 2*lap(Tx2) - Tx1  AND  attention aggregation ----------
__global__ void k_lap3_attn(const int* __restrict__ offsets, const int4* __restrict__ payload,
                            const float* __restrict__ dinv,
                            const unsigned short* __restrict__ Tx2b,
                            const unsigned short* __restrict__ Tx1b,
                            const unsigned short* __restrict__ Vhb,
                            const float* __restrict__ ssS,
                            int n, unsigned short* __restrict__ Tx3b,
                            float* __restrict__ out) {
    int w = threadIdx.x >> 6, lane = threadIdx.x & 63;
    int node = blockIdx.x * 4 + w;
    if (node >= n) return;
    int q = lane & 7, g = lane >> 3;  // head == q
    int beg = offsets[node], end = offsets[node + 1];
    float a[8], aV[8];
#pragma unroll
    for (int c = 0; c < 8; ++c) { a[c] = 0.f; aV[c] = 0.f; }
    float aZ = 0.f;
    int e2 = beg;
    for (; e2 + 16 <= end; e2 += 16) {
        int ea = e2 + g, eb = e2 + 8 + g;
        int4 pa = payload[ea], pb = payload[eb];
        u16x8 xa = *(const u16x8*)(Tx2b + (size_t)pa.x * DD + q * 8);
        u16x8 xb = *(const u16x8*)(Tx2b + (size_t)pb.x * DD + q * 8);
        u16x8 va = *(const u16x8*)(Vhb + (size_t)pa.x * DD + q * 8);
        u16x8 vb = *(const u16x8*)(Vhb + (size_t)pb.x * DD + q * 8);
        float sva = ssS[(size_t)ea * HH + q];
        float svb = ssS[(size_t)eb * HH + q];
        float da = i2f(pa.z), db = i2f(pb.z);
#pragma unroll
        for (int c = 0; c < 8; ++c) {
            a[c] = fmaf(da, bf2f(xa[c]), a[c]);
            a[c] = fmaf(db, bf2f(xb[c]), a[c]);
            aV[c] = fmaf(sva, bf2f(va[c]), aV[c]);
            aV[c] = fmaf(svb, bf2f(vb[c]), aV[c]);
        }
        aZ += sva + svb;
    }
    for (; e2 < end; e2 += 8) {
        int e = e2 + g;
        if (e < end) {
            int4 pl = payload[e];
            u16x8 x = *(const u16x8*)(Tx2b + (size_t)pl.x * DD + q * 8);
            u16x8 v = *(const u16x8*)(Vhb + (size_t)pl.x * DD + q * 8);
            float sv = ssS[(size_t)e * HH + q];
            float d = i2f(pl.z);
#pragma unroll
            for (int c = 0; c < 8; ++c) {
                a[c] = fmaf(d, bf2f(x[c]), a[c]);
                aV[c] = fmaf(sv, bf2f(v[c]), aV[c]);
            }
            aZ += sv;
        }
    }
#pragma unroll
    for (int c = 0; c < 8; ++c) {
        a[c] += __shfl_xor(a[c], 8, 64);   a[c] += __shfl_xor(a[c], 16, 64);
        a[c] += __shfl_xor(a[c], 32, 64);
        aV[c] += __shfl_xor(aV[c], 8, 64); aV[c] += __shfl_xor(aV[c], 16, 64);
        aV[c] += __shfl_xor(aV[c], 32, 64);
    }
    aZ += __shfl_xor(aZ, 8, 64); aZ += __shfl_xor(aZ, 16, 64); aZ += __shfl_xor(aZ, 32, 64);
    if (g == 0) {
        float dn = dinv[node];
        u16x8 pv = *(const u16x8*)(Tx1b + (size_t)node * DD + q * 8);
        u16x8 o;
        float inv = 1.0f / (aZ + 1e-6f);
        float4 o1, o2;
#pragma unroll
        for (int c = 0; c < 8; ++c) {
            float v = 2.0f * (-dn * a[c]) - bf2f(pv[c]);
            o[c] = (unsigned short)f2bf(v);
        }
        o1.x = aV[0] * inv; o1.y = aV[1] * inv; o1.z = aV[2] * inv; o1.w = aV[3] * inv;
        o2.x = aV[4] * inv; o2.y = aV[5] * inv; o2.z = aV[6] * inv; o2.w = aV[7] * inv;
        *(u16x8*)(Tx3b + (size_t)node * DD + q * 8) = o;
        *(float4*)(out + (size_t)node * 192 + 128 + q * 8) = o1;
        *(float4*)(out + (size_t)node * 192 + 128 + q * 8 + 4) = o2;
    }
}

// ---------- QKV via MFMA: one wave per 16 nodes, no LDS ----------
__global__ __launch_bounds__(256) void k_qkv(
        const unsigned short* __restrict__ hpb,
        const unsigned short* __restrict__ WQTp, const unsigned short* __restrict__ WKTp,
        const unsigned short* __restrict__ WVT, int n,
        float* __restrict__ Qhp, float* __restrict__ Khp, unsigned short* __restrict__ Vhb) {
    int lane = threadIdx.x & 63;
    int q = lane & 15, g = lane >> 4;
    int wid = (blockIdx.x * 256 + threadIdx.x) >> 6;
    int nb16 = wid * 16;
    if (nb16 >= n) return;
    int node = nb16 + q;
    int nodec = node < n ? node : n - 1;

    f32x4 aq[4], ak[4], av[4];
#pragma unroll
    for (int tc = 0; tc < 4; ++tc) {
        aq[tc] = (f32x4){0, 0, 0, 0}; ak[tc] = (f32x4){0, 0, 0, 0}; av[tc] = (f32x4){0, 0, 0, 0};
    }
#pragma unroll
    for (int kk = 0; kk < 4; ++kk) {
        bf16x8 a = *(const bf16x8*)(hpb + (size_t)nodec * 128 + kk * 32 + g * 8);
#pragma unroll
        for (int tc = 0; tc < 4; ++tc) {
            bf16x8 bq = *(const bf16x8*)(WQTp + (tc * 16 + q) * 128 + kk * 32 + g * 8);
            bf16x8 bk = *(const bf16x8*)(WKTp + (tc * 16 + q) * 128 + kk * 32 + g * 8);
            bf16x8 bv = *(const bf16x8*)(WVT + (tc * 16 + q) * 128 + kk * 32 + g * 8);
            aq[tc] = __builtin_amdgcn_mfma_f32_16x16x32_bf16(a, bq, aq[tc], 0, 0, 0);
            ak[tc] = __builtin_amdgcn_mfma_f32_16x16x32_bf16(a, bk, ak[tc], 0, 0, 0);
            av[tc] = __builtin_amdgcn_mfma_f32_16x16x32_bf16(a, bv, av[tc], 0, 0, 0);
        }
    }
#pragma unroll
    for (int tc = 0; tc < 4; ++tc) {
#pragma unroll
        for (int r = 0; r < 4; ++r) {
            int nd = nb16 + g * 4 + r;
            if (nd < n) {
                Qhp[(size_t)nd * 64 + tc * 16 + q] = aq[tc][r];
                Khp[(size_t)nd * 64 + tc * 16 + q] = ak[tc][r];
                Vhb[(size_t)nd * 64 + tc * 16 + q] = (unsigned short)f2bf(av[tc][r]);
            }
        }
    }
}

// ---------- per-edge scores: MFMA over dst-sorted edges, depth-2 pipeline ----------
__global__ __launch_bounds__(256) void k_score(
        const float* __restrict__ efeat, const short* __restrict__ WETb,
        const int4* __restrict__ payload, const int* __restrict__ dsts,
        const float* __restrict__ Qhp, const float* __restrict__ Khp,
        int E, float* __restrict__ ssS) {
    int lane = threadIdx.x & 63;
    int q = lane & 15, g = lane >> 4;

    bf16x8 bfrag[2][4];
#pragma unroll
    for (int kc = 0; kc < 2; ++kc)
#pragma unroll
        for (int tc = 0; tc < 4; ++tc)
            bfrag[kc][tc] = *(const bf16x8*)(WETb + (tc * 16 + q) * 64 + kc * 32 + g * 8);

    const float invs = 0.35355339059327373f;  // 1/sqrt(8)
    int nwaves = (gridDim.x * blockDim.x) >> 6;
    int wid = (blockIdx.x * blockDim.x + threadIdx.x) >> 6;
    int ntiles = (E + 15) >> 4;
    int wt = wid;
    if (wt >= ntiles) return;

    int er = wt * 16 + q;
    int rowC = payload[er < E ? er : E - 1].w;
    const float* epC = efeat + (size_t)rowC * 64;
    float4 c0 = *(const float4*)(epC + g * 8);
    float4 c1 = *(const float4*)(epC + g * 8 + 4);
    float4 c2 = *(const float4*)(epC + 32 + g * 8);
    float4 c3 = *(const float4*)(epC + 32 + g * 8 + 4);
    int wtN = wt + nwaves;
    int rowN = 0;
    if (wtN < ntiles) {
        int ern = wtN * 16 + q;
        rowN = payload[ern < E ? ern : E - 1].w;
    }

    while (true) {
        int ebase = wt * 16;
        bool hasN = wtN < ntiles;
        float4 n0, n1, n2, n3;
        if (hasN) {
            const float* epN = efeat + (size_t)rowN * 64;
            n0 = *(const float4*)(epN + g * 8);
            n1 = *(const float4*)(epN + g * 8 + 4);
            n2 = *(const float4*)(epN + 32 + g * 8);
            n3 = *(const float4*)(epN + 32 + g * 8 + 4);
        }
        int wtN2 = wtN + nwaves;
        int rowN2 = 0;
        if (wtN2 < ntiles) {
            int ern = wtN2 * 16 + q;
            rowN2 = payload[ern < E ? ern : E - 1].w;
        }
        int sA[4], tA[4];
#pragma unroll
        for (int r = 0; r < 4; ++r) {
            int e = ebase + g * 4 + r;
            int ec = e < E ? e : E - 1;
            sA[r] = payload[ec].x;
            tA[r] = dsts[ec];
        }

        f32x4 acc0 = {0, 0, 0, 0}, acc1 = {0, 0, 0, 0};
        f32x4 acc2 = {0, 0, 0, 0}, acc3 = {0, 0, 0, 0};
        {
            bf16x8 a;
            a[0] = f2bf(c0.x); a[1] = f2bf(c0.y); a[2] = f2bf(c0.z); a[3] = f2bf(c0.w);
            a[4] = f2bf(c1.x); a[5] = f2bf(c1.y); a[6] = f2bf(c1.z); a[7] = f2bf(c1.w);
            acc0 = __builtin_amdgcn_mfma_f32_16x16x32_bf16(a, bfrag[0][0], acc0, 0, 0, 0);
            acc1 = __builtin_amdgcn_mfma_f32_16x16x32_bf16(a, bfrag[0][1], acc1, 0, 0, 0);
            acc2 = __builtin_amdgcn_mfma_f32_16x16x32_bf16(a, bfrag[0][2], acc2, 0, 0, 0);
            acc3 = __builtin_amdgcn_mfma_f32_16x16x32_bf16(a, bfrag[0][3], acc3, 0, 0, 0);
            a[0] = f2bf(c2.x); a[1] = f2bf(c2.y); a[2] = f2bf(c2.z); a[3] = f2bf(c2.w);
            a[4] = f2bf(c3.x); a[5] = f2bf(c3.y); a[6] = f2bf(c3.z); a[7] = f2bf(c3.w);
            acc0 = __builtin_amdgcn_mfma_f32_16x16x32_bf16(a, bfrag[1][0], acc0, 0, 0, 0);
            acc1 = __builtin_amdgcn_mfma_f32_16x16x32_bf16(a, bfrag[1][1], acc1, 0, 0, 0);
            acc2 = __builtin_amdgcn_mfma_f32_16x16x32_bf16(a, bfrag[1][2], acc2, 0, 0, 0);
            acc3 = __builtin_amdgcn_mfma_f32_16x16x32_bf16(a, bfrag[1][3], acc3, 0, 0, 0);
        }

#pragma unroll
        for (int r = 0; r < 4; ++r) {
            int e = ebase + g * 4 + r;
            const float* Kp = Khp + (size_t)sA[r] * 64 + q;
            const float* Qp = Qhp + (size_t)tA[r] * 64 + q;
            float pv = Kp[0] * Qp[0] * acc0[r]
                     + Kp[16] * Qp[16] * acc1[r]
                     + Kp[32] * Qp[32] * acc2[r]
                     + Kp[48] * Qp[48] * acc3[r];
            pv *= invs;
            pv += __shfl_xor(pv, 8, 64);
            float sc = __expf(fminf(fmaxf(pv, -5.0f), 5.0f));
            if ((lane & 8) == 0 && e < E) ssS[(size_t)e * HH + (q & 7)] = sc;
        }

        if (!hasN) break;
        c0 = n0; c1 = n1; c2 = n2; c3 = n3;
        wt = wtN; wtN = wtN2; rowN = rowN2;
    }
}

// ---------- output via MFMA: cheb (4 fc-scaled tables) + gcn, one wave per 16 nodes ----------
__global__ __launch_bounds__(256) void k_out(
        const unsigned short* __restrict__ hpb, const unsigned short* __restrict__ Tx1b,
        const unsigned short* __restrict__ Tx2b, const unsigned short* __restrict__ Tx3b,
        const unsigned short* __restrict__ aggb, const float* __restrict__ fc,
        const unsigned short* __restrict__ WcT, const unsigned short* __restrict__ WgT,
        const float* __restrict__ bc, const float* __restrict__ bg,
        int n, float* __restrict__ out) {
    int lane = threadIdx.x & 63;
    int q = lane & 15, g = lane >> 4;
    int wid = (blockIdx.x * 256 + threadIdx.x) >> 6;
    int nb16 = wid * 16;
    if (nb16 >= n) return;
    int node = nb16 + q;
    int nodec = node < n ? node : n - 1;
    float f0 = fc[nodec], f1 = fc[n + nodec], f2 = fc[2 * n + nodec], f3 = fc[3 * n + nodec];

    f32x4 ac[4], ag[4];
#pragma unroll
    for (int tc = 0; tc < 4; ++tc) { ac[tc] = (f32x4){0,0,0,0}; ag[tc] = (f32x4){0,0,0,0}; }

#pragma unroll
    for (int kk = 0; kk < 2; ++kk) {
        int off = kk * 32 + g * 8;
        bf16x8 a0r = *(const bf16x8*)(hpb + (size_t)nodec * 128 + off);   // Tx0 = h
        bf16x8 a1r = *(const bf16x8*)(Tx1b + (size_t)nodec * 64 + off);
        bf16x8 a2r = *(const bf16x8*)(Tx2b + (size_t)nodec * 64 + off);
        bf16x8 a3r = *(const bf16x8*)(Tx3b + (size_t)nodec * 64 + off);
        bf16x8 aA  = *(const bf16x8*)(aggb + (size_t)nodec * 64 + off);
        bf16x8 a0, a1, a2, a3;
#pragma unroll
        for (int j = 0; j < 8; ++j) {
            a0[j] = f2bf(f0 * bf2f((unsigned short)a0r[j]));
            a1[j] = f2bf(f1 * bf2f((unsigned short)a1r[j]));
            a2[j] = f2bf(f2 * bf2f((unsigned short)a2r[j]));
            a3[j] = f2bf(f3 * bf2f((unsigned short)a3r[j]));
        }
#pragma unroll
        for (int tc = 0; tc < 4; ++tc) {
            bf16x8 b0 = *(const bf16x8*)(WcT + 0 * 4096 + (tc * 16 + q) * 64 + off);
            bf16x8 b1 = *(const bf16x8*)(WcT + 1 * 4096 + (tc * 16 + q) * 64 + off);
            bf16x8 b2 = *(const bf16x8*)(WcT + 2 * 4096 + (tc * 16 + q) * 64 + off);
            bf16x8 b3 = *(const bf16x8*)(WcT + 3 * 4096 + (tc * 16 + q) * 64 + off);
            bf16x8 bgw = *(const bf16x8*)(WgT + (tc * 16 + q) * 64 + off);
            ac[tc] = __builtin_amdgcn_mfma_f32_16x16x32_bf16(a0, b0, ac[tc], 0, 0, 0);
            ac[tc] = __builtin_amdgcn_mfma_f32_16x16x32_bf16(a1, b1, ac[tc], 0, 0, 0);
            ac[tc] = __builtin_amdgcn_mfma_f32_16x16x32_bf16(a2, b2, ac[tc], 0, 0, 0);
            ac[tc] = __builtin_amdgcn_mfma_f32_16x16x32_bf16(a3, b3, ac[tc], 0, 0, 0);
            ag[tc] = __builtin_amdgcn_mfma_f32_16x16x32_bf16(aA, bgw, ag[tc], 0, 0, 0);
        }
    }
#pragma unroll
    for (int tc = 0; tc < 4; ++tc) {
        float bcv = bc[tc * 16 + q], bgv = bg[tc * 16 + q];
#pragma unroll
        for (int r = 0; r < 4; ++r) {
            int nd = nb16 + g * 4 + r;
            if (nd < n) {
                out[(size_t)nd * 192 + tc * 16 + q] = ac[tc][r] + bcv;
                out[(size_t)nd * 192 + 64 + tc * 16 + q] = ag[tc][r] + bgv;
            }
        }
    }
}

extern "C" void kernel_launch(void* const* d_in, const int* in_sizes, int n_in,
                              void* d_out, int out_size, void* d_ws, size_t ws_size,
                              hipStream_t stream) {
    const float* h  = (const float*)d_in[0];
    const float* p  = (const float*)d_in[1];
    const float* ef = (const float*)d_in[2];
    const float* ew = (const float*)d_in[3];
    const float* fc = (const float*)d_in[4];
    const int* esrc = (const int*)d_in[5];
    const int* edst = (const int*)d_in[6];
    const float* Wc = (const float*)d_in[7];
    const float* bc = (const float*)d_in[8];
    const float* Wg = (const float*)d_in[9];
    const float* bg = (const float*)d_in[10];
    const float* WQ = (const float*)d_in[11];
    const float* WK = (const float*)d_in[12];
    const float* WV = (const float*)d_in[13];
    const float* WE = (const float*)d_in[14];

    const int n = in_sizes[0] / DD;   // 50000
    const int E = in_sizes[5];        // 800000
    float* out = (float*)d_out;

    char* wsp = (char*)d_ws;
    size_t o = 0;
    auto alloc = [&](size_t bytes) -> void* {
        void* r = (void*)(wsp + o);
        o = (o + bytes + 255) & ~(size_t)255;
        return r;
    };
    int* deg     = (int*)alloc((size_t)n * 4);
    int* offsets = (int*)alloc((size_t)(n + 1) * 4);
    int* cursor  = (int*)alloc((size_t)n * 4);
    int4* payload = (int4*)alloc((size_t)E * 16);
    int* dsts    = (int*)alloc((size_t)E * 4);
    int* bsum    = (int*)alloc(1024 * 4);
    float* dinv  = (float*)alloc((size_t)n * 4);
    short* WETb  = (short*)alloc(4096 * 2);
    unsigned short* WQTp = (unsigned short*)alloc(8192 * 2);
    unsigned short* WKTp = (unsigned short*)alloc(8192 * 2);
    unsigned short* WVT  = (unsigned short*)alloc(8192 * 2);
    unsigned short* WcT  = (unsigned short*)alloc(16384 * 2);
    unsigned short* WgT  = (unsigned short*)alloc(4096 * 2);
    unsigned short* hpb  = (unsigned short*)alloc((size_t)n * 128 * 2);
    unsigned short* Tx1b = (unsigned short*)alloc((size_t)n * DD * 2);
    unsigned short* Tx2b = (unsigned short*)alloc((size_t)n * DD * 2);
    unsigned short* Tx3b = (unsigned short*)alloc((size_t)n * DD * 2);
    unsigned short* aggb = (unsigned short*)alloc((size_t)n * DD * 2);
    unsigned short* Vhb  = (unsigned short*)alloc((size_t)n * DD * 2);
    float* Qhp   = (float*)alloc((size_t)n * DD * 4);
    float* Khp   = (float*)alloc((size_t)n * DD * 4);
    float* ssS   = (float*)alloc((size_t)E * HH * 4);
    (void)ws_size; (void)n_in; (void)out_size;

    hipMemsetAsync(deg, 0, (size_t)n * 4, stream);

    int nb = (n + 255) / 256;
    k_count<<<(E + 255) / 256, 256, 0, stream>>>(edst, E, deg);
    k_blocksum<<<nb, 256, 0, stream>>>(deg, n, bsum);
    k_scan_bsum<<<1, 256, 0, stream>>>(bsum, nb);
    k_scan_final<<<nb, 256, 0, stream>>>(deg, bsum, n, E, offsets, cursor, dinv);
    k_scatter<<<(E + 255) / 256, 256, 0, stream>>>(edst, esrc, ew, dinv, E, cursor, payload);
    k_dstfill<<<nb, 256, 0, stream>>>(offsets, n, dsts);
    k_prep<<<128, 256, 0, stream>>>(WQ, WK, WV, Wc, Wg, WE, WQTp, WKTp, WVT, WcT, WgT, WETb);
    k_hpb<<<(n * 64 + 255) / 256, 256, 0, stream>>>(h, p, n, hpb);

    int qkv_waves = (n + 15) / 16;
    k_qkv<<<(qkv_waves + 3) / 4, 256, 0, stream>>>(hpb, WQTp, WKTp, WVT, n, Qhp, Khp, Vhb);

    k_score<<<2048, 256, 0, stream>>>(ef, WETb, payload, dsts, Qhp, Khp, E, ssS);

    k_pass1<<<(n + 3) / 4, 256, 0, stream>>>(offsets, payload, dinv, hpb, n, Tx1b, aggb);
    k_lap<<<(n + 3) / 4, 256, 0, stream>>>(offsets, payload, dinv, Tx1b, 64, hpb, 128,
                                           2.0f, -1.0f, n, Tx2b);
    k_lap3_attn<<<(n + 3) / 4, 256, 0, stream>>>(offsets, payload, dinv, Tx2b, Tx1b, Vhb,
                                                 ssS, n, Tx3b, out);

    int out_waves = (n + 15) / 16;
    k_out<<<(out_waves + 3) / 4, 256, 0, stream>>>(hpb, Tx1b, Tx2b, Tx3b, aggb, fc,
                                                   WcT, WgT, bc, bg, n, out);
}

// Round 12
// 332.520 us; speedup vs baseline: 2.6372x; 1.0317x over previous
//
#include <hip/hip_runtime.h>
#include <math.h>

#define DD 64
#define HH 8
#define KORD 4

typedef __attribute__((ext_vector_type(8))) short bf16x8;
typedef __attribute__((ext_vector_type(4))) float f32x4;
typedef __attribute__((ext_vector_type(8))) unsigned short u16x8;
typedef __attribute__((ext_vector_type(4))) unsigned short u16x4;

__device__ __forceinline__ short f2bf(float f) {
    unsigned u = __builtin_bit_cast(unsigned, f);
    u = (u + 0x7fffu + ((u >> 16) & 1u)) >> 16;
    return (short)u;
}
__device__ __forceinline__ float bf2f(unsigned short u) {
    unsigned x = ((unsigned)u) << 16;
    return __builtin_bit_cast(float, x);
}
__device__ __forceinline__ float i2f(int v) { return __builtin_bit_cast(float, v); }

// ---------- CSR build ----------
__global__ void k_count(const int* __restrict__ dst, int E, int* __restrict__ deg) {
    int i = blockIdx.x * 256 + threadIdx.x;
    if (i < E) atomicAdd(&deg[dst[i]], 1);
}

__global__ void k_blocksum(const int* __restrict__ deg, int n, int* __restrict__ bsum) {
    __shared__ int s[256];
    int i = blockIdx.x * 256 + threadIdx.x;
    s[threadIdx.x] = (i < n) ? deg[i] : 0;
    __syncthreads();
    for (int off = 128; off > 0; off >>= 1) {
        if (threadIdx.x < off) s[threadIdx.x] += s[threadIdx.x + off];
        __syncthreads();
    }
    if (threadIdx.x == 0) bsum[blockIdx.x] = s[0];
}

__global__ void k_scan_bsum(int* __restrict__ bsum, int nb) {
    __shared__ int s[256];
    int t = threadIdx.x;
    int v = (t < nb) ? bsum[t] : 0;
    s[t] = v;
    __syncthreads();
    for (int off = 1; off < 256; off <<= 1) {
        int tmp = (t >= off) ? s[t - off] : 0;
        __syncthreads();
        s[t] += tmp;
        __syncthreads();
    }
    if (t < nb) bsum[t] = s[t] - v;  // exclusive
}

__global__ void k_scan_final(const int* __restrict__ deg, const int* __restrict__ bsum,
                             int n, int E, int* __restrict__ offsets,
                             int* __restrict__ cursor, float* __restrict__ dinv) {
    __shared__ int s[256];
    int t = threadIdx.x, i = blockIdx.x * 256 + t;
    int v = (i < n) ? deg[i] : 0;
    s[t] = v;
    __syncthreads();
    for (int off = 1; off < 256; off <<= 1) {
        int tmp = (t >= off) ? s[t - off] : 0;
        __syncthreads();
        s[t] += tmp;
        __syncthreads();
    }
    if (i < n) {
        int excl = s[t] - v + bsum[blockIdx.x];
        offsets[i] = excl;
        cursor[i] = excl;
        int dv = v < 1 ? 1 : v;
        dinv[i] = 1.0f / sqrtf((float)dv);
    }
    if (i == 0) offsets[n] = E;
}

// scatter: ONE 16B payload store per edge: {src, ew, dinv[src], orig_eid}
__global__ void k_scatter(const int* __restrict__ dst, const int* __restrict__ src,
                          const float* __restrict__ ew, const float* __restrict__ dinv,
                          int E, int* __restrict__ cursor, int4* __restrict__ payload) {
    int i = blockIdx.x * 256 + threadIdx.x;
    if (i < E) {
        int s = src[i], d = dst[i];
        int p = atomicAdd(&cursor[d], 1);
        int4 pl;
        pl.x = s;
        pl.y = __builtin_bit_cast(int, ew[i]);
        pl.z = __builtin_bit_cast(int, dinv[s]);
        pl.w = i;
        payload[p] = pl;
    }
}

__global__ void k_dstfill(const int* __restrict__ offsets, int n, int* __restrict__ dsts) {
    int node = blockIdx.x * 256 + threadIdx.x;
    if (node < n) {
        int beg = offsets[node], end = offsets[node + 1];
        for (int e = beg; e < end; ++e) dsts[e] = node;
    }
}

// hpb[node][0..63]=bf16(h), [64..127]=bf16(p)
__global__ void k_hpb(const float* __restrict__ h, const float* __restrict__ p,
                      int n, unsigned short* __restrict__ hpb) {
    int i = blockIdx.x * 256 + threadIdx.x;
    if (i < n * 64) {
        int node = i >> 6, j = i & 63;
        hpb[(size_t)node * 128 + j] = (unsigned short)f2bf(h[i]);
        hpb[(size_t)node * 128 + 64 + j] = (unsigned short)f2bf(p[i]);
    }
}

// All weight transposes to bf16 (one kernel).
__global__ void k_prep(const float* __restrict__ WQ, const float* __restrict__ WK,
                       const float* __restrict__ WV, const float* __restrict__ Wc,
                       const float* __restrict__ Wg, const float* __restrict__ WE,
                       unsigned short* __restrict__ WQTp, unsigned short* __restrict__ WKTp,
                       unsigned short* __restrict__ WVT, unsigned short* __restrict__ WcT,
                       unsigned short* __restrict__ WgT, short* __restrict__ WETb) {
    int i = blockIdx.x * 256 + threadIdx.x;
    if (i < 8192) {
        int col = i >> 7, k = i & 127;
        int q = col & 15, tc = col >> 4;
        int d = ((q & 7) << 3) + (q >> 3) + (tc << 1);
        WQTp[i] = (unsigned short)f2bf(WQ[k * 64 + d]);
        WKTp[i] = (unsigned short)f2bf(WK[k * 64 + d]);
        WVT[i]  = (unsigned short)f2bf(WV[k * 64 + col]);
    } else if (i < 8192 + 16384) {
        int j = i - 8192;
        int k4 = j >> 12, r = j & 4095;
        int col = r >> 6, kk = r & 63;
        WcT[j] = (unsigned short)f2bf(Wc[k4 * 4096 + kk * 64 + col]);
    } else if (i < 8192 + 16384 + 4096) {
        int j = i - 8192 - 16384;
        int col = j >> 6, kk = j & 63;
        WgT[j] = (unsigned short)f2bf(Wg[kk * 64 + col]);
    } else if (i < 8192 + 16384 + 4096 + 4096) {
        int j = i - 8192 - 16384 - 4096;
        int col = j >> 6, jj = j & 63;
        int q = col & 15, tc = col >> 4;
        int d = ((q & 7) << 3) + (q >> 3) + (tc << 1);
        WETb[j] = f2bf(WE[jj * 64 + d]);
    }
}

// ---------- pass 1: Tx1 = lap_mul(h), agg = sum ew*h[src]  (hpb stride 128) ----------
__global__ void k_pass1(const int* __restrict__ offsets, const int4* __restrict__ payload,
                        const float* __restrict__ dinv, const unsigned short* __restrict__ hpb,
                        int n, unsigned short* __restrict__ Tx1b,
                        unsigned short* __restrict__ aggb) {
    int w = threadIdx.x >> 6, lane = threadIdx.x & 63;
    int node = blockIdx.x * 4 + w;
    if (node >= n) return;
    int q = lane & 7, g = lane >> 3;
    int beg = offsets[node], end = offsets[node + 1];
    float aL[8], aG[8];
#pragma unroll
    for (int c = 0; c < 8; ++c) { aL[c] = 0.f; aG[c] = 0.f; }
    int e2 = beg;
    for (; e2 + 16 <= end; e2 += 16) {
        int4 pa = payload[e2 + g], pb = payload[e2 + 8 + g];
        u16x8 va = *(const u16x8*)(hpb + (size_t)pa.x * 128 + q * 8);
        u16x8 vb = *(const u16x8*)(hpb + (size_t)pb.x * 128 + q * 8);
        float da = i2f(pa.z), db = i2f(pb.z);
        float wa = i2f(pa.y), wb = i2f(pb.y);
#pragma unroll
        for (int c = 0; c < 8; ++c) {
            float fa = bf2f(va[c]), fb = bf2f(vb[c]);
            aL[c] = fmaf(da, fa, aL[c]); aL[c] = fmaf(db, fb, aL[c]);
            aG[c] = fmaf(wa, fa, aG[c]); aG[c] = fmaf(wb, fb, aG[c]);
        }
    }
    for (; e2 < end; e2 += 8) {
        int e = e2 + g;
        if (e < end) {
            int4 pl = payload[e];
            u16x8 v = *(const u16x8*)(hpb + (size_t)pl.x * 128 + q * 8);
            float d = i2f(pl.z), wv = i2f(pl.y);
#pragma unroll
            for (int c = 0; c < 8; ++c) {
                float f = bf2f(v[c]);
                aL[c] = fmaf(d, f, aL[c]);
                aG[c] = fmaf(wv, f, aG[c]);
            }
        }
    }
#pragma unroll
    for (int c = 0; c < 8; ++c) {
        aL[c] += __shfl_xor(aL[c], 8, 64);  aL[c] += __shfl_xor(aL[c], 16, 64);
        aL[c] += __shfl_xor(aL[c], 32, 64);
        aG[c] += __shfl_xor(aG[c], 8, 64);  aG[c] += __shfl_xor(aG[c], 16, 64);
        aG[c] += __shfl_xor(aG[c], 32, 64);
    }
    if (g == 0) {
        float dn = dinv[node];
        u16x8 o1, o2;
#pragma unroll
        for (int c = 0; c < 8; ++c) {
            o1[c] = (unsigned short)f2bf(-dn * aL[c]);
            o2[c] = (unsigned short)f2bf(aG[c]);
        }
        *(u16x8*)(Tx1b + (size_t)node * DD + q * 8) = o1;
        *(u16x8*)(aggb + (size_t)node * DD + q * 8) = o2;
    }
}

// ---------- out = alpha * lap_mul(x) + beta * prev  (strides xs/ps) ----------
__global__ void k_lap(const int* __restrict__ offsets, const int4* __restrict__ payload,
                      const float* __restrict__ dinv, const unsigned short* __restrict__ x,
                      int xs, const unsigned short* __restrict__ prev, int ps,
                      float alpha, float beta, int n, unsigned short* __restrict__ out) {
    int w = threadIdx.x >> 6, lane = threadIdx.x & 63;
    int node = blockIdx.x * 4 + w;
    if (node >= n) return;
    int q = lane & 7, g = lane >> 3;
    int beg = offsets[node], end = offsets[node + 1];
    float a[8];
#pragma unroll
    for (int c = 0; c < 8; ++c) a[c] = 0.f;
    int e2 = beg;
    for (; e2 + 16 <= end; e2 += 16) {
        int4 pa = payload[e2 + g], pb = payload[e2 + 8 + g];
        u16x8 va = *(const u16x8*)(x + (size_t)pa.x * xs + q * 8);
        u16x8 vb = *(const u16x8*)(x + (size_t)pb.x * xs + q * 8);
        float da = i2f(pa.z), db = i2f(pb.z);
#pragma unroll
        for (int c = 0; c < 8; ++c) {
            a[c] = fmaf(da, bf2f(va[c]), a[c]);
            a[c] = fmaf(db, bf2f(vb[c]), a[c]);
        }
    }
    for (; e2 < end; e2 += 8) {
        int e = e2 + g;
        if (e < end) {
            int4 pl = payload[e];
            u16x8 v = *(const u16x8*)(x + (size_t)pl.x * xs + q * 8);
            float d = i2f(pl.z);
#pragma unroll
            for (int c = 0; c < 8; ++c) a[c] = fmaf(d, bf2f(v[c]), a[c]);
        }
    }
#pragma unroll
    for (int c = 0; c < 8; ++c) {
        a[c] += __shfl_xor(a[c], 8, 64);  a[c] += __shfl_xor(a[c], 16, 64);
        a[c] += __shfl_xor(a[c], 32, 64);
    }
    if (g == 0) {
        float dn = dinv[node];
        u16x8 pv = *(const u16x8*)(prev + (size_t)node * ps + q * 8);
        u16x8 o;
#pragma unroll
        for (int c = 0; c < 8; ++c) {
            float v = alpha * (-dn * a[c]) + beta * bf2f(pv[c]);
            o[c] = (unsigned short)f2bf(v);
        }
        *(u16x8*)(out + (size_t)node * DD + q * 8) = o;
    }
}

// ---------- fused: Tx3 = 2*lap(Tx2) - Tx1  AND  attention aggregation (ss bf16) ----------
__global__ void k_lap3_attn(const int* __restrict__ offsets, const int4* __restrict__ payload,
                            const float* __restrict__ dinv,
                            const unsigned short* __restrict__ Tx2b,
                            const unsigned short* __restrict__ Tx1b,
                            const unsigned short* __restrict__ Vhb,
                            const unsigned short* __restrict__ ssb,
                            int n, unsigned short* __restrict__ Tx3b,
                            float* __restrict__ out) {
    int w = threadIdx.x >> 6, lane = threadIdx.x & 63;
    int node = blockIdx.x * 4 + w;
    if (node >= n) return;
    int q = lane & 7, g = lane >> 3;  // head == q
    int beg = offsets[node], end = offsets[node + 1];
    float a[8], aV[8];
#pragma unroll
    for (int c = 0; c < 8; ++c) { a[c] = 0.f; aV[c] = 0.f; }
    float aZ = 0.f;
    int e2 = beg;
    for (; e2 + 16 <= end; e2 += 16) {
        int ea = e2 + g, eb = e2 + 8 + g;
        int4 pa = payload[ea], pb = payload[eb];
        u16x8 xa = *(const u16x8*)(Tx2b + (size_t)pa.x * DD + q * 8);
        u16x8 xb = *(const u16x8*)(Tx2b + (size_t)pb.x * DD + q * 8);
        u16x8 va = *(const u16x8*)(Vhb + (size_t)pa.x * DD + q * 8);
        u16x8 vb = *(const u16x8*)(Vhb + (size_t)pb.x * DD + q * 8);
        float sva = bf2f(ssb[(size_t)ea * HH + q]);
        float svb = bf2f(ssb[(size_t)eb * HH + q]);
        float da = i2f(pa.z), db = i2f(pb.z);
#pragma unroll
        for (int c = 0; c < 8; ++c) {
            a[c] = fmaf(da, bf2f(xa[c]), a[c]);
            a[c] = fmaf(db, bf2f(xb[c]), a[c]);
            aV[c] = fmaf(sva, bf2f(va[c]), aV[c]);
            aV[c] = fmaf(svb, bf2f(vb[c]), aV[c]);
        }
        aZ += sva + svb;
    }
    for (; e2 < end; e2 += 8) {
        int e = e2 + g;
        if (e < end) {
            int4 pl = payload[e];
            u16x8 x = *(const u16x8*)(Tx2b + (size_t)pl.x * DD + q * 8);
            u16x8 v = *(const u16x8*)(Vhb + (size_t)pl.x * DD + q * 8);
            float sv = bf2f(ssb[(size_t)e * HH + q]);
            float d = i2f(pl.z);
#pragma unroll
            for (int c = 0; c < 8; ++c) {
                a[c] = fmaf(d, bf2f(x[c]), a[c]);
                aV[c] = fmaf(sv, bf2f(v[c]), aV[c]);
            }
            aZ += sv;
        }
    }
#pragma unroll
    for (int c = 0; c < 8; ++c) {
        a[c] += __shfl_xor(a[c], 8, 64);   a[c] += __shfl_xor(a[c], 16, 64);
        a[c] += __shfl_xor(a[c], 32, 64);
        aV[c] += __shfl_xor(aV[c], 8, 64); aV[c] += __shfl_xor(aV[c], 16, 64);
        aV[c] += __shfl_xor(aV[c], 32, 64);
    }
    aZ += __shfl_xor(aZ, 8, 64); aZ += __shfl_xor(aZ, 16, 64); aZ += __shfl_xor(aZ, 32, 64);
    if (g == 0) {
        float dn = dinv[node];
        u16x8 pv = *(const u16x8*)(Tx1b + (size_t)node * DD + q * 8);
        u16x8 o;
        float inv = 1.0f / (aZ + 1e-6f);
        float4 o1, o2;
#pragma unroll
        for (int c = 0; c < 8; ++c) {
            float v = 2.0f * (-dn * a[c]) - bf2f(pv[c]);
            o[c] = (unsigned short)f2bf(v);
        }
        o1.x = aV[0] * inv; o1.y = aV[1] * inv; o1.z = aV[2] * inv; o1.w = aV[3] * inv;
        o2.x = aV[4] * inv; o2.y = aV[5] * inv; o2.z = aV[6] * inv; o2.w = aV[7] * inv;
        *(u16x8*)(Tx3b + (size_t)node * DD + q * 8) = o;
        *(float4*)(out + (size_t)node * 192 + 128 + q * 8) = o1;
        *(float4*)(out + (size_t)node * 192 + 128 + q * 8 + 4) = o2;
    }
}

// ---------- QKV via MFMA: K/Q stored bf16 in lane-contiguous layout [node][q*4+tc] ----------
__global__ __launch_bounds__(256) void k_qkv(
        const unsigned short* __restrict__ hpb,
        const unsigned short* __restrict__ WQTp, const unsigned short* __restrict__ WKTp,
        const unsigned short* __restrict__ WVT, int n,
        unsigned short* __restrict__ Qhb, unsigned short* __restrict__ Khb,
        unsigned short* __restrict__ Vhb) {
    int lane = threadIdx.x & 63;
    int q = lane & 15, g = lane >> 4;
    int wid = (blockIdx.x * 256 + threadIdx.x) >> 6;
    int nb16 = wid * 16;
    if (nb16 >= n) return;
    int node = nb16 + q;
    int nodec = node < n ? node : n - 1;

    f32x4 aq[4], ak[4], av[4];
#pragma unroll
    for (int tc = 0; tc < 4; ++tc) {
        aq[tc] = (f32x4){0, 0, 0, 0}; ak[tc] = (f32x4){0, 0, 0, 0}; av[tc] = (f32x4){0, 0, 0, 0};
    }
#pragma unroll
    for (int kk = 0; kk < 4; ++kk) {
        bf16x8 a = *(const bf16x8*)(hpb + (size_t)nodec * 128 + kk * 32 + g * 8);
#pragma unroll
        for (int tc = 0; tc < 4; ++tc) {
            bf16x8 bq = *(const bf16x8*)(WQTp + (tc * 16 + q) * 128 + kk * 32 + g * 8);
            bf16x8 bk = *(const bf16x8*)(WKTp + (tc * 16 + q) * 128 + kk * 32 + g * 8);
            bf16x8 bv = *(const bf16x8*)(WVT + (tc * 16 + q) * 128 + kk * 32 + g * 8);
            aq[tc] = __builtin_amdgcn_mfma_f32_16x16x32_bf16(a, bq, aq[tc], 0, 0, 0);
            ak[tc] = __builtin_amdgcn_mfma_f32_16x16x32_bf16(a, bk, ak[tc], 0, 0, 0);
            av[tc] = __builtin_amdgcn_mfma_f32_16x16x32_bf16(a, bv, av[tc], 0, 0, 0);
        }
    }
#pragma unroll
    for (int r = 0; r < 4; ++r) {
        int nd = nb16 + g * 4 + r;
        if (nd < n) {
            u16x4 oq, ok;
#pragma unroll
            for (int tc = 0; tc < 4; ++tc) {
                oq[tc] = (unsigned short)f2bf(aq[tc][r]);
                ok[tc] = (unsigned short)f2bf(ak[tc][r]);
            }
            *(u16x4*)(Qhb + (size_t)nd * 64 + q * 4) = oq;
            *(u16x4*)(Khb + (size_t)nd * 64 + q * 4) = ok;
#pragma unroll
            for (int tc = 0; tc < 4; ++tc)
                Vhb[(size_t)nd * 64 + tc * 16 + q] = (unsigned short)f2bf(av[tc][r]);
        }
    }
}

// ---------- per-edge scores: MFMA, depth-2 pipeline, bf16 K/Q u16x4 epilogue ----------
__global__ __launch_bounds__(256) void k_score(
        const float* __restrict__ efeat, const short* __restrict__ WETb,
        const int4* __restrict__ payload, const int* __restrict__ dsts,
        const unsigned short* __restrict__ Qhb, const unsigned short* __restrict__ Khb,
        int E, unsigned short* __restrict__ ssb) {
    int lane = threadIdx.x & 63;
    int q = lane & 15, g = lane >> 4;

    bf16x8 bfrag[2][4];
#pragma unroll
    for (int kc = 0; kc < 2; ++kc)
#pragma unroll
        for (int tc = 0; tc < 4; ++tc)
            bfrag[kc][tc] = *(const bf16x8*)(WETb + (tc * 16 + q) * 64 + kc * 32 + g * 8);

    const float invs = 0.35355339059327373f;  // 1/sqrt(8)
    int nwaves = (gridDim.x * blockDim.x) >> 6;
    int wid = (blockIdx.x * blockDim.x + threadIdx.x) >> 6;
    int ntiles = (E + 15) >> 4;
    int wt = wid;
    if (wt >= ntiles) return;

    int er = wt * 16 + q;
    int rowC = payload[er < E ? er : E - 1].w;
    const float* epC = efeat + (size_t)rowC * 64;
    float4 c0 = *(const float4*)(epC + g * 8);
    float4 c1 = *(const float4*)(epC + g * 8 + 4);
    float4 c2 = *(const float4*)(epC + 32 + g * 8);
    float4 c3 = *(const float4*)(epC + 32 + g * 8 + 4);
    int wtN = wt + nwaves;
    int rowN = 0;
    if (wtN < ntiles) {
        int ern = wtN * 16 + q;
        rowN = payload[ern < E ? ern : E - 1].w;
    }

    while (true) {
        int ebase = wt * 16;
        bool hasN = wtN < ntiles;
        float4 n0, n1, n2, n3;
        if (hasN) {
            const float* epN = efeat + (size_t)rowN * 64;
            n0 = *(const float4*)(epN + g * 8);
            n1 = *(const float4*)(epN + g * 8 + 4);
            n2 = *(const float4*)(epN + 32 + g * 8);
            n3 = *(const float4*)(epN + 32 + g * 8 + 4);
        }
        int wtN2 = wtN + nwaves;
        int rowN2 = 0;
        if (wtN2 < ntiles) {
            int ern = wtN2 * 16 + q;
            rowN2 = payload[ern < E ? ern : E - 1].w;
        }
        // issue K/Q row loads for the epilogue (u16x4 per edge-r)
        u16x4 kv4[4], qv4[4];
#pragma unroll
        for (int r = 0; r < 4; ++r) {
            int e = ebase + g * 4 + r;
            int ec = e < E ? e : E - 1;
            int sA = payload[ec].x;
            int tA = dsts[ec];
            kv4[r] = *(const u16x4*)(Khb + (size_t)sA * 64 + q * 4);
            qv4[r] = *(const u16x4*)(Qhb + (size_t)tA * 64 + q * 4);
        }

        f32x4 acc0 = {0, 0, 0, 0}, acc1 = {0, 0, 0, 0};
        f32x4 acc2 = {0, 0, 0, 0}, acc3 = {0, 0, 0, 0};
        {
            bf16x8 a;
            a[0] = f2bf(c0.x); a[1] = f2bf(c0.y); a[2] = f2bf(c0.z); a[3] = f2bf(c0.w);
            a[4] = f2bf(c1.x); a[5] = f2bf(c1.y); a[6] = f2bf(c1.z); a[7] = f2bf(c1.w);
            acc0 = __builtin_amdgcn_mfma_f32_16x16x32_bf16(a, bfrag[0][0], acc0, 0, 0, 0);
            acc1 = __builtin_amdgcn_mfma_f32_16x16x32_bf16(a, bfrag[0][1], acc1, 0, 0, 0);
            acc2 = __builtin_amdgcn_mfma_f32_16x16x32_bf16(a, bfrag[0][2], acc2, 0, 0, 0);
            acc3 = __builtin_amdgcn_mfma_f32_16x16x32_bf16(a, bfrag[0][3], acc3, 0, 0, 0);
            a[0] = f2bf(c2.x); a[1] = f2bf(c2.y); a[2] = f2bf(c2.z); a[3] = f2bf(c2.w);
            a[4] = f2bf(c3.x); a[5] = f2bf(c3.y); a[6] = f2bf(c3.z); a[7] = f2bf(c3.w);
            acc0 = __builtin_amdgcn_mfma_f32_16x16x32_bf16(a, bfrag[1][0], acc0, 0, 0, 0);
            acc1 = __builtin_amdgcn_mfma_f32_16x16x32_bf16(a, bfrag[1][1], acc1, 0, 0, 0);
            acc2 = __builtin_amdgcn_mfma_f32_16x16x32_bf16(a, bfrag[1][2], acc2, 0, 0, 0);
            acc3 = __builtin_amdgcn_mfma_f32_16x16x32_bf16(a, bfrag[1][3], acc3, 0, 0, 0);
        }

#pragma unroll
        for (int r = 0; r < 4; ++r) {
            int e = ebase + g * 4 + r;
            f32x4* accp[4] = {&acc0, &acc1, &acc2, &acc3};
            float pv = bf2f(kv4[r][0]) * bf2f(qv4[r][0]) * acc0[r]
                     + bf2f(kv4[r][1]) * bf2f(qv4[r][1]) * acc1[r]
                     + bf2f(kv4[r][2]) * bf2f(qv4[r][2]) * acc2[r]
                     + bf2f(kv4[r][3]) * bf2f(qv4[r][3]) * acc3[r];
            (void)accp;
            pv *= invs;
            pv += __shfl_xor(pv, 8, 64);
            float sc = __expf(fminf(fmaxf(pv, -5.0f), 5.0f));
            if ((lane & 8) == 0 && e < E) ssb[(size_t)e * HH + (q & 7)] = (unsigned short)f2bf(sc);
        }

        if (!hasN) break;
        c0 = n0; c1 = n1; c2 = n2; c3 = n3;
        wt = wtN; wtN = wtN2; rowN = rowN2;
    }
}

// ---------- output via MFMA: cheb (4 fc-scaled tables) + gcn ----------
__global__ __launch_bounds__(256) void k_out(
        const unsigned short* __restrict__ hpb, const unsigned short* __restrict__ Tx1b,
        const unsigned short* __restrict__ Tx2b, const unsigned short* __restrict__ Tx3b,
        const unsigned short* __restrict__ aggb, const float* __restrict__ fc,
        const unsigned short* __restrict__ WcT, const unsigned short* __restrict__ WgT,
        const float* __restrict__ bc, const float* __restrict__ bg,
        int n, float* __restrict__ out) {
    int lane = threadIdx.x & 63;
    int q = lane & 15, g = lane >> 4;
    int wid = (blockIdx.x * 256 + threadIdx.x) >> 6;
    int nb16 = wid * 16;
    if (nb16 >= n) return;
    int node = nb16 + q;
    int nodec = node < n ? node : n - 1;
    float f0 = fc[nodec], f1 = fc[n + nodec], f2 = fc[2 * n + nodec], f3 = fc[3 * n + nodec];

    f32x4 ac[4], ag[4];
#pragma unroll
    for (int tc = 0; tc < 4; ++tc) { ac[tc] = (f32x4){0,0,0,0}; ag[tc] = (f32x4){0,0,0,0}; }

#pragma unroll
    for (int kk = 0; kk < 2; ++kk) {
        int off = kk * 32 + g * 8;
        bf16x8 a0r = *(const bf16x8*)(hpb + (size_t)nodec * 128 + off);   // Tx0 = h
        bf16x8 a1r = *(const bf16x8*)(Tx1b + (size_t)nodec * 64 + off);
        bf16x8 a2r = *(const bf16x8*)(Tx2b + (size_t)nodec * 64 + off);
        bf16x8 a3r = *(const bf16x8*)(Tx3b + (size_t)nodec * 64 + off);
        bf16x8 aA  = *(const bf16x8*)(aggb + (size_t)nodec * 64 + off);
        bf16x8 a0, a1, a2, a3;
#pragma unroll
        for (int j = 0; j < 8; ++j) {
            a0[j] = f2bf(f0 * bf2f((unsigned short)a0r[j]));
            a1[j] = f2bf(f1 * bf2f((unsigned short)a1r[j]));
            a2[j] = f2bf(f2 * bf2f((unsigned short)a2r[j]));
            a3[j] = f2bf(f3 * bf2f((unsigned short)a3r[j]));
        }
#pragma unroll
        for (int tc = 0; tc < 4; ++tc) {
            bf16x8 b0 = *(const bf16x8*)(WcT + 0 * 4096 + (tc * 16 + q) * 64 + off);
            bf16x8 b1 = *(const bf16x8*)(WcT + 1 * 4096 + (tc * 16 + q) * 64 + off);
            bf16x8 b2 = *(const bf16x8*)(WcT + 2 * 4096 + (tc * 16 + q) * 64 + off);
            bf16x8 b3 = *(const bf16x8*)(WcT + 3 * 4096 + (tc * 16 + q) * 64 + off);
            bf16x8 bgw = *(const bf16x8*)(WgT + (tc * 16 + q) * 64 + off);
            ac[tc] = __builtin_amdgcn_mfma_f32_16x16x32_bf16(a0, b0, ac[tc], 0, 0, 0);
            ac[tc] = __builtin_amdgcn_mfma_f32_16x16x32_bf16(a1, b1, ac[tc], 0, 0, 0);
            ac[tc] = __builtin_amdgcn_mfma_f32_16x16x32_bf16(a2, b2, ac[tc], 0, 0, 0);
            ac[tc] = __builtin_amdgcn_mfma_f32_16x16x32_bf16(a3, b3, ac[tc], 0, 0, 0);
            ag[tc] = __builtin_amdgcn_mfma_f32_16x16x32_bf16(aA, bgw, ag[tc], 0, 0, 0);
        }
    }
#pragma unroll
    for (int tc = 0; tc < 4; ++tc) {
        float bcv = bc[tc * 16 + q], bgv = bg[tc * 16 + q];
#pragma unroll
        for (int r = 0; r < 4; ++r) {
            int nd = nb16 + g * 4 + r;
            if (nd < n) {
                out[(size_t)nd * 192 + tc * 16 + q] = ac[tc][r] + bcv;
                out[(size_t)nd * 192 + 64 + tc * 16 + q] = ag[tc][r] + bgv;
            }
        }
    }
}

extern "C" void kernel_launch(void* const* d_in, const int* in_sizes, int n_in,
                              void* d_out, int out_size, void* d_ws, size_t ws_size,
                              hipStream_t stream) {
    const float* h  = (const float*)d_in[0];
    const float* p  = (const float*)d_in[1];
    const float* ef = (const float*)d_in[2];
    const float* ew = (const float*)d_in[3];
    const float* fc = (const float*)d_in[4];
    const int* esrc = (const int*)d_in[5];
    const int* edst = (const int*)d_in[6];
    const float* Wc = (const float*)d_in[7];
    const float* bc = (const float*)d_in[8];
    const float* Wg = (const float*)d_in[9];
    const float* bg = (const float*)d_in[10];
    const float* WQ = (const float*)d_in[11];
    const float* WK = (const float*)d_in[12];
    const float* WV = (const float*)d_in[13];
    const float* WE = (const float*)d_in[14];

    const int n = in_sizes[0] / DD;   // 50000
    const int E = in_sizes[5];        // 800000
    float* out = (float*)d_out;

    char* wsp = (char*)d_ws;
    size_t o = 0;
    auto alloc = [&](size_t bytes) -> void* {
        void* r = (void*)(wsp + o);
        o = (o + bytes + 255) & ~(size_t)255;
        return r;
    };
    int* deg     = (int*)alloc((size_t)n * 4);
    int* offsets = (int*)alloc((size_t)(n + 1) * 4);
    int* cursor  = (int*)alloc((size_t)n * 4);
    int4* payload = (int4*)alloc((size_t)E * 16);
    int* dsts    = (int*)alloc((size_t)E * 4);
    int* bsum    = (int*)alloc(1024 * 4);
    float* dinv  = (float*)alloc((size_t)n * 4);
    short* WETb  = (short*)alloc(4096 * 2);
    unsigned short* WQTp = (unsigned short*)alloc(8192 * 2);
    unsigned short* WKTp = (unsigned short*)alloc(8192 * 2);
    unsigned short* WVT  = (unsigned short*)alloc(8192 * 2);
    unsigned short* WcT  = (unsigned short*)alloc(16384 * 2);
    unsigned short* WgT  = (unsigned short*)alloc(4096 * 2);
    unsigned short* hpb  = (unsigned short*)alloc((size_t)n * 128 * 2);
    unsigned short* Tx1b = (unsigned short*)alloc((size_t)n * DD * 2);
    unsigned short* Tx2b = (unsigned short*)alloc((size_t)n * DD * 2);
    unsigned short* Tx3b = (unsigned short*)alloc((size_t)n * DD * 2);
    unsigned short* aggb = (unsigned short*)alloc((size_t)n * DD * 2);
    unsigned short* Vhb  = (unsigned short*)alloc((size_t)n * DD * 2);
    unsigned short* Qhb  = (unsigned short*)alloc((size_t)n * DD * 2);
    unsigned short* Khb  = (unsigned short*)alloc((size_t)n * DD * 2);
    unsigned short* ssb  = (unsigned short*)alloc((size_t)E * HH * 2);
    (void)ws_size; (void)n_in; (void)out_size;

    hipMemsetAsync(deg, 0, (size_t)n * 4, stream);

    int nb = (n + 255) / 256;
    k_count<<<(E + 255) / 256, 256, 0, stream>>>(edst, E, deg);
    k_blocksum<<<nb, 256, 0, stream>>>(deg, n, bsum);
    k_scan_bsum<<<1, 256, 0, stream>>>(bsum, nb);
    k_scan_final<<<nb, 256, 0, stream>>>(deg, bsum, n, E, offsets, cursor, dinv);
    k_scatter<<<(E + 255) / 256, 256, 0, stream>>>(edst, esrc, ew, dinv, E, cursor, payload);
    k_dstfill<<<nb, 256, 0, stream>>>(offsets, n, dsts);
    k_prep<<<128, 256, 0, stream>>>(WQ, WK, WV, Wc, Wg, WE, WQTp, WKTp, WVT, WcT, WgT, WETb);
    k_hpb<<<(n * 64 + 255) / 256, 256, 0, stream>>>(h, p, n, hpb);

    int qkv_waves = (n + 15) / 16;
    k_qkv<<<(qkv_waves + 3) / 4, 256, 0, stream>>>(hpb, WQTp, WKTp, WVT, n, Qhb, Khb, Vhb);

    k_score<<<2048, 256, 0, stream>>>(ef, WETb, payload, dsts, Qhb, Khb, E, ssb);

    k_pass1<<<(n + 3) / 4, 256, 0, stream>>>(offsets, payload, dinv, hpb, n, Tx1b, aggb);
    k_lap<<<(n + 3) / 4, 256, 0, stream>>>(offsets, payload, dinv, Tx1b, 64, hpb, 128,
                                           2.0f, -1.0f, n, Tx2b);
    k_lap3_attn<<<(n + 3) / 4, 256, 0, stream>>>(offsets, payload, dinv, Tx2b, Tx1b, Vhb,
                                                 ssb, n, Tx3b, out);

    int out_waves = (n + 15) / 16;
    k_out<<<(out_waves + 3) / 4, 256, 0, stream>>>(hpb, Tx1b, Tx2b, Tx3b, aggb, fc,
                                                   WcT, WgT, bc, bg, n, out);
}

// Round 13
// 331.638 us; speedup vs baseline: 2.6443x; 1.0027x over previous
//
#include <hip/hip_runtime.h>
#include <math.h>

#define DD 64
#define HH 8
#define KORD 4

typedef __attribute__((ext_vector_type(8))) short bf16x8;
typedef __attribute__((ext_vector_type(4))) float f32x4;
typedef __attribute__((ext_vector_type(8))) unsigned short u16x8;
typedef __attribute__((ext_vector_type(4))) unsigned short u16x4;

__device__ __forceinline__ short f2bf(float f) {
    unsigned u = __builtin_bit_cast(unsigned, f);
    u = (u + 0x7fffu + ((u >> 16) & 1u)) >> 16;
    return (short)u;
}
__device__ __forceinline__ float bf2f(unsigned short u) {
    unsigned x = ((unsigned)u) << 16;
    return __builtin_bit_cast(float, x);
}
__device__ __forceinline__ float i2f(int v) { return __builtin_bit_cast(float, v); }

// ---------- fused: edge-count || weight-prep || hp bf16 cast ----------
__global__ void fused_init(const int* __restrict__ dst, int E, int* __restrict__ deg,
                           const float* __restrict__ WQ, const float* __restrict__ WK,
                           const float* __restrict__ WV, const float* __restrict__ Wc,
                           const float* __restrict__ Wg, const float* __restrict__ WE,
                           unsigned short* __restrict__ WQTp, unsigned short* __restrict__ WKTp,
                           unsigned short* __restrict__ WVT, unsigned short* __restrict__ WcT,
                           unsigned short* __restrict__ WgT, short* __restrict__ WETb,
                           const float* __restrict__ h, const float* __restrict__ p,
                           int n, unsigned short* __restrict__ hpb, int CB, int PRB) {
    int b = blockIdx.x, t = threadIdx.x;
    if (b < CB) {
        int i = b * 256 + t;
        if (i < E) atomicAdd(&deg[dst[i]], 1);
    } else if (b < CB + PRB) {
        int i = (b - CB) * 256 + t;
        if (i < 8192) {
            int col = i >> 7, k = i & 127;
            int q = col & 15, tc = col >> 4;
            int d = ((q & 7) << 3) + (q >> 3) + (tc << 1);
            WQTp[i] = (unsigned short)f2bf(WQ[k * 64 + d]);
            WKTp[i] = (unsigned short)f2bf(WK[k * 64 + d]);
            WVT[i]  = (unsigned short)f2bf(WV[k * 64 + col]);
        } else if (i < 8192 + 16384) {
            int j = i - 8192;
            int k4 = j >> 12, r = j & 4095;
            int col = r >> 6, kk = r & 63;
            WcT[j] = (unsigned short)f2bf(Wc[k4 * 4096 + kk * 64 + col]);
        } else if (i < 8192 + 16384 + 4096) {
            int j = i - 8192 - 16384;
            int col = j >> 6, kk = j & 63;
            WgT[j] = (unsigned short)f2bf(Wg[kk * 64 + col]);
        } else if (i < 8192 + 16384 + 4096 + 4096) {
            int j = i - 8192 - 16384 - 4096;
            int col = j >> 6, jj = j & 63;
            int q = col & 15, tc = col >> 4;
            int d = ((q & 7) << 3) + (q >> 3) + (tc << 1);
            WETb[j] = f2bf(WE[jj * 64 + d]);
        }
    } else {
        int i = (b - CB - PRB) * 256 + t;
        if (i < n * 64) {
            int node = i >> 6, j = i & 63;
            hpb[(size_t)node * 128 + j] = (unsigned short)f2bf(h[i]);
            hpb[(size_t)node * 128 + 64 + j] = (unsigned short)f2bf(p[i]);
        }
    }
}

__global__ void k_blocksum(const int* __restrict__ deg, int n, int* __restrict__ bsum) {
    __shared__ int s[256];
    int i = blockIdx.x * 256 + threadIdx.x;
    s[threadIdx.x] = (i < n) ? deg[i] : 0;
    __syncthreads();
    for (int off = 128; off > 0; off >>= 1) {
        if (threadIdx.x < off) s[threadIdx.x] += s[threadIdx.x + off];
        __syncthreads();
    }
    if (threadIdx.x == 0) bsum[blockIdx.x] = s[0];
}

__global__ void k_scan_bsum(int* __restrict__ bsum, int nb) {
    __shared__ int s[256];
    int t = threadIdx.x;
    int v = (t < nb) ? bsum[t] : 0;
    s[t] = v;
    __syncthreads();
    for (int off = 1; off < 256; off <<= 1) {
        int tmp = (t >= off) ? s[t - off] : 0;
        __syncthreads();
        s[t] += tmp;
        __syncthreads();
    }
    if (t < nb) bsum[t] = s[t] - v;  // exclusive
}

__global__ void k_scan_final(const int* __restrict__ deg, const int* __restrict__ bsum,
                             int n, int E, int* __restrict__ offsets,
                             int* __restrict__ cursor, float* __restrict__ dinv) {
    __shared__ int s[256];
    int t = threadIdx.x, i = blockIdx.x * 256 + t;
    int v = (i < n) ? deg[i] : 0;
    s[t] = v;
    __syncthreads();
    for (int off = 1; off < 256; off <<= 1) {
        int tmp = (t >= off) ? s[t - off] : 0;
        __syncthreads();
        s[t] += tmp;
        __syncthreads();
    }
    if (i < n) {
        int excl = s[t] - v + bsum[blockIdx.x];
        offsets[i] = excl;
        cursor[i] = excl;
        int dv = v < 1 ? 1 : v;
        dinv[i] = 1.0f / sqrtf((float)dv);
    }
    if (i == 0) offsets[n] = E;
}

// ---------- fused: payload scatter || dst fill ----------
__global__ void fused_scatter(const int* __restrict__ dst, const int* __restrict__ src,
                              const float* __restrict__ ew, const float* __restrict__ dinv,
                              int E, int* __restrict__ cursor, int4* __restrict__ payload,
                              const int* __restrict__ offsets, int n, int* __restrict__ dsts,
                              int SCB) {
    int b = blockIdx.x, t = threadIdx.x;
    if (b < SCB) {
        int i = b * 256 + t;
        if (i < E) {
            int s = src[i], d = dst[i];
            int pcur = atomicAdd(&cursor[d], 1);
            int4 pl;
            pl.x = s;
            pl.y = __builtin_bit_cast(int, ew[i]);
            pl.z = __builtin_bit_cast(int, dinv[s]);
            pl.w = i;
            payload[pcur] = pl;
        }
    } else {
        int node = (b - SCB) * 256 + t;
        if (node < n) {
            int beg = offsets[node], end = offsets[node + 1];
            for (int e = beg; e < end; ++e) dsts[e] = node;
        }
    }
}

// ---------- fused: QKV MFMA || pass1 gathers ----------
__global__ __launch_bounds__(256) void fused_qp(
        const unsigned short* __restrict__ hpb,
        const unsigned short* __restrict__ WQTp, const unsigned short* __restrict__ WKTp,
        const unsigned short* __restrict__ WVT, int n,
        unsigned short* __restrict__ Qhb, unsigned short* __restrict__ Khb,
        unsigned short* __restrict__ Vhb,
        const int* __restrict__ offsets, const int4* __restrict__ payload,
        const float* __restrict__ dinv,
        unsigned short* __restrict__ Tx1b, unsigned short* __restrict__ aggb, int QB) {
    int t = threadIdx.x;
    if (blockIdx.x < QB) {
        // ---- k_qkv body ----
        int lane = t & 63;
        int q = lane & 15, g = lane >> 4;
        int wid = (blockIdx.x * 256 + t) >> 6;
        int nb16 = wid * 16;
        if (nb16 >= n) return;
        int node = nb16 + q;
        int nodec = node < n ? node : n - 1;

        f32x4 aq[4], ak[4], av[4];
#pragma unroll
        for (int tc = 0; tc < 4; ++tc) {
            aq[tc] = (f32x4){0, 0, 0, 0}; ak[tc] = (f32x4){0, 0, 0, 0}; av[tc] = (f32x4){0, 0, 0, 0};
        }
#pragma unroll
        for (int kk = 0; kk < 4; ++kk) {
            bf16x8 a = *(const bf16x8*)(hpb + (size_t)nodec * 128 + kk * 32 + g * 8);
#pragma unroll
            for (int tc = 0; tc < 4; ++tc) {
                bf16x8 bq = *(const bf16x8*)(WQTp + (tc * 16 + q) * 128 + kk * 32 + g * 8);
                bf16x8 bk = *(const bf16x8*)(WKTp + (tc * 16 + q) * 128 + kk * 32 + g * 8);
                bf16x8 bv = *(const bf16x8*)(WVT + (tc * 16 + q) * 128 + kk * 32 + g * 8);
                aq[tc] = __builtin_amdgcn_mfma_f32_16x16x32_bf16(a, bq, aq[tc], 0, 0, 0);
                ak[tc] = __builtin_amdgcn_mfma_f32_16x16x32_bf16(a, bk, ak[tc], 0, 0, 0);
                av[tc] = __builtin_amdgcn_mfma_f32_16x16x32_bf16(a, bv, av[tc], 0, 0, 0);
            }
        }
#pragma unroll
        for (int r = 0; r < 4; ++r) {
            int nd = nb16 + g * 4 + r;
            if (nd < n) {
                u16x4 oq, ok;
#pragma unroll
                for (int tc = 0; tc < 4; ++tc) {
                    oq[tc] = (unsigned short)f2bf(aq[tc][r]);
                    ok[tc] = (unsigned short)f2bf(ak[tc][r]);
                }
                *(u16x4*)(Qhb + (size_t)nd * 64 + q * 4) = oq;
                *(u16x4*)(Khb + (size_t)nd * 64 + q * 4) = ok;
#pragma unroll
                for (int tc = 0; tc < 4; ++tc)
                    Vhb[(size_t)nd * 64 + tc * 16 + q] = (unsigned short)f2bf(av[tc][r]);
            }
        }
    } else {
        // ---- k_pass1 body ----
        int w = t >> 6, lane = t & 63;
        int node = (blockIdx.x - QB) * 4 + w;
        if (node >= n) return;
        int q = lane & 7, g = lane >> 3;
        int beg = offsets[node], end = offsets[node + 1];
        float aL[8], aG[8];
#pragma unroll
        for (int c = 0; c < 8; ++c) { aL[c] = 0.f; aG[c] = 0.f; }
        int e2 = beg;
        for (; e2 + 16 <= end; e2 += 16) {
            int4 pa = payload[e2 + g], pb = payload[e2 + 8 + g];
            u16x8 va = *(const u16x8*)(hpb + (size_t)pa.x * 128 + q * 8);
            u16x8 vb = *(const u16x8*)(hpb + (size_t)pb.x * 128 + q * 8);
            float da = i2f(pa.z), db = i2f(pb.z);
            float wa = i2f(pa.y), wb = i2f(pb.y);
#pragma unroll
            for (int c = 0; c < 8; ++c) {
                float fa = bf2f(va[c]), fb = bf2f(vb[c]);
                aL[c] = fmaf(da, fa, aL[c]); aL[c] = fmaf(db, fb, aL[c]);
                aG[c] = fmaf(wa, fa, aG[c]); aG[c] = fmaf(wb, fb, aG[c]);
            }
        }
        for (; e2 < end; e2 += 8) {
            int e = e2 + g;
            if (e < end) {
                int4 pl = payload[e];
                u16x8 v = *(const u16x8*)(hpb + (size_t)pl.x * 128 + q * 8);
                float d = i2f(pl.z), wv = i2f(pl.y);
#pragma unroll
                for (int c = 0; c < 8; ++c) {
                    float f = bf2f(v[c]);
                    aL[c] = fmaf(d, f, aL[c]);
                    aG[c] = fmaf(wv, f, aG[c]);
                }
            }
        }
#pragma unroll
        for (int c = 0; c < 8; ++c) {
            aL[c] += __shfl_xor(aL[c], 8, 64);  aL[c] += __shfl_xor(aL[c], 16, 64);
            aL[c] += __shfl_xor(aL[c], 32, 64);
            aG[c] += __shfl_xor(aG[c], 8, 64);  aG[c] += __shfl_xor(aG[c], 16, 64);
            aG[c] += __shfl_xor(aG[c], 32, 64);
        }
        if (g == 0) {
            float dn = dinv[node];
            u16x8 o1, o2;
#pragma unroll
            for (int c = 0; c < 8; ++c) {
                o1[c] = (unsigned short)f2bf(-dn * aL[c]);
                o2[c] = (unsigned short)f2bf(aG[c]);
            }
            *(u16x8*)(Tx1b + (size_t)node * DD + q * 8) = o1;
            *(u16x8*)(aggb + (size_t)node * DD + q * 8) = o2;
        }
    }
}

// ---------- fused: score MFMA pipeline || lap(Tx1->Tx2) gathers ----------
__global__ __launch_bounds__(256) void fused_sl(
        const float* __restrict__ efeat, const short* __restrict__ WETb,
        const int4* __restrict__ payload, const int* __restrict__ dsts,
        const unsigned short* __restrict__ Qhb, const unsigned short* __restrict__ Khb,
        int E, unsigned short* __restrict__ ssb,
        const int* __restrict__ offsets, const float* __restrict__ dinv,
        const unsigned short* __restrict__ Tx1b, const unsigned short* __restrict__ hpb,
        int n, unsigned short* __restrict__ Tx2b, int SB, int score_nwaves) {
    int t = threadIdx.x;
    if (blockIdx.x < SB) {
        // ---- k_score body ----
        int lane = t & 63;
        int q = lane & 15, g = lane >> 4;
        bf16x8 bfrag[2][4];
#pragma unroll
        for (int kc = 0; kc < 2; ++kc)
#pragma unroll
            for (int tc = 0; tc < 4; ++tc)
                bfrag[kc][tc] = *(const bf16x8*)(WETb + (tc * 16 + q) * 64 + kc * 32 + g * 8);

        const float invs = 0.35355339059327373f;  // 1/sqrt(8)
        int nwaves = score_nwaves;
        int wid = (blockIdx.x * 256 + t) >> 6;
        int ntiles = (E + 15) >> 4;
        int wt = wid;
        if (wt >= ntiles) return;

        int er = wt * 16 + q;
        int rowC = payload[er < E ? er : E - 1].w;
        const float* epC = efeat + (size_t)rowC * 64;
        float4 c0 = *(const float4*)(epC + g * 8);
        float4 c1 = *(const float4*)(epC + g * 8 + 4);
        float4 c2 = *(const float4*)(epC + 32 + g * 8);
        float4 c3 = *(const float4*)(epC + 32 + g * 8 + 4);
        int wtN = wt + nwaves;
        int rowN = 0;
        if (wtN < ntiles) {
            int ern = wtN * 16 + q;
            rowN = payload[ern < E ? ern : E - 1].w;
        }

        while (true) {
            int ebase = wt * 16;
            bool hasN = wtN < ntiles;
            float4 n0, n1, n2, n3;
            if (hasN) {
                const float* epN = efeat + (size_t)rowN * 64;
                n0 = *(const float4*)(epN + g * 8);
                n1 = *(const float4*)(epN + g * 8 + 4);
                n2 = *(const float4*)(epN + 32 + g * 8);
                n3 = *(const float4*)(epN + 32 + g * 8 + 4);
            }
            int wtN2 = wtN + nwaves;
            int rowN2 = 0;
            if (wtN2 < ntiles) {
                int ern = wtN2 * 16 + q;
                rowN2 = payload[ern < E ? ern : E - 1].w;
            }
            u16x4 kv4[4], qv4[4];
#pragma unroll
            for (int r = 0; r < 4; ++r) {
                int e = ebase + g * 4 + r;
                int ec = e < E ? e : E - 1;
                int sA = payload[ec].x;
                int tA = dsts[ec];
                kv4[r] = *(const u16x4*)(Khb + (size_t)sA * 64 + q * 4);
                qv4[r] = *(const u16x4*)(Qhb + (size_t)tA * 64 + q * 4);
            }

            f32x4 acc0 = {0, 0, 0, 0}, acc1 = {0, 0, 0, 0};
            f32x4 acc2 = {0, 0, 0, 0}, acc3 = {0, 0, 0, 0};
            {
                bf16x8 a;
                a[0] = f2bf(c0.x); a[1] = f2bf(c0.y); a[2] = f2bf(c0.z); a[3] = f2bf(c0.w);
                a[4] = f2bf(c1.x); a[5] = f2bf(c1.y); a[6] = f2bf(c1.z); a[7] = f2bf(c1.w);
                acc0 = __builtin_amdgcn_mfma_f32_16x16x32_bf16(a, bfrag[0][0], acc0, 0, 0, 0);
                acc1 = __builtin_amdgcn_mfma_f32_16x16x32_bf16(a, bfrag[0][1], acc1, 0, 0, 0);
                acc2 = __builtin_amdgcn_mfma_f32_16x16x32_bf16(a, bfrag[0][2], acc2, 0, 0, 0);
                acc3 = __builtin_amdgcn_mfma_f32_16x16x32_bf16(a, bfrag[0][3], acc3, 0, 0, 0);
                a[0] = f2bf(c2.x); a[1] = f2bf(c2.y); a[2] = f2bf(c2.z); a[3] = f2bf(c2.w);
                a[4] = f2bf(c3.x); a[5] = f2bf(c3.y); a[6] = f2bf(c3.z); a[7] = f2bf(c3.w);
                acc0 = __builtin_amdgcn_mfma_f32_16x16x32_bf16(a, bfrag[1][0], acc0, 0, 0, 0);
                acc1 = __builtin_amdgcn_mfma_f32_16x16x32_bf16(a, bfrag[1][1], acc1, 0, 0, 0);
                acc2 = __builtin_amdgcn_mfma_f32_16x16x32_bf16(a, bfrag[1][2], acc2, 0, 0, 0);
                acc3 = __builtin_amdgcn_mfma_f32_16x16x32_bf16(a, bfrag[1][3], acc3, 0, 0, 0);
            }

#pragma unroll
            for (int r = 0; r < 4; ++r) {
                int e = ebase + g * 4 + r;
                float pv = bf2f(kv4[r][0]) * bf2f(qv4[r][0]) * acc0[r]
                         + bf2f(kv4[r][1]) * bf2f(qv4[r][1]) * acc1[r]
                         + bf2f(kv4[r][2]) * bf2f(qv4[r][2]) * acc2[r]
                         + bf2f(kv4[r][3]) * bf2f(qv4[r][3]) * acc3[r];
                pv *= invs;
                pv += __shfl_xor(pv, 8, 64);
                float sc = __expf(fminf(fmaxf(pv, -5.0f), 5.0f));
                if ((lane & 8) == 0 && e < E) ssb[(size_t)e * HH + (q & 7)] = (unsigned short)f2bf(sc);
            }

            if (!hasN) break;
            c0 = n0; c1 = n1; c2 = n2; c3 = n3;
            wt = wtN; wtN = wtN2; rowN = rowN2;
        }
    } else {
        // ---- k_lap body: Tx2 = 2*lap(Tx1) - h ----
        int w = t >> 6, lane = t & 63;
        int node = (blockIdx.x - SB) * 4 + w;
        if (node >= n) return;
        int q = lane & 7, g = lane >> 3;
        int beg = offsets[node], end = offsets[node + 1];
        float a[8];
#pragma unroll
        for (int c = 0; c < 8; ++c) a[c] = 0.f;
        int e2 = beg;
        for (; e2 + 16 <= end; e2 += 16) {
            int4 pa = payload[e2 + g], pb = payload[e2 + 8 + g];
            u16x8 va = *(const u16x8*)(Tx1b + (size_t)pa.x * 64 + q * 8);
            u16x8 vb = *(const u16x8*)(Tx1b + (size_t)pb.x * 64 + q * 8);
            float da = i2f(pa.z), db = i2f(pb.z);
#pragma unroll
            for (int c = 0; c < 8; ++c) {
                a[c] = fmaf(da, bf2f(va[c]), a[c]);
                a[c] = fmaf(db, bf2f(vb[c]), a[c]);
            }
        }
        for (; e2 < end; e2 += 8) {
            int e = e2 + g;
            if (e < end) {
                int4 pl = payload[e];
                u16x8 v = *(const u16x8*)(Tx1b + (size_t)pl.x * 64 + q * 8);
                float d = i2f(pl.z);
#pragma unroll
                for (int c = 0; c < 8; ++c) a[c] = fmaf(d, bf2f(v[c]), a[c]);
            }
        }
#pragma unroll
        for (int c = 0; c < 8; ++c) {
            a[c] += __shfl_xor(a[c], 8, 64);  a[c] += __shfl_xor(a[c], 16, 64);
            a[c] += __shfl_xor(a[c], 32, 64);
        }
        if (g == 0) {
            float dn = dinv[node];
            u16x8 pv = *(const u16x8*)(hpb + (size_t)node * 128 + q * 8);
            u16x8 o;
#pragma unroll
            for (int c = 0; c < 8; ++c) {
                float v = 2.0f * (-dn * a[c]) - bf2f(pv[c]);
                o[c] = (unsigned short)f2bf(v);
            }
            *(u16x8*)(Tx2b + (size_t)node * DD + q * 8) = o;
        }
    }
}

// ---------- fused: Tx3 = 2*lap(Tx2) - Tx1  AND  attention aggregation (ss bf16) ----------
__global__ void k_lap3_attn(const int* __restrict__ offsets, const int4* __restrict__ payload,
                            const float* __restrict__ dinv,
                            const unsigned short* __restrict__ Tx2b,
                            const unsigned short* __restrict__ Tx1b,
                            const unsigned short* __restrict__ Vhb,
                            const unsigned short* __restrict__ ssb,
                            int n, unsigned short* __restrict__ Tx3b,
                            float* __restrict__ out) {
    int w = threadIdx.x >> 6, lane = threadIdx.x & 63;
    int node = blockIdx.x * 4 + w;
    if (node >= n) return;
    int q = lane & 7, g = lane >> 3;  // head == q
    int beg = offsets[node], end = offsets[node + 1];
    float a[8], aV[8];
#pragma unroll
    for (int c = 0; c < 8; ++c) { a[c] = 0.f; aV[c] = 0.f; }
    float aZ = 0.f;
    int e2 = beg;
    for (; e2 + 16 <= end; e2 += 16) {
        int ea = e2 + g, eb = e2 + 8 + g;
        int4 pa = payload[ea], pb = payload[eb];
        u16x8 xa = *(const u16x8*)(Tx2b + (size_t)pa.x * DD + q * 8);
        u16x8 xb = *(const u16x8*)(Tx2b + (size_t)pb.x * DD + q * 8);
        u16x8 va = *(const u16x8*)(Vhb + (size_t)pa.x * DD + q * 8);
        u16x8 vb = *(const u16x8*)(Vhb + (size_t)pb.x * DD + q * 8);
        float sva = bf2f(ssb[(size_t)ea * HH + q]);
        float svb = bf2f(ssb[(size_t)eb * HH + q]);
        float da = i2f(pa.z), db = i2f(pb.z);
#pragma unroll
        for (int c = 0; c < 8; ++c) {
            a[c] = fmaf(da, bf2f(xa[c]), a[c]);
            a[c] = fmaf(db, bf2f(xb[c]), a[c]);
            aV[c] = fmaf(sva, bf2f(va[c]), aV[c]);
            aV[c] = fmaf(svb, bf2f(vb[c]), aV[c]);
        }
        aZ += sva + svb;
    }
    for (; e2 < end; e2 += 8) {
        int e = e2 + g;
        if (e < end) {
            int4 pl = payload[e];
            u16x8 x = *(const u16x8*)(Tx2b + (size_t)pl.x * DD + q * 8);
            u16x8 v = *(const u16x8*)(Vhb + (size_t)pl.x * DD + q * 8);
            float sv = bf2f(ssb[(size_t)e * HH + q]);
            float d = i2f(pl.z);
#pragma unroll
            for (int c = 0; c < 8; ++c) {
                a[c] = fmaf(d, bf2f(x[c]), a[c]);
                aV[c] = fmaf(sv, bf2f(v[c]), aV[c]);
            }
            aZ += sv;
        }
    }
#pragma unroll
    for (int c = 0; c < 8; ++c) {
        a[c] += __shfl_xor(a[c], 8, 64);   a[c] += __shfl_xor(a[c], 16, 64);
        a[c] += __shfl_xor(a[c], 32, 64);
        aV[c] += __shfl_xor(aV[c], 8, 64); aV[c] += __shfl_xor(aV[c], 16, 64);
        aV[c] += __shfl_xor(aV[c], 32, 64);
    }
    aZ += __shfl_xor(aZ, 8, 64); aZ += __shfl_xor(aZ, 16, 64); aZ += __shfl_xor(aZ, 32, 64);
    if (g == 0) {
        float dn = dinv[node];
        u16x8 pv = *(const u16x8*)(Tx1b + (size_t)node * DD + q * 8);
        u16x8 o;
        float inv = 1.0f / (aZ + 1e-6f);
        float4 o1, o2;
#pragma unroll
        for (int c = 0; c < 8; ++c) {
            float v = 2.0f * (-dn * a[c]) - bf2f(pv[c]);
            o[c] = (unsigned short)f2bf(v);
        }
        o1.x = aV[0] * inv; o1.y = aV[1] * inv; o1.z = aV[2] * inv; o1.w = aV[3] * inv;
        o2.x = aV[4] * inv; o2.y = aV[5] * inv; o2.z = aV[6] * inv; o2.w = aV[7] * inv;
        *(u16x8*)(Tx3b + (size_t)node * DD + q * 8) = o;
        *(float4*)(out + (size_t)node * 192 + 128 + q * 8) = o1;
        *(float4*)(out + (size_t)node * 192 + 128 + q * 8 + 4) = o2;
    }
}

// ---------- output via MFMA: cheb (4 fc-scaled tables) + gcn ----------
__global__ __launch_bounds__(256) void k_out(
        const unsigned short* __restrict__ hpb, const unsigned short* __restrict__ Tx1b,
        const unsigned short* __restrict__ Tx2b, const unsigned short* __restrict__ Tx3b,
        const unsigned short* __restrict__ aggb, const float* __restrict__ fc,
        const unsigned short* __restrict__ WcT, const unsigned short* __restrict__ WgT,
        const float* __restrict__ bc, const float* __restrict__ bg,
        int n, float* __restrict__ out) {
    int lane = threadIdx.x & 63;
    int q = lane & 15, g = lane >> 4;
    int wid = (blockIdx.x * 256 + threadIdx.x) >> 6;
    int nb16 = wid * 16;
    if (nb16 >= n) return;
    int node = nb16 + q;
    int nodec = node < n ? node : n - 1;
    float f0 = fc[nodec], f1 = fc[n + nodec], f2 = fc[2 * n + nodec], f3 = fc[3 * n + nodec];

    f32x4 ac[4], ag[4];
#pragma unroll
    for (int tc = 0; tc < 4; ++tc) { ac[tc] = (f32x4){0,0,0,0}; ag[tc] = (f32x4){0,0,0,0}; }

#pragma unroll
    for (int kk = 0; kk < 2; ++kk) {
        int off = kk * 32 + g * 8;
        bf16x8 a0r = *(const bf16x8*)(hpb + (size_t)nodec * 128 + off);   // Tx0 = h
        bf16x8 a1r = *(const bf16x8*)(Tx1b + (size_t)nodec * 64 + off);
        bf16x8 a2r = *(const bf16x8*)(Tx2b + (size_t)nodec * 64 + off);
        bf16x8 a3r = *(const bf16x8*)(Tx3b + (size_t)nodec * 64 + off);
        bf16x8 aA  = *(const bf16x8*)(aggb + (size_t)nodec * 64 + off);
        bf16x8 a0, a1, a2, a3;
#pragma unroll
        for (int j = 0; j < 8; ++j) {
            a0[j] = f2bf(f0 * bf2f((unsigned short)a0r[j]));
            a1[j] = f2bf(f1 * bf2f((unsigned short)a1r[j]));
            a2[j] = f2bf(f2 * bf2f((unsigned short)a2r[j]));
            a3[j] = f2bf(f3 * bf2f((unsigned short)a3r[j]));
        }
#pragma unroll
        for (int tc = 0; tc < 4; ++tc) {
            bf16x8 b0 = *(const bf16x8*)(WcT + 0 * 4096 + (tc * 16 + q) * 64 + off);
            bf16x8 b1 = *(const bf16x8*)(WcT + 1 * 4096 + (tc * 16 + q) * 64 + off);
            bf16x8 b2 = *(const bf16x8*)(WcT + 2 * 4096 + (tc * 16 + q) * 64 + off);
            bf16x8 b3 = *(const bf16x8*)(WcT + 3 * 4096 + (tc * 16 + q) * 64 + off);
            bf16x8 bgw = *(const bf16x8*)(WgT + (tc * 16 + q) * 64 + off);
            ac[tc] = __builtin_amdgcn_mfma_f32_16x16x32_bf16(a0, b0, ac[tc], 0, 0, 0);
            ac[tc] = __builtin_amdgcn_mfma_f32_16x16x32_bf16(a1, b1, ac[tc], 0, 0, 0);
            ac[tc] = __builtin_amdgcn_mfma_f32_16x16x32_bf16(a2, b2, ac[tc], 0, 0, 0);
            ac[tc] = __builtin_amdgcn_mfma_f32_16x16x32_bf16(a3, b3, ac[tc], 0, 0, 0);
            ag[tc] = __builtin_amdgcn_mfma_f32_16x16x32_bf16(aA, bgw, ag[tc], 0, 0, 0);
        }
    }
#pragma unroll
    for (int tc = 0; tc < 4; ++tc) {
        float bcv = bc[tc * 16 + q], bgv = bg[tc * 16 + q];
#pragma unroll
        for (int r = 0; r < 4; ++r) {
            int nd = nb16 + g * 4 + r;
            if (nd < n) {
                out[(size_t)nd * 192 + tc * 16 + q] = ac[tc][r] + bcv;
                out[(size_t)nd * 192 + 64 + tc * 16 + q] = ag[tc][r] + bgv;
            }
        }
    }
}

extern "C" void kernel_launch(void* const* d_in, const int* in_sizes, int n_in,
                              void* d_out, int out_size, void* d_ws, size_t ws_size,
                              hipStream_t stream) {
    const float* h  = (const float*)d_in[0];
    const float* p  = (const float*)d_in[1];
    const float* ef = (const float*)d_in[2];
    const float* ew = (const float*)d_in[3];
    const float* fc = (const float*)d_in[4];
    const int* esrc = (const int*)d_in[5];
    const int* edst = (const int*)d_in[6];
    const float* Wc = (const float*)d_in[7];
    const float* bc = (const float*)d_in[8];
    const float* Wg = (const float*)d_in[9];
    const float* bg = (const float*)d_in[10];
    const float* WQ = (const float*)d_in[11];
    const float* WK = (const float*)d_in[12];
    const float* WV = (const float*)d_in[13];
    const float* WE = (const float*)d_in[14];

    const int n = in_sizes[0] / DD;   // 50000
    const int E = in_sizes[5];        // 800000
    float* out = (float*)d_out;

    char* wsp = (char*)d_ws;
    size_t o = 0;
    auto alloc = [&](size_t bytes) -> void* {
        void* r = (void*)(wsp + o);
        o = (o + bytes + 255) & ~(size_t)255;
        return r;
    };
    int* deg     = (int*)alloc((size_t)n * 4);
    int* offsets = (int*)alloc((size_t)(n + 1) * 4);
    int* cursor  = (int*)alloc((size_t)n * 4);
    int4* payload = (int4*)alloc((size_t)E * 16);
    int* dsts    = (int*)alloc((size_t)E * 4);
    int* bsum    = (int*)alloc(1024 * 4);
    float* dinv  = (float*)alloc((size_t)n * 4);
    short* WETb  = (short*)alloc(4096 * 2);
    unsigned short* WQTp = (unsigned short*)alloc(8192 * 2);
    unsigned short* WKTp = (unsigned short*)alloc(8192 * 2);
    unsigned short* WVT  = (unsigned short*)alloc(8192 * 2);
    unsigned short* WcT  = (unsigned short*)alloc(16384 * 2);
    unsigned short* WgT  = (unsigned short*)alloc(4096 * 2);
    unsigned short* hpb  = (unsigned short*)alloc((size_t)n * 128 * 2);
    unsigned short* Tx1b = (unsigned short*)alloc((size_t)n * DD * 2);
    unsigned short* Tx2b = (unsigned short*)alloc((size_t)n * DD * 2);
    unsigned short* Tx3b = (unsigned short*)alloc((size_t)n * DD * 2);
    unsigned short* aggb = (unsigned short*)alloc((size_t)n * DD * 2);
    unsigned short* Vhb  = (unsigned short*)alloc((size_t)n * DD * 2);
    unsigned short* Qhb  = (unsigned short*)alloc((size_t)n * DD * 2);
    unsigned short* Khb  = (unsigned short*)alloc((size_t)n * DD * 2);
    unsigned short* ssb  = (unsigned short*)alloc((size_t)E * HH * 2);
    (void)ws_size; (void)n_in; (void)out_size;

    hipMemsetAsync(deg, 0, (size_t)n * 4, stream);

    int nb = (n + 255) / 256;
    int CB = (E + 255) / 256;                 // count blocks
    int PRB = 128;                            // prep blocks (32768/256)
    int HB = (n * 64 + 255) / 256;            // hpb blocks
    fused_init<<<CB + PRB + HB, 256, 0, stream>>>(edst, E, deg, WQ, WK, WV, Wc, Wg, WE,
                                                  WQTp, WKTp, WVT, WcT, WgT, WETb,
                                                  h, p, n, hpb, CB, PRB);
    k_blocksum<<<nb, 256, 0, stream>>>(deg, n, bsum);
    k_scan_bsum<<<1, 256, 0, stream>>>(bsum, nb);
    k_scan_final<<<nb, 256, 0, stream>>>(deg, bsum, n, E, offsets, cursor, dinv);

    int SCB = (E + 255) / 256;
    fused_scatter<<<SCB + nb, 256, 0, stream>>>(edst, esrc, ew, dinv, E, cursor, payload,
                                                offsets, n, dsts, SCB);

    int qkv_waves = (n + 15) / 16;
    int QB = (qkv_waves + 3) / 4;
    int PB = (n + 3) / 4;
    fused_qp<<<QB + PB, 256, 0, stream>>>(hpb, WQTp, WKTp, WVT, n, Qhb, Khb, Vhb,
                                          offsets, payload, dinv, Tx1b, aggb, QB);

    int SB = 2048;
    int LB = (n + 3) / 4;
    fused_sl<<<SB + LB, 256, 0, stream>>>(ef, WETb, payload, dsts, Qhb, Khb, E, ssb,
                                          offsets, dinv, Tx1b, hpb, n, Tx2b, SB, SB * 4);

    k_lap3_attn<<<(n + 3) / 4, 256, 0, stream>>>(offsets, payload, dinv, Tx2b, Tx1b, Vhb,
                                                 ssb, n, Tx3b, out);

    int out_waves = (n + 15) / 16;
    k_out<<<(out_waves + 3) / 4, 256, 0, stream>>>(hpb, Tx1b, Tx2b, Tx3b, aggb, fc,
                                                   WcT, WgT, bc, bg, n, out);
}

// Round 14
// 330.668 us; speedup vs baseline: 2.6520x; 1.0029x over previous
//
#include <hip/hip_runtime.h>
#include <math.h>

#define DD 64
#define HH 8
#define KORD 4

typedef __attribute__((ext_vector_type(8))) short bf16x8;
typedef __attribute__((ext_vector_type(4))) float f32x4;
typedef __attribute__((ext_vector_type(8))) unsigned short u16x8;
typedef __attribute__((ext_vector_type(4))) unsigned short u16x4;

__device__ __forceinline__ short f2bf(float f) {
    unsigned u = __builtin_bit_cast(unsigned, f);
    u = (u + 0x7fffu + ((u >> 16) & 1u)) >> 16;
    return (short)u;
}
__device__ __forceinline__ float bf2f(unsigned short u) {
    unsigned x = ((unsigned)u) << 16;
    return __builtin_bit_cast(float, x);
}
__device__ __forceinline__ float i2f(int v) { return __builtin_bit_cast(float, v); }

// ---------- fused: edge-count || weight-prep || hp bf16 cast ----------
__global__ void fused_init(const int* __restrict__ dst, int E, int* __restrict__ deg,
                           const float* __restrict__ WQ, const float* __restrict__ WK,
                           const float* __restrict__ WV, const float* __restrict__ Wc,
                           const float* __restrict__ Wg, const float* __restrict__ WE,
                           unsigned short* __restrict__ WQTp, unsigned short* __restrict__ WKTp,
                           unsigned short* __restrict__ WVT, unsigned short* __restrict__ WcT,
                           unsigned short* __restrict__ WgT, short* __restrict__ WETb,
                           const float* __restrict__ h, const float* __restrict__ p,
                           int n, unsigned short* __restrict__ hpb, int CB, int PRB) {
    int b = blockIdx.x, t = threadIdx.x;
    if (b < CB) {
        int i = b * 256 + t;
        if (i < E) atomicAdd(&deg[dst[i]], 1);
    } else if (b < CB + PRB) {
        int i = (b - CB) * 256 + t;
        if (i < 8192) {
            int col = i >> 7, k = i & 127;
            int q = col & 15, tc = col >> 4;
            int d = ((q & 7) << 3) + (q >> 3) + (tc << 1);
            WQTp[i] = (unsigned short)f2bf(WQ[k * 64 + d]);
            WKTp[i] = (unsigned short)f2bf(WK[k * 64 + d]);
            WVT[i]  = (unsigned short)f2bf(WV[k * 64 + col]);
        } else if (i < 8192 + 16384) {
            int j = i - 8192;
            int k4 = j >> 12, r = j & 4095;
            int col = r >> 6, kk = r & 63;
            WcT[j] = (unsigned short)f2bf(Wc[k4 * 4096 + kk * 64 + col]);
        } else if (i < 8192 + 16384 + 4096) {
            int j = i - 8192 - 16384;
            int col = j >> 6, kk = j & 63;
            WgT[j] = (unsigned short)f2bf(Wg[kk * 64 + col]);
        } else if (i < 8192 + 16384 + 4096 + 4096) {
            int j = i - 8192 - 16384 - 4096;
            int col = j >> 6, jj = j & 63;
            int q = col & 15, tc = col >> 4;
            int d = ((q & 7) << 3) + (q >> 3) + (tc << 1);
            WETb[j] = f2bf(WE[jj * 64 + d]);
        }
    } else {
        int i = (b - CB - PRB) * 256 + t;
        if (i < n * 64) {
            int node = i >> 6, j = i & 63;
            hpb[(size_t)node * 128 + j] = (unsigned short)f2bf(h[i]);
            hpb[(size_t)node * 128 + 64 + j] = (unsigned short)f2bf(p[i]);
        }
    }
}

__global__ void k_blocksum(const int* __restrict__ deg, int n, int* __restrict__ bsum) {
    __shared__ int s[256];
    int i = blockIdx.x * 256 + threadIdx.x;
    s[threadIdx.x] = (i < n) ? deg[i] : 0;
    __syncthreads();
    for (int off = 128; off > 0; off >>= 1) {
        if (threadIdx.x < off) s[threadIdx.x] += s[threadIdx.x + off];
        __syncthreads();
    }
    if (threadIdx.x == 0) bsum[blockIdx.x] = s[0];
}

__global__ void k_scan_bsum(int* __restrict__ bsum, int nb) {
    __shared__ int s[256];
    int t = threadIdx.x;
    int v = (t < nb) ? bsum[t] : 0;
    s[t] = v;
    __syncthreads();
    for (int off = 1; off < 256; off <<= 1) {
        int tmp = (t >= off) ? s[t - off] : 0;
        __syncthreads();
        s[t] += tmp;
        __syncthreads();
    }
    if (t < nb) bsum[t] = s[t] - v;  // exclusive
}

__global__ void k_scan_final(const int* __restrict__ deg, const int* __restrict__ bsum,
                             int n, int E, int* __restrict__ offsets,
                             int* __restrict__ cursor, float* __restrict__ dinv) {
    __shared__ int s[256];
    int t = threadIdx.x, i = blockIdx.x * 256 + t;
    int v = (i < n) ? deg[i] : 0;
    s[t] = v;
    __syncthreads();
    for (int off = 1; off < 256; off <<= 1) {
        int tmp = (t >= off) ? s[t - off] : 0;
        __syncthreads();
        s[t] += tmp;
        __syncthreads();
    }
    if (i < n) {
        int excl = s[t] - v + bsum[blockIdx.x];
        offsets[i] = excl;
        cursor[i] = excl;
        int dv = v < 1 ? 1 : v;
        dinv[i] = 1.0f / sqrtf((float)dv);
    }
    if (i == 0) offsets[n] = E;
}

// ---------- fused: payload scatter (+spos) || dst fill ----------
__global__ void fused_scatter(const int* __restrict__ dst, const int* __restrict__ src,
                              const float* __restrict__ ew, const float* __restrict__ dinv,
                              int E, int* __restrict__ cursor, int4* __restrict__ payload,
                              int* __restrict__ spos,
                              const int* __restrict__ offsets, int n, int* __restrict__ dsts,
                              int SCB) {
    int b = blockIdx.x, t = threadIdx.x;
    if (b < SCB) {
        int i = b * 256 + t;
        if (i < E) {
            int s = src[i], d = dst[i];
            int pcur = atomicAdd(&cursor[d], 1);
            int4 pl;
            pl.x = s;
            pl.y = __builtin_bit_cast(int, ew[i]);
            pl.z = __builtin_bit_cast(int, dinv[s]);
            pl.w = i;
            payload[pcur] = pl;
            spos[i] = pcur;
        }
    } else {
        int node = (b - SCB) * 256 + t;
        if (node < n) {
            int beg = offsets[node], end = offsets[node + 1];
            for (int e = beg; e < end; ++e) dsts[e] = node;
        }
    }
}

// ---------- fused: QKV MFMA || pass1 gathers ----------
__global__ __launch_bounds__(256) void fused_qp(
        const unsigned short* __restrict__ hpb,
        const unsigned short* __restrict__ WQTp, const unsigned short* __restrict__ WKTp,
        const unsigned short* __restrict__ WVT, int n,
        unsigned short* __restrict__ Qhb, unsigned short* __restrict__ Khb,
        unsigned short* __restrict__ Vhb,
        const int* __restrict__ offsets, const int4* __restrict__ payload,
        const float* __restrict__ dinv,
        unsigned short* __restrict__ Tx1b, unsigned short* __restrict__ aggb, int QB) {
    int t = threadIdx.x;
    if (blockIdx.x < QB) {
        // ---- k_qkv body ----
        int lane = t & 63;
        int q = lane & 15, g = lane >> 4;
        int wid = (blockIdx.x * 256 + t) >> 6;
        int nb16 = wid * 16;
        if (nb16 >= n) return;
        int node = nb16 + q;
        int nodec = node < n ? node : n - 1;

        f32x4 aq[4], ak[4], av[4];
#pragma unroll
        for (int tc = 0; tc < 4; ++tc) {
            aq[tc] = (f32x4){0, 0, 0, 0}; ak[tc] = (f32x4){0, 0, 0, 0}; av[tc] = (f32x4){0, 0, 0, 0};
        }
#pragma unroll
        for (int kk = 0; kk < 4; ++kk) {
            bf16x8 a = *(const bf16x8*)(hpb + (size_t)nodec * 128 + kk * 32 + g * 8);
#pragma unroll
            for (int tc = 0; tc < 4; ++tc) {
                bf16x8 bq = *(const bf16x8*)(WQTp + (tc * 16 + q) * 128 + kk * 32 + g * 8);
                bf16x8 bk = *(const bf16x8*)(WKTp + (tc * 16 + q) * 128 + kk * 32 + g * 8);
                bf16x8 bv = *(const bf16x8*)(WVT + (tc * 16 + q) * 128 + kk * 32 + g * 8);
                aq[tc] = __builtin_amdgcn_mfma_f32_16x16x32_bf16(a, bq, aq[tc], 0, 0, 0);
                ak[tc] = __builtin_amdgcn_mfma_f32_16x16x32_bf16(a, bk, ak[tc], 0, 0, 0);
                av[tc] = __builtin_amdgcn_mfma_f32_16x16x32_bf16(a, bv, av[tc], 0, 0, 0);
            }
        }
#pragma unroll
        for (int r = 0; r < 4; ++r) {
            int nd = nb16 + g * 4 + r;
            if (nd < n) {
                u16x4 oq, ok;
#pragma unroll
                for (int tc = 0; tc < 4; ++tc) {
                    oq[tc] = (unsigned short)f2bf(aq[tc][r]);
                    ok[tc] = (unsigned short)f2bf(ak[tc][r]);
                }
                *(u16x4*)(Qhb + (size_t)nd * 64 + q * 4) = oq;
                *(u16x4*)(Khb + (size_t)nd * 64 + q * 4) = ok;
#pragma unroll
                for (int tc = 0; tc < 4; ++tc)
                    Vhb[(size_t)nd * 64 + tc * 16 + q] = (unsigned short)f2bf(av[tc][r]);
            }
        }
    } else {
        // ---- k_pass1 body ----
        int w = t >> 6, lane = t & 63;
        int node = (blockIdx.x - QB) * 4 + w;
        if (node >= n) return;
        int q = lane & 7, g = lane >> 3;
        int beg = offsets[node], end = offsets[node + 1];
        float aL[8], aG[8];
#pragma unroll
        for (int c = 0; c < 8; ++c) { aL[c] = 0.f; aG[c] = 0.f; }
        int e2 = beg;
        for (; e2 + 16 <= end; e2 += 16) {
            int4 pa = payload[e2 + g], pb = payload[e2 + 8 + g];
            u16x8 va = *(const u16x8*)(hpb + (size_t)pa.x * 128 + q * 8);
            u16x8 vb = *(const u16x8*)(hpb + (size_t)pb.x * 128 + q * 8);
            float da = i2f(pa.z), db = i2f(pb.z);
            float wa = i2f(pa.y), wb = i2f(pb.y);
#pragma unroll
            for (int c = 0; c < 8; ++c) {
                float fa = bf2f(va[c]), fb = bf2f(vb[c]);
                aL[c] = fmaf(da, fa, aL[c]); aL[c] = fmaf(db, fb, aL[c]);
                aG[c] = fmaf(wa, fa, aG[c]); aG[c] = fmaf(wb, fb, aG[c]);
            }
        }
        for (; e2 < end; e2 += 8) {
            int e = e2 + g;
            if (e < end) {
                int4 pl = payload[e];
                u16x8 v = *(const u16x8*)(hpb + (size_t)pl.x * 128 + q * 8);
                float d = i2f(pl.z), wv = i2f(pl.y);
#pragma unroll
                for (int c = 0; c < 8; ++c) {
                    float f = bf2f(v[c]);
                    aL[c] = fmaf(d, f, aL[c]);
                    aG[c] = fmaf(wv, f, aG[c]);
                }
            }
        }
#pragma unroll
        for (int c = 0; c < 8; ++c) {
            aL[c] += __shfl_xor(aL[c], 8, 64);  aL[c] += __shfl_xor(aL[c], 16, 64);
            aL[c] += __shfl_xor(aL[c], 32, 64);
            aG[c] += __shfl_xor(aG[c], 8, 64);  aG[c] += __shfl_xor(aG[c], 16, 64);
            aG[c] += __shfl_xor(aG[c], 32, 64);
        }
        if (g == 0) {
            float dn = dinv[node];
            u16x8 o1, o2;
#pragma unroll
            for (int c = 0; c < 8; ++c) {
                o1[c] = (unsigned short)f2bf(-dn * aL[c]);
                o2[c] = (unsigned short)f2bf(aG[c]);
            }
            *(u16x8*)(Tx1b + (size_t)node * DD + q * 8) = o1;
            *(u16x8*)(aggb + (size_t)node * DD + q * 8) = o2;
        }
    }
}

// ---------- fused: score (original-order coalesced e-stream) || lap(Tx1->Tx2) ----------
__global__ __launch_bounds__(256) void fused_sl(
        const float* __restrict__ efeat, const short* __restrict__ WETb,
        const int* __restrict__ esrc, const int* __restrict__ edst,
        const int* __restrict__ spos,
        const int4* __restrict__ payload,
        const unsigned short* __restrict__ Qhb, const unsigned short* __restrict__ Khb,
        int E, unsigned short* __restrict__ ssb,
        const int* __restrict__ offsets, const float* __restrict__ dinv,
        const unsigned short* __restrict__ Tx1b, const unsigned short* __restrict__ hpb,
        int n, unsigned short* __restrict__ Tx2b, int SB, int score_nwaves) {
    int t = threadIdx.x;
    if (blockIdx.x < SB) {
        // ---- score: original edge order, coalesced e-stream ----
        int lane = t & 63;
        int q = lane & 15, g = lane >> 4;
        bf16x8 bfrag[2][4];
#pragma unroll
        for (int kc = 0; kc < 2; ++kc)
#pragma unroll
            for (int tc = 0; tc < 4; ++tc)
                bfrag[kc][tc] = *(const bf16x8*)(WETb + (tc * 16 + q) * 64 + kc * 32 + g * 8);

        const float invs = 0.35355339059327373f;  // 1/sqrt(8)
        int wid = (blockIdx.x * 256 + t) >> 6;
        int ntiles = (E + 15) >> 4;

        for (int wt = wid; wt < ntiles; wt += score_nwaves) {
            int ebase = wt * 16;
            int er = ebase + q;
            int erc = er < E ? er : E - 1;
            const float* ep = efeat + (size_t)erc * 64;   // sequential across tile
            float4 c0 = *(const float4*)(ep + g * 8);
            float4 c1 = *(const float4*)(ep + g * 8 + 4);
            float4 c2 = *(const float4*)(ep + 32 + g * 8);
            float4 c3 = *(const float4*)(ep + 32 + g * 8 + 4);

            u16x4 kv4[4], qv4[4];
            int sp[4];
#pragma unroll
            for (int r = 0; r < 4; ++r) {
                int e = ebase + g * 4 + r;
                int ec = e < E ? e : E - 1;
                int sA = esrc[ec], tA = edst[ec];
                sp[r] = spos[ec];
                kv4[r] = *(const u16x4*)(Khb + (size_t)sA * 64 + q * 4);
                qv4[r] = *(const u16x4*)(Qhb + (size_t)tA * 64 + q * 4);
            }

            f32x4 acc0 = {0, 0, 0, 0}, acc1 = {0, 0, 0, 0};
            f32x4 acc2 = {0, 0, 0, 0}, acc3 = {0, 0, 0, 0};
            {
                bf16x8 a;
                a[0] = f2bf(c0.x); a[1] = f2bf(c0.y); a[2] = f2bf(c0.z); a[3] = f2bf(c0.w);
                a[4] = f2bf(c1.x); a[5] = f2bf(c1.y); a[6] = f2bf(c1.z); a[7] = f2bf(c1.w);
                acc0 = __builtin_amdgcn_mfma_f32_16x16x32_bf16(a, bfrag[0][0], acc0, 0, 0, 0);
                acc1 = __builtin_amdgcn_mfma_f32_16x16x32_bf16(a, bfrag[0][1], acc1, 0, 0, 0);
                acc2 = __builtin_amdgcn_mfma_f32_16x16x32_bf16(a, bfrag[0][2], acc2, 0, 0, 0);
                acc3 = __builtin_amdgcn_mfma_f32_16x16x32_bf16(a, bfrag[0][3], acc3, 0, 0, 0);
                a[0] = f2bf(c2.x); a[1] = f2bf(c2.y); a[2] = f2bf(c2.z); a[3] = f2bf(c2.w);
                a[4] = f2bf(c3.x); a[5] = f2bf(c3.y); a[6] = f2bf(c3.z); a[7] = f2bf(c3.w);
                acc0 = __builtin_amdgcn_mfma_f32_16x16x32_bf16(a, bfrag[1][0], acc0, 0, 0, 0);
                acc1 = __builtin_amdgcn_mfma_f32_16x16x32_bf16(a, bfrag[1][1], acc1, 0, 0, 0);
                acc2 = __builtin_amdgcn_mfma_f32_16x16x32_bf16(a, bfrag[1][2], acc2, 0, 0, 0);
                acc3 = __builtin_amdgcn_mfma_f32_16x16x32_bf16(a, bfrag[1][3], acc3, 0, 0, 0);
            }

#pragma unroll
            for (int r = 0; r < 4; ++r) {
                int e = ebase + g * 4 + r;
                float pv = bf2f(kv4[r][0]) * bf2f(qv4[r][0]) * acc0[r]
                         + bf2f(kv4[r][1]) * bf2f(qv4[r][1]) * acc1[r]
                         + bf2f(kv4[r][2]) * bf2f(qv4[r][2]) * acc2[r]
                         + bf2f(kv4[r][3]) * bf2f(qv4[r][3]) * acc3[r];
                pv *= invs;
                pv += __shfl_xor(pv, 8, 64);
                float sc = __expf(fminf(fmaxf(pv, -5.0f), 5.0f));
                if ((lane & 8) == 0 && e < E)
                    ssb[(size_t)sp[r] * HH + (q & 7)] = (unsigned short)f2bf(sc);
            }
        }
    } else {
        // ---- lap: Tx2 = 2*lap(Tx1) - h ----
        int w = t >> 6, lane = t & 63;
        int node = (blockIdx.x - SB) * 4 + w;
        if (node >= n) return;
        int q = lane & 7, g = lane >> 3;
        int beg = offsets[node], end = offsets[node + 1];
        float a[8];
#pragma unroll
        for (int c = 0; c < 8; ++c) a[c] = 0.f;
        int e2 = beg;
        for (; e2 + 16 <= end; e2 += 16) {
            int4 pa = payload[e2 + g], pb = payload[e2 + 8 + g];
            u16x8 va = *(const u16x8*)(Tx1b + (size_t)pa.x * 64 + q * 8);
            u16x8 vb = *(const u16x8*)(Tx1b + (size_t)pb.x * 64 + q * 8);
            float da = i2f(pa.z), db = i2f(pb.z);
#pragma unroll
            for (int c = 0; c < 8; ++c) {
                a[c] = fmaf(da, bf2f(va[c]), a[c]);
                a[c] = fmaf(db, bf2f(vb[c]), a[c]);
            }
        }
        for (; e2 < end; e2 += 8) {
            int e = e2 + g;
            if (e < end) {
                int4 pl = payload[e];
                u16x8 v = *(const u16x8*)(Tx1b + (size_t)pl.x * 64 + q * 8);
                float d = i2f(pl.z);
#pragma unroll
                for (int c = 0; c < 8; ++c) a[c] = fmaf(d, bf2f(v[c]), a[c]);
            }
        }
#pragma unroll
        for (int c = 0; c < 8; ++c) {
            a[c] += __shfl_xor(a[c], 8, 64);  a[c] += __shfl_xor(a[c], 16, 64);
            a[c] += __shfl_xor(a[c], 32, 64);
        }
        if (g == 0) {
            float dn = dinv[node];
            u16x8 pv = *(const u16x8*)(hpb + (size_t)node * 128 + q * 8);
            u16x8 o;
#pragma unroll
            for (int c = 0; c < 8; ++c) {
                float v = 2.0f * (-dn * a[c]) - bf2f(pv[c]);
                o[c] = (unsigned short)f2bf(v);
            }
            *(u16x8*)(Tx2b + (size_t)node * DD + q * 8) = o;
        }
    }
}

// ---------- fused: Tx3 = 2*lap(Tx2) - Tx1  AND  attention aggregation (ss bf16) ----------
__global__ void k_lap3_attn(const int* __restrict__ offsets, const int4* __restrict__ payload,
                            const float* __restrict__ dinv,
                            const unsigned short* __restrict__ Tx2b,
                            const unsigned short* __restrict__ Tx1b,
                            const unsigned short* __restrict__ Vhb,
                            const unsigned short* __restrict__ ssb,
                            int n, unsigned short* __restrict__ Tx3b,
                            float* __restrict__ out) {
    int w = threadIdx.x >> 6, lane = threadIdx.x & 63;
    int node = blockIdx.x * 4 + w;
    if (node >= n) return;
    int q = lane & 7, g = lane >> 3;  // head == q
    int beg = offsets[node], end = offsets[node + 1];
    float a[8], aV[8];
#pragma unroll
    for (int c = 0; c < 8; ++c) { a[c] = 0.f; aV[c] = 0.f; }
    float aZ = 0.f;
    int e2 = beg;
    for (; e2 + 16 <= end; e2 += 16) {
        int ea = e2 + g, eb = e2 + 8 + g;
        int4 pa = payload[ea], pb = payload[eb];
        u16x8 xa = *(const u16x8*)(Tx2b + (size_t)pa.x * DD + q * 8);
        u16x8 xb = *(const u16x8*)(Tx2b + (size_t)pb.x * DD + q * 8);
        u16x8 va = *(const u16x8*)(Vhb + (size_t)pa.x * DD + q * 8);
        u16x8 vb = *(const u16x8*)(Vhb + (size_t)pb.x * DD + q * 8);
        float sva = bf2f(ssb[(size_t)ea * HH + q]);
        float svb = bf2f(ssb[(size_t)eb * HH + q]);
        float da = i2f(pa.z), db = i2f(pb.z);
#pragma unroll
        for (int c = 0; c < 8; ++c) {
            a[c] = fmaf(da, bf2f(xa[c]), a[c]);
            a[c] = fmaf(db, bf2f(xb[c]), a[c]);
            aV[c] = fmaf(sva, bf2f(va[c]), aV[c]);
            aV[c] = fmaf(svb, bf2f(vb[c]), aV[c]);
        }
        aZ += sva + svb;
    }
    for (; e2 < end; e2 += 8) {
        int e = e2 + g;
        if (e < end) {
            int4 pl = payload[e];
            u16x8 x = *(const u16x8*)(Tx2b + (size_t)pl.x * DD + q * 8);
            u16x8 v = *(const u16x8*)(Vhb + (size_t)pl.x * DD + q * 8);
            float sv = bf2f(ssb[(size_t)e * HH + q]);
            float d = i2f(pl.z);
#pragma unroll
            for (int c = 0; c < 8; ++c) {
                a[c] = fmaf(d, bf2f(x[c]), a[c]);
                aV[c] = fmaf(sv, bf2f(v[c]), aV[c]);
            }
            aZ += sv;
        }
    }
#pragma unroll
    for (int c = 0; c < 8; ++c) {
        a[c] += __shfl_xor(a[c], 8, 64);   a[c] += __shfl_xor(a[c], 16, 64);
        a[c] += __shfl_xor(a[c], 32, 64);
        aV[c] += __shfl_xor(aV[c], 8, 64); aV[c] += __shfl_xor(aV[c], 16, 64);
        aV[c] += __shfl_xor(aV[c], 32, 64);
    }
    aZ += __shfl_xor(aZ, 8, 64); aZ += __shfl_xor(aZ, 16, 64); aZ += __shfl_xor(aZ, 32, 64);
    if (g == 0) {
        float dn = dinv[node];
        u16x8 pv = *(const u16x8*)(Tx1b + (size_t)node * DD + q * 8);
        u16x8 o;
        float inv = 1.0f / (aZ + 1e-6f);
        float4 o1, o2;
#pragma unroll
        for (int c = 0; c < 8; ++c) {
            float v = 2.0f * (-dn * a[c]) - bf2f(pv[c]);
            o[c] = (unsigned short)f2bf(v);
        }
        o1.x = aV[0] * inv; o1.y = aV[1] * inv; o1.z = aV[2] * inv; o1.w = aV[3] * inv;
        o2.x = aV[4] * inv; o2.y = aV[5] * inv; o2.z = aV[6] * inv; o2.w = aV[7] * inv;
        *(u16x8*)(Tx3b + (size_t)node * DD + q * 8) = o;
        *(float4*)(out + (size_t)node * 192 + 128 + q * 8) = o1;
        *(float4*)(out + (size_t)node * 192 + 128 + q * 8 + 4) = o2;
    }
}

// ---------- output via MFMA: cheb (4 fc-scaled tables) + gcn ----------
__global__ __launch_bounds__(256) void k_out(
        const unsigned short* __restrict__ hpb, const unsigned short* __restrict__ Tx1b,
        const unsigned short* __restrict__ Tx2b, const unsigned short* __restrict__ Tx3b,
        const unsigned short* __restrict__ aggb, const float* __restrict__ fc,
        const unsigned short* __restrict__ WcT, const unsigned short* __restrict__ WgT,
        const float* __restrict__ bc, const float* __restrict__ bg,
        int n, float* __restrict__ out) {
    int lane = threadIdx.x & 63;
    int q = lane & 15, g = lane >> 4;
    int wid = (blockIdx.x * 256 + threadIdx.x) >> 6;
    int nb16 = wid * 16;
    if (nb16 >= n) return;
    int node = nb16 + q;
    int nodec = node < n ? node : n - 1;
    float f0 = fc[nodec], f1 = fc[n + nodec], f2 = fc[2 * n + nodec], f3 = fc[3 * n + nodec];

    f32x4 ac[4], ag[4];
#pragma unroll
    for (int tc = 0; tc < 4; ++tc) { ac[tc] = (f32x4){0,0,0,0}; ag[tc] = (f32x4){0,0,0,0}; }

#pragma unroll
    for (int kk = 0; kk < 2; ++kk) {
        int off = kk * 32 + g * 8;
        bf16x8 a0r = *(const bf16x8*)(hpb + (size_t)nodec * 128 + off);   // Tx0 = h
        bf16x8 a1r = *(const bf16x8*)(Tx1b + (size_t)nodec * 64 + off);
        bf16x8 a2r = *(const bf16x8*)(Tx2b + (size_t)nodec * 64 + off);
        bf16x8 a3r = *(const bf16x8*)(Tx3b + (size_t)nodec * 64 + off);
        bf16x8 aA  = *(const bf16x8*)(aggb + (size_t)nodec * 64 + off);
        bf16x8 a0, a1, a2, a3;
#pragma unroll
        for (int j = 0; j < 8; ++j) {
            a0[j] = f2bf(f0 * bf2f((unsigned short)a0r[j]));
            a1[j] = f2bf(f1 * bf2f((unsigned short)a1r[j]));
            a2[j] = f2bf(f2 * bf2f((unsigned short)a2r[j]));
            a3[j] = f2bf(f3 * bf2f((unsigned short)a3r[j]));
        }
#pragma unroll
        for (int tc = 0; tc < 4; ++tc) {
            bf16x8 b0 = *(const bf16x8*)(WcT + 0 * 4096 + (tc * 16 + q) * 64 + off);
            bf16x8 b1 = *(const bf16x8*)(WcT + 1 * 4096 + (tc * 16 + q) * 64 + off);
            bf16x8 b2 = *(const bf16x8*)(WcT + 2 * 4096 + (tc * 16 + q) * 64 + off);
            bf16x8 b3 = *(const bf16x8*)(WcT + 3 * 4096 + (tc * 16 + q) * 64 + off);
            bf16x8 bgw = *(const bf16x8*)(WgT + (tc * 16 + q) * 64 + off);
            ac[tc] = __builtin_amdgcn_mfma_f32_16x16x32_bf16(a0, b0, ac[tc], 0, 0, 0);
            ac[tc] = __builtin_amdgcn_mfma_f32_16x16x32_bf16(a1, b1, ac[tc], 0, 0, 0);
            ac[tc] = __builtin_amdgcn_mfma_f32_16x16x32_bf16(a2, b2, ac[tc], 0, 0, 0);
            ac[tc] = __builtin_amdgcn_mfma_f32_16x16x32_bf16(a3, b3, ac[tc], 0, 0, 0);
            ag[tc] = __builtin_amdgcn_mfma_f32_16x16x32_bf16(aA, bgw, ag[tc], 0, 0, 0);
        }
    }
#pragma unroll
    for (int tc = 0; tc < 4; ++tc) {
        float bcv = bc[tc * 16 + q], bgv = bg[tc * 16 + q];
#pragma unroll
        for (int r = 0; r < 4; ++r) {
            int nd = nb16 + g * 4 + r;
            if (nd < n) {
                out[(size_t)nd * 192 + tc * 16 + q] = ac[tc][r] + bcv;
                out[(size_t)nd * 192 + 64 + tc * 16 + q] = ag[tc][r] + bgv;
            }
        }
    }
}

extern "C" void kernel_launch(void* const* d_in, const int* in_sizes, int n_in,
                              void* d_out, int out_size, void* d_ws, size_t ws_size,
                              hipStream_t stream) {
    const float* h  = (const float*)d_in[0];
    const float* p  = (const float*)d_in[1];
    const float* ef = (const float*)d_in[2];
    const float* ew = (const float*)d_in[3];
    const float* fc = (const float*)d_in[4];
    const int* esrc = (const int*)d_in[5];
    const int* edst = (const int*)d_in[6];
    const float* Wc = (const float*)d_in[7];
    const float* bc = (const float*)d_in[8];
    const float* Wg = (const float*)d_in[9];
    const float* bg = (const float*)d_in[10];
    const float* WQ = (const float*)d_in[11];
    const float* WK = (const float*)d_in[12];
    const float* WV = (const float*)d_in[13];
    const float* WE = (const float*)d_in[14];

    const int n = in_sizes[0] / DD;   // 50000
    const int E = in_sizes[5];        // 800000
    float* out = (float*)d_out;

    char* wsp = (char*)d_ws;
    size_t o = 0;
    auto alloc = [&](size_t bytes) -> void* {
        void* r = (void*)(wsp + o);
        o = (o + bytes + 255) & ~(size_t)255;
        return r;
    };
    int* deg     = (int*)alloc((size_t)n * 4);
    int* offsets = (int*)alloc((size_t)(n + 1) * 4);
    int* cursor  = (int*)alloc((size_t)n * 4);
    int4* payload = (int4*)alloc((size_t)E * 16);
    int* spos    = (int*)alloc((size_t)E * 4);
    int* dsts    = (int*)alloc((size_t)E * 4);
    int* bsum    = (int*)alloc(1024 * 4);
    float* dinv  = (float*)alloc((size_t)n * 4);
    short* WETb  = (short*)alloc(4096 * 2);
    unsigned short* WQTp = (unsigned short*)alloc(8192 * 2);
    unsigned short* WKTp = (unsigned short*)alloc(8192 * 2);
    unsigned short* WVT  = (unsigned short*)alloc(8192 * 2);
    unsigned short* WcT  = (unsigned short*)alloc(16384 * 2);
    unsigned short* WgT  = (unsigned short*)alloc(4096 * 2);
    unsigned short* hpb  = (unsigned short*)alloc((size_t)n * 128 * 2);
    unsigned short* Tx1b = (unsigned short*)alloc((size_t)n * DD * 2);
    unsigned short* Tx2b = (unsigned short*)alloc((size_t)n * DD * 2);
    unsigned short* Tx3b = (unsigned short*)alloc((size_t)n * DD * 2);
    unsigned short* aggb = (unsigned short*)alloc((size_t)n * DD * 2);
    unsigned short* Vhb  = (unsigned short*)alloc((size_t)n * DD * 2);
    unsigned short* Qhb  = (unsigned short*)alloc((size_t)n * DD * 2);
    unsigned short* Khb  = (unsigned short*)alloc((size_t)n * DD * 2);
    unsigned short* ssb  = (unsigned short*)alloc((size_t)E * HH * 2);
    (void)ws_size; (void)n_in; (void)out_size;

    hipMemsetAsync(deg, 0, (size_t)n * 4, stream);

    int nb = (n + 255) / 256;
    int CB = (E + 255) / 256;                 // count blocks
    int PRB = 128;                            // prep blocks (32768/256)
    int HB = (n * 64 + 255) / 256;            // hpb blocks
    fused_init<<<CB + PRB + HB, 256, 0, stream>>>(edst, E, deg, WQ, WK, WV, Wc, Wg, WE,
                                                  WQTp, WKTp, WVT, WcT, WgT, WETb,
                                                  h, p, n, hpb, CB, PRB);
    k_blocksum<<<nb, 256, 0, stream>>>(deg, n, bsum);
    k_scan_bsum<<<1, 256, 0, stream>>>(bsum, nb);
    k_scan_final<<<nb, 256, 0, stream>>>(deg, bsum, n, E, offsets, cursor, dinv);

    int SCB = (E + 255) / 256;
    fused_scatter<<<SCB + nb, 256, 0, stream>>>(edst, esrc, ew, dinv, E, cursor, payload,
                                                spos, offsets, n, dsts, SCB);

    int qkv_waves = (n + 15) / 16;
    int QB = (qkv_waves + 3) / 4;
    int PB = (n + 3) / 4;
    fused_qp<<<QB + PB, 256, 0, stream>>>(hpb, WQTp, WKTp, WVT, n, Qhb, Khb, Vhb,
                                          offsets, payload, dinv, Tx1b, aggb, QB);

    int SB = 1024;   // half-machine score blocks -> lap blocks co-resident
    int LB = (n + 3) / 4;
    fused_sl<<<SB + LB, 256, 0, stream>>>(ef, WETb, esrc, edst, spos, payload, Qhb, Khb,
                                          E, ssb, offsets, dinv, Tx1b, hpb, n, Tx2b,
                                          SB, SB * 4);

    k_lap3_attn<<<(n + 3) / 4, 256, 0, stream>>>(offsets, payload, dinv, Tx2b, Tx1b, Vhb,
                                                 ssb, n, Tx3b, out);

    int out_waves = (n + 15) / 16;
    k_out<<<(out_waves + 3) / 4, 256, 0, stream>>>(hpb, Tx1b, Tx2b, Tx3b, aggb, fc,
                                                   WcT, WgT, bc, bg, n, out);
}